// Round 7
// baseline (1074.308 us; speedup 1.0000x reference)
//
#include <hip/hip_runtime.h>
#include <stdint.h>
#include <math.h>

// ---------------------------------------------------------------------------
// CosineHammingAttention — bit-faithful HIP port of the JAX reference.
// B=2 H=8 N=4096 D=64, NUM_PROJS=7, BUCKET=256, SAMPLE=800, PM_ITERS=32
// R2: parallelize Gram.  R3: 64 rows x 4 chunks attention (occupancy fix).
// R5: __expf, sort fuses qblock (512 thr), p split 128+256 blocks, sample
//     fuses gather, gram f32 chunk accum.
// R6: REVERT R5's float4 compute-loop reads in sparse/residual — they forced
//     4-aligned reg tuples + acc[68] -> spill (VGPR 128->88, VALUBusy
//     52->38.6%, dur 440->538). Scalar acc[65] loops restored; __expf kept.
// ---------------------------------------------------------------------------

typedef unsigned int u32;

namespace {
constexpr int Bc = 2, Hc = 8, BHc = 16;
constexpr int Nc = 4096, Dc = 64, D1c = 65;
constexpr int NBc = 16;      // N / BUCKET
constexpr int Sc = 800;      // SAMPLE
constexpr int PMITERc = 32;
constexpr int GCH = 128;             // Gram rows per chunk
constexpr int NCHUNK = Nc / GCH;     // 32
constexpr int WST = 68;              // padded sigV row stride (16B-aligned rows)
}

__device__ __forceinline__ u32 rotl32(u32 x, u32 d) { return (x << d) | (x >> (32u - d)); }

// Exact JAX threefry2x32 (20 rounds).
__device__ __forceinline__ void threefry2x32(u32 k0, u32 k1, u32 x0, u32 x1, u32& o0, u32& o1) {
  u32 ks2 = k0 ^ k1 ^ 0x1BD11BDAu;
  x0 += k0; x1 += k1;
#define TF_RND(r) { x0 += x1; x1 = rotl32(x1, r); x1 ^= x0; }
  TF_RND(13) TF_RND(15) TF_RND(26) TF_RND(6)
  x0 += k1; x1 += ks2 + 1u;
  TF_RND(17) TF_RND(29) TF_RND(16) TF_RND(24)
  x0 += ks2; x1 += k0 + 2u;
  TF_RND(13) TF_RND(15) TF_RND(26) TF_RND(6)
  x0 += k0; x1 += k1 + 3u;
  TF_RND(17) TF_RND(29) TF_RND(16) TF_RND(24)
  x0 += k1; x1 += ks2 + 4u;
  TF_RND(13) TF_RND(15) TF_RND(26) TF_RND(6)
  x0 += ks2; x1 += k0 + 5u;
#undef TF_RND
  o0 = x0; o1 = x1;
}

// gumbel sample for flat element i of the (800,16,4096) array, key = (0,1234)
// partitionable threefry: bits = out0 ^ out1 of counter (0, i)
__device__ __forceinline__ float gumbel_at(u32 i) {
  u32 o0, o1;
  threefry2x32(0u, 1234u, 0u, i, o0, o1);
  u32 bits = o0 ^ o1;
  u32 fb = (bits >> 9) | 0x3f800000u;
  float u = __uint_as_float(fb) - 1.0f;           // [0,1) on 2^-23 grid
  if (u == 0.0f) u = 1.1754944e-38f;              // max(tiny, u) per jax.random.uniform
  return -__logf(-__logf(u));
}

// ---- K1: LSH hash codes for q and k ---------------------------------------
__global__ __launch_bounds__(256) void hash_kernel(
    const float* __restrict__ q, const float* __restrict__ k,
    const float* __restrict__ pd, int* __restrict__ hq, int* __restrict__ hk) {
  int tid = blockIdx.x * 256 + threadIdx.x;
  int which = tid / (BHc * Nc);
  int rem = tid % (BHc * Nc);
  int bh = rem / Nc, n = rem % Nc;
  int b = bh / Hc, h = bh % Hc;
  const float* x = which ? k : q;
  const float* row = x + (((size_t)b * Nc + n) * Hc + h) * Dc;   // [B,N,H,D]
  const float* pdr = pd + (size_t)bh * Dc * 7;                   // [B,H,D,7]
  double acc[7];
#pragma unroll
  for (int r = 0; r < 7; r++) acc[r] = 0.0;
  for (int d = 0; d < Dc; d++) {
    double vv = (double)row[d];
    const float* pr = pdr + d * 7;
#pragma unroll
    for (int r = 0; r < 7; r++) acc[r] += vv * (double)pr[r];
  }
  int code = 0;
#pragma unroll
  for (int r = 0; r < 7; r++) code |= (acc[r] > 0.0) ? (1 << r) : 0;
  int hash = code ^ (code >> 1);   // _hamming_perm == binary-reflected Gray code
  (which ? hk : hq)[bh * Nc + n] = hash;
}

// ---- K2: stable counting sort, quarter-split; q-branch also writes qblk ---
__global__ __launch_bounds__(512) void sort_kernel(
    const int* __restrict__ hq, const int* __restrict__ hk,
    int* __restrict__ qidx, int* __restrict__ kidx, int* __restrict__ qblk) {
  __shared__ int sh[Nc];
  __shared__ int cnt[4][128];
  __shared__ int off[128];
  int bh = blockIdx.x;
  int which = blockIdx.y;
  const int* hash = which ? hk : hq;
  int* out = which ? kidx : qidx;
  int t = threadIdx.x;
  for (int i = t; i < Nc; i += 512) sh[i] = hash[bh * Nc + i];
  __syncthreads();
  int qr = t >> 7, b = t & 127;      // quarter, bin
  int c = 0;
  for (int i = qr * 1024; i < (qr + 1) * 1024; i++) c += (sh[i] == b);
  cnt[qr][b] = c;
  __syncthreads();
  if (t == 0) {
    int run = 0;
    for (int j = 0; j < 128; j++) {
      int tot = cnt[0][j] + cnt[1][j] + cnt[2][j] + cnt[3][j];
      off[j] = run; run += tot;
    }
  }
  __syncthreads();
  int o = off[b];
  for (int qq = 0; qq < qr; qq++) o += cnt[qq][b];
  for (int i = qr * 1024; i < (qr + 1) * 1024; i++)
    if (sh[i] == b) {
      out[bh * Nc + o] = i;
      if (which == 0) qblk[bh * Nc + i] = o >> 8;
      o++;
    }
}

// ---- K4: block-sparse attention, 64 rows x 4 key-chunks per block ---------
__global__ __launch_bounds__(256) void sparse_kernel(
    const float* __restrict__ q, const float* __restrict__ k, const float* __restrict__ v,
    const int* __restrict__ qidx, const int* __restrict__ kidx, float* __restrict__ att) {
  __shared__ float S[8320];        // main: kb[64][64] | wb[64][64]; combine: 128*65
  float* kb = S;
  float* wb = S + 4096;
  int blk = blockIdx.x;
  int bh = blk >> 6;               // 64 blocks per bh
  int rem = blk & 63;
  int g = rem >> 2, qq = rem & 3;  // bucket, query-quadrant
  int b = bh / Hc, h = bh % Hc;
  int t = threadIdx.x;
  int r = t & 63, cid = t >> 6;
  int nq = qidx[bh * Nc + g * 256 + qq * 64 + r];
  const float* qrow = q + (((size_t)b * Nc + nq) * Hc + h) * Dc;
  float qreg[Dc];
#pragma unroll
  for (int d4 = 0; d4 < 16; d4++) {
    float4 f = ((const float4*)qrow)[d4];
    qreg[4 * d4] = f.x; qreg[4 * d4 + 1] = f.y; qreg[4 * d4 + 2] = f.z; qreg[4 * d4 + 3] = f.w;
  }
  float acc[D1c];
#pragma unroll
  for (int p = 0; p < D1c; p++) acc[p] = 0.f;
  const int* kidxB = kidx + bh * Nc + g * 256;
  for (int tile = 0; tile < 4; tile++) {
    for (int e4 = t; e4 < 64 * 16; e4 += 256) {
      int j = e4 >> 4, d4 = e4 & 15;
      int m = kidxB[tile * 64 + j];
      const float* kr = k + (((size_t)b * Nc + m) * Hc + h) * Dc;
      const float* vr = v + (((size_t)b * Nc + m) * Hc + h) * Dc;
      ((float4*)(kb + j * 64))[d4] = ((const float4*)kr)[d4];
      ((float4*)(wb + j * 64))[d4] = ((const float4*)vr)[d4];
    }
    __syncthreads();
    for (int jj = 0; jj < 16; jj++) {
      int j = cid * 16 + jj;
      float s0 = 0, s1 = 0, s2 = 0, s3 = 0;
      const float* kj = kb + j * 64;
#pragma unroll
      for (int d = 0; d < Dc; d += 4) {
        s0 += qreg[d] * kj[d];
        s1 += qreg[d + 1] * kj[d + 1];
        s2 += qreg[d + 2] * kj[d + 2];
        s3 += qreg[d + 3] * kj[d + 3];
      }
      float e_ = __expf((s0 + s1) + (s2 + s3));
      const float* wj = wb + j * 64;
#pragma unroll
      for (int p = 0; p < Dc; p++) acc[p] += e_ * wj[p];
      acc[Dc] += e_;               // v_aug's all-ones column
    }
    __syncthreads();
  }
  // tree-combine the 4 chunk partials (fixed order -> deterministic)
  if (t >= 128) { float* dst = S + (t - 128) * D1c;
#pragma unroll
    for (int p = 0; p < D1c; p++) dst[p] = acc[p]; }
  __syncthreads();
  if (t < 128) { const float* src = S + t * D1c;
#pragma unroll
    for (int p = 0; p < D1c; p++) acc[p] += src[p]; }
  __syncthreads();
  if (t >= 64 && t < 128) { float* dst = S + (t - 64) * D1c;
#pragma unroll
    for (int p = 0; p < D1c; p++) dst[p] = acc[p]; }
  __syncthreads();
  if (t < 64) {
    const float* src = S + t * D1c;
    float* arow = att + ((size_t)bh * Nc + nq) * D1c;   // scatter to original order
#pragma unroll
    for (int p = 0; p < D1c; p++) arow[p] = acc[p] + src[p];
  }
}

// ---- K5a: partial Gram over 128-row chunks (f32 accum, grid = BH*32) ------
__global__ __launch_bounds__(256) void gram_partial_kernel(
    const float* __restrict__ v, double* __restrict__ part) {
  __shared__ float ch[GCH][D1c];
  int bh = blockIdx.x / NCHUNK, c = blockIdx.x % NCHUNK;
  int b = bh / Hc, h = bh % Hc;
  int t = threadIdx.x;
  for (int e = t; e < GCH * D1c; e += 256) {
    int r = e / D1c, p = e % D1c;
    int n = c * GCH + r;
    ch[r][p] = (p < Dc) ? v[(((size_t)b * Nc + n) * Hc + h) * Dc + p] : 1.0f;
  }
  __syncthreads();
  for (int pi = t; pi < D1c * D1c; pi += 256) {
    int tt = pi / D1c, uu = pi % D1c;
    float a = 0.0f;
    for (int r = 0; r < GCH; r++) a += ch[r][tt] * ch[r][uu];
    part[((size_t)bh * NCHUNK + c) * (D1c * D1c) + pi] = (double)a;
  }
}

// ---- K5b: reduce chunk partials (fixed order -> deterministic) ------------
__global__ __launch_bounds__(256) void gram_reduce_kernel(
    const double* __restrict__ part, double* __restrict__ gram) {
  int idx = blockIdx.x * 256 + threadIdx.x;   // over BH * 4225
  if (idx >= BHc * D1c * D1c) return;
  int bh = idx / (D1c * D1c), pi = idx % (D1c * D1c);
  double s = 0.0;
  for (int c = 0; c < NCHUNK; c++)
    s += part[((size_t)bh * NCHUNK + c) * (D1c * D1c) + pi];
  gram[(size_t)bh * (D1c * D1c) + pi] = s;
}

// ---- K6: power method for spectral norm -----------------------------------
__global__ __launch_bounds__(128) void power_kernel(
    const double* __restrict__ gram, const float* __restrict__ pm, double* __restrict__ sigma) {
  __shared__ double G[D1c * D1c];
  __shared__ double x[D1c], y[D1c];
  __shared__ double nrm;
  int bh = blockIdx.x, t = threadIdx.x;
  for (int e = t; e < D1c * D1c; e += 128) G[e] = gram[(size_t)bh * D1c * D1c + e];
  if (t < D1c) x[t] = (double)pm[bh * D1c + t];
  __syncthreads();
  if (t == 0) {
    double s = 0; for (int i = 0; i < D1c; i++) s += x[i] * x[i];
    nrm = sqrt(s);
  }
  __syncthreads();
  if (t < D1c) x[t] /= nrm;
  for (int it = 0; it < PMITERc; it++) {
    __syncthreads();
    if (t < D1c) {
      double s = 0;
      for (int u = 0; u < D1c; u++) s += G[t * D1c + u] * x[u];
      y[t] = s;
    }
    __syncthreads();
    if (t == 0) {
      double s = 0; for (int i = 0; i < D1c; i++) s += y[i] * y[i];
      nrm = sqrt(s);
    }
    __syncthreads();
    if (t < D1c) x[t] = y[t] / nrm;
  }
  __syncthreads();
  if (t == 0) sigma[bh] = nrm;
}

// ---- K7a: unnormalized P + per-segment partial sums (grid = BH*8) ---------
__global__ __launch_bounds__(256) void p_partial_kernel(
    const float* __restrict__ v, const int* __restrict__ kidx,
    const double* __restrict__ sigma, double* __restrict__ Pun, double* __restrict__ psum) {
  __shared__ double red[256];
  int blk = blockIdx.x;
  int bh = blk >> 3, seg = blk & 7;
  int b = bh / Hc, h = bh % Hc;
  int t = threadIdx.x;
  double sg = sigma[bh];
  double part = 0.0;
  for (int n = seg * 512 + t; n < (seg + 1) * 512; n += 256) {
    int m = kidx[bh * Nc + n];
    const float* vr = v + (((size_t)b * Nc + m) * Hc + h) * Dc;
    double ss = 1.0;  // the appended 1.0 component of v_aug
    for (int d = 0; d < Dc; d++) { double vv = vr[d]; ss += vv * vv; }
    double Pd = sqrt(ss) / sg + (1.0 / (double)Nc);
    Pun[bh * Nc + n] = Pd;
    part += Pd;
  }
  red[t] = part;
  __syncthreads();
  for (int w = 128; w > 0; w >>= 1) {
    if (t < w) red[t] += red[t + w];
    __syncthreads();
  }
  if (t == 0) psum[blk] = red[0];
}

// ---- K7b: normalize + log -------------------------------------------------
__global__ __launch_bounds__(256) void p_final_kernel(
    const double* __restrict__ Pun, const double* __restrict__ psum,
    float* __restrict__ P, float* __restrict__ logP) {
  int idx = blockIdx.x * 256 + threadIdx.x;   // over BH*N
  int bh = idx / Nc;
  double tot = 0.0;
#pragma unroll
  for (int s = 0; s < 8; s++) tot += psum[bh * 8 + s];
  float Pf = (float)(Pun[idx] / tot);
  P[idx] = Pf;
  logP[idx] = logf(Pf);
}

// ---- K8: categorical sampling (argmax gumbel+logP) + fused gather ---------
__global__ __launch_bounds__(256) void sample_kernel(
    const float* __restrict__ logP, const int* __restrict__ kidx,
    const float* __restrict__ P, const float* __restrict__ key, const float* __restrict__ value,
    float* __restrict__ Kpi, float* __restrict__ sigV, int* __restrict__ sblk) {
  __shared__ float sv[256];
  __shared__ int si[256];
  int blk = blockIdx.x;           // bh*S + s
  int bh = blk / Sc, s = blk % Sc;
  int b = bh / Hc, h = bh % Hc;
  int t = threadIdx.x;
  float best = -3.4e38f; int besti = Nc;
  const float* lp = logP + bh * Nc;
  u32 base = ((u32)(s * BHc + bh)) * (u32)Nc;  // flat index into (800,16,4096)
  for (int n = t; n < Nc; n += 256) {
    float val = gumbel_at(base + (u32)n) + lp[n];
    if (val > best || (val == best && n < besti)) { best = val; besti = n; }
  }
  sv[t] = best; si[t] = besti;
  __syncthreads();
  for (int w = 128; w > 0; w >>= 1) {
    if (t < w) {
      float v2 = sv[t + w]; int i2 = si[t + w];
      if (v2 > sv[t] || (v2 == sv[t] && i2 < si[t])) { sv[t] = v2; si[t] = i2; }
    }
    __syncthreads();
  }
  int m = si[0];
  if (t == 0) sblk[blk] = m >> 8;
  int src = kidx[bh * Nc + m];
  float sg = 1.0f / (P[bh * Nc + m] * (float)Sc);
  const float* kr = key + (((size_t)b * Nc + src) * Hc + h) * Dc;
  const float* vr = value + (((size_t)b * Nc + src) * Hc + h) * Dc;
  if (t < Dc) Kpi[(size_t)blk * Dc + t] = kr[t];
  if (t < WST) sigV[(size_t)blk * WST + t] =
      (t < Dc) ? sg * vr[t] : ((t == Dc) ? sg : 0.0f);   // [65..67] = pad
}

// ---- K10: residual attention, 64 rows x 4 sample-chunks per block ---------
__global__ __launch_bounds__(256) void residual_kernel(
    const float* __restrict__ q,
    const float* __restrict__ Kpi, const float* __restrict__ sigV, const int* __restrict__ sblk,
    const int* __restrict__ qblk, const float* __restrict__ att, float* __restrict__ out) {
  __shared__ float S[8448];        // main: kl[64][64] | wl[64][68]; combine: 128*65
  __shared__ int bl[64];
  float* kl = S;
  float* wl = S + 4096;
  int blk = blockIdx.x;
  int bh = blk >> 6;               // 64 row-groups per bh
  int n0 = (blk & 63) * 64;
  int b = bh / Hc, h = bh % Hc;
  int t = threadIdx.x;
  int r = t & 63, cid = t >> 6;
  int n = n0 + r;
  const float* qrow = q + (((size_t)b * Nc + n) * Hc + h) * Dc;
  float qreg[Dc];
#pragma unroll
  for (int d4 = 0; d4 < 16; d4++) {
    float4 f = ((const float4*)qrow)[d4];
    qreg[4 * d4] = f.x; qreg[4 * d4 + 1] = f.y; qreg[4 * d4 + 2] = f.z; qreg[4 * d4 + 3] = f.w;
  }
  int myblk = qblk[bh * Nc + n];
  float acc[D1c];
#pragma unroll
  for (int p = 0; p < D1c; p++) acc[p] = 0.f;
  const float* KpiB = Kpi + (size_t)bh * Sc * Dc;
  const float* sigVB = sigV + (size_t)bh * Sc * WST;
  const int* sblkB = sblk + bh * Sc;
  for (int tile = 0; tile < 13; tile++) {       // 12 tiles of 64 + tail 32
    int base = tile * 64;
    int cnt = (tile < 12) ? 64 : 32;
    for (int e4 = t; e4 < cnt * 16; e4 += 256)     // kl: flat float4 copy
      ((float4*)kl)[e4] = ((const float4*)(KpiB + (size_t)base * Dc))[e4];
    for (int e4 = t; e4 < cnt * 17; e4 += 256)     // wl: flat float4 copy (stride 68)
      ((float4*)wl)[e4] = ((const float4*)(sigVB + (size_t)base * WST))[e4];
    if (t < cnt) bl[t] = sblkB[base + t];
    __syncthreads();
    int per = cnt >> 2;
    for (int jj = 0; jj < per; jj++) {
      int j = cid * per + jj;
      float s0 = 0, s1 = 0, s2 = 0, s3 = 0;
      const float* kj = kl + j * 64;
#pragma unroll
      for (int d = 0; d < Dc; d += 4) {
        s0 += qreg[d] * kj[d];
        s1 += qreg[d + 1] * kj[d + 1];
        s2 += qreg[d + 2] * kj[d + 2];
        s3 += qreg[d + 3] * kj[d + 3];
      }
      float e_ = __expf((s0 + s1) + (s2 + s3));
      float w = (bl[j] == myblk) ? 0.0f : e_;    // mask: sample in query's own block
      const float* wj = wl + j * WST;
#pragma unroll
      for (int p = 0; p < D1c; p++) acc[p] += w * wj[p];
    }
    __syncthreads();
  }
  // tree-combine the 4 chunk partials (fixed order -> deterministic)
  if (t >= 128) { float* dst = S + (t - 128) * D1c;
#pragma unroll
    for (int p = 0; p < D1c; p++) dst[p] = acc[p]; }
  __syncthreads();
  if (t < 128) { const float* src = S + t * D1c;
#pragma unroll
    for (int p = 0; p < D1c; p++) acc[p] += src[p]; }
  __syncthreads();
  if (t >= 64 && t < 128) { float* dst = S + (t - 64) * D1c;
#pragma unroll
    for (int p = 0; p < D1c; p++) dst[p] = acc[p]; }
  __syncthreads();
  if (t < 64) {
    const float* src = S + t * D1c;
#pragma unroll
    for (int p = 0; p < D1c; p++) acc[p] += src[p];
    const float* arow = att + ((size_t)bh * Nc + n) * D1c;
    float denom = arow[Dc] + acc[Dc];
    float* orow = out + ((size_t)bh * Nc + n) * Dc;
#pragma unroll
    for (int d = 0; d < Dc; d++) orow[d] = (arow[d] + acc[d]) / denom;
  }
}

// ---------------------------------------------------------------------------
extern "C" void kernel_launch(void* const* d_in, const int* in_sizes, int n_in,
                              void* d_out, int out_size, void* d_ws, size_t ws_size,
                              hipStream_t stream) {
  const float* q  = (const float*)d_in[0];
  const float* k  = (const float*)d_in[1];
  const float* v  = (const float*)d_in[2];
  const float* pd = (const float*)d_in[3];
  const float* pm = (const float*)d_in[4];
  float* out = (float*)d_out;

  char* w = (char*)d_ws;
  size_t off = 0;
  auto take = [&](size_t nbytes) -> void* {
    void* p = w + off;
    off += (nbytes + 255) & ~(size_t)255;
    return p;
  };
  double* gram = (double*)take((size_t)BHc * D1c * D1c * sizeof(double));
  double* sigm = (double*)take((size_t)BHc * sizeof(double));
  double* Pun  = (double*)take((size_t)BHc * Nc * sizeof(double));
  double* psum = (double*)take((size_t)BHc * 8 * sizeof(double));
  int* hq   = (int*)take((size_t)BHc * Nc * 4);
  int* hk   = (int*)take((size_t)BHc * Nc * 4);
  int* qidx = (int*)take((size_t)BHc * Nc * 4);
  int* kidx = (int*)take((size_t)BHc * Nc * 4);
  int* qblk = (int*)take((size_t)BHc * Nc * 4);
  float* P    = (float*)take((size_t)BHc * Nc * 4);
  float* logP = (float*)take((size_t)BHc * Nc * 4);
  int* sblk = (int*)take((size_t)BHc * Sc * 4);
  float* Kpi  = (float*)take((size_t)BHc * Sc * Dc * 4);
  float* sigV = (float*)take((size_t)BHc * Sc * WST * 4);
  // union region: Gram chunk partials (used first), then att (written after
  // gram_reduce has consumed the partials — stream order guarantees this).
  size_t partBytes = (size_t)BHc * NCHUNK * D1c * D1c * sizeof(double);
  size_t attBytes  = (size_t)BHc * Nc * D1c * 4;
  void* uni = take(partBytes > attBytes ? partBytes : attBytes);
  double* part = (double*)uni;
  float*  att  = (float*)uni;
  (void)ws_size; (void)in_sizes; (void)n_in; (void)out_size;

  hash_kernel<<<2 * BHc * Nc / 256, 256, 0, stream>>>(q, k, pd, hq, hk);
  sort_kernel<<<dim3(BHc, 2), 512, 0, stream>>>(hq, hk, qidx, kidx, qblk);
  gram_partial_kernel<<<BHc * NCHUNK, 256, 0, stream>>>(v, part);
  gram_reduce_kernel<<<(BHc * D1c * D1c + 255) / 256, 256, 0, stream>>>(part, gram);
  power_kernel<<<BHc, 128, 0, stream>>>(gram, pm, sigm);
  p_partial_kernel<<<BHc * 8, 256, 0, stream>>>(v, kidx, sigm, Pun, psum);
  p_final_kernel<<<BHc * Nc / 256, 256, 0, stream>>>(Pun, psum, P, logP);
  sample_kernel<<<BHc * Sc, 256, 0, stream>>>(logP, kidx, P, k, v, Kpi, sigV, sblk);
  sparse_kernel<<<BHc * NBc * 4, 256, 0, stream>>>(q, k, v, qidx, kidx, att);  // writes att (over part)
  residual_kernel<<<BHc * 64, 256, 0, stream>>>(q, Kpi, sigV, sblk, qblk, att, out);
}

// Round 8
// 1045.683 us; speedup vs baseline: 1.0274x; 1.0274x over previous
//
#include <hip/hip_runtime.h>
#include <stdint.h>
#include <math.h>

// ---------------------------------------------------------------------------
// CosineHammingAttention — bit-faithful HIP port of the JAX reference.
// B=2 H=8 N=4096 D=64, NUM_PROJS=7, BUCKET=256, SAMPLE=800, PM_ITERS=32
// R2: parallelize Gram.  R3: 64 rows x 4 chunks attention (occupancy fix).
// R5: __expf, sort fuses qblock, p split, sample fuses gather, f32 gram.
// R6: scalar compute loops (R5 float4-regs theory was wrong — same 88 VGPR).
// R7: __launch_bounds__(256,3) on sparse/residual: allocator was budgeting
//     88 VGPR (occupancy heuristic) < ~134 live -> no load-ahead ILP ->
//     lgkm stalls (VALU busy-time flat, wall +100us). Cap 512/3=170 VGPR.
// ---------------------------------------------------------------------------

typedef unsigned int u32;

namespace {
constexpr int Bc = 2, Hc = 8, BHc = 16;
constexpr int Nc = 4096, Dc = 64, D1c = 65;
constexpr int NBc = 16;      // N / BUCKET
constexpr int Sc = 800;      // SAMPLE
constexpr int PMITERc = 32;
constexpr int GCH = 128;             // Gram rows per chunk
constexpr int NCHUNK = Nc / GCH;     // 32
constexpr int WST = 68;              // padded sigV row stride (16B-aligned rows)
}

__device__ __forceinline__ u32 rotl32(u32 x, u32 d) { return (x << d) | (x >> (32u - d)); }

// Exact JAX threefry2x32 (20 rounds).
__device__ __forceinline__ void threefry2x32(u32 k0, u32 k1, u32 x0, u32 x1, u32& o0, u32& o1) {
  u32 ks2 = k0 ^ k1 ^ 0x1BD11BDAu;
  x0 += k0; x1 += k1;
#define TF_RND(r) { x0 += x1; x1 = rotl32(x1, r); x1 ^= x0; }
  TF_RND(13) TF_RND(15) TF_RND(26) TF_RND(6)
  x0 += k1; x1 += ks2 + 1u;
  TF_RND(17) TF_RND(29) TF_RND(16) TF_RND(24)
  x0 += ks2; x1 += k0 + 2u;
  TF_RND(13) TF_RND(15) TF_RND(26) TF_RND(6)
  x0 += k0; x1 += k1 + 3u;
  TF_RND(17) TF_RND(29) TF_RND(16) TF_RND(24)
  x0 += k1; x1 += ks2 + 4u;
  TF_RND(13) TF_RND(15) TF_RND(26) TF_RND(6)
  x0 += ks2; x1 += k0 + 5u;
#undef TF_RND
  o0 = x0; o1 = x1;
}

// gumbel sample for flat element i of the (800,16,4096) array, key = (0,1234)
// partitionable threefry: bits = out0 ^ out1 of counter (0, i)
__device__ __forceinline__ float gumbel_at(u32 i) {
  u32 o0, o1;
  threefry2x32(0u, 1234u, 0u, i, o0, o1);
  u32 bits = o0 ^ o1;
  u32 fb = (bits >> 9) | 0x3f800000u;
  float u = __uint_as_float(fb) - 1.0f;           // [0,1) on 2^-23 grid
  if (u == 0.0f) u = 1.1754944e-38f;              // max(tiny, u) per jax.random.uniform
  return -__logf(-__logf(u));
}

// ---- K1: LSH hash codes for q and k ---------------------------------------
__global__ __launch_bounds__(256) void hash_kernel(
    const float* __restrict__ q, const float* __restrict__ k,
    const float* __restrict__ pd, int* __restrict__ hq, int* __restrict__ hk) {
  int tid = blockIdx.x * 256 + threadIdx.x;
  int which = tid / (BHc * Nc);
  int rem = tid % (BHc * Nc);
  int bh = rem / Nc, n = rem % Nc;
  int b = bh / Hc, h = bh % Hc;
  const float* x = which ? k : q;
  const float* row = x + (((size_t)b * Nc + n) * Hc + h) * Dc;   // [B,N,H,D]
  const float* pdr = pd + (size_t)bh * Dc * 7;                   // [B,H,D,7]
  double acc[7];
#pragma unroll
  for (int r = 0; r < 7; r++) acc[r] = 0.0;
  for (int d = 0; d < Dc; d++) {
    double vv = (double)row[d];
    const float* pr = pdr + d * 7;
#pragma unroll
    for (int r = 0; r < 7; r++) acc[r] += vv * (double)pr[r];
  }
  int code = 0;
#pragma unroll
  for (int r = 0; r < 7; r++) code |= (acc[r] > 0.0) ? (1 << r) : 0;
  int hash = code ^ (code >> 1);   // _hamming_perm == binary-reflected Gray code
  (which ? hk : hq)[bh * Nc + n] = hash;
}

// ---- K2: stable counting sort, quarter-split; q-branch also writes qblk ---
__global__ __launch_bounds__(512) void sort_kernel(
    const int* __restrict__ hq, const int* __restrict__ hk,
    int* __restrict__ qidx, int* __restrict__ kidx, int* __restrict__ qblk) {
  __shared__ int sh[Nc];
  __shared__ int cnt[4][128];
  __shared__ int off[128];
  int bh = blockIdx.x;
  int which = blockIdx.y;
  const int* hash = which ? hk : hq;
  int* out = which ? kidx : qidx;
  int t = threadIdx.x;
  for (int i = t; i < Nc; i += 512) sh[i] = hash[bh * Nc + i];
  __syncthreads();
  int qr = t >> 7, b = t & 127;      // quarter, bin
  int c = 0;
  for (int i = qr * 1024; i < (qr + 1) * 1024; i++) c += (sh[i] == b);
  cnt[qr][b] = c;
  __syncthreads();
  if (t == 0) {
    int run = 0;
    for (int j = 0; j < 128; j++) {
      int tot = cnt[0][j] + cnt[1][j] + cnt[2][j] + cnt[3][j];
      off[j] = run; run += tot;
    }
  }
  __syncthreads();
  int o = off[b];
  for (int qq = 0; qq < qr; qq++) o += cnt[qq][b];
  for (int i = qr * 1024; i < (qr + 1) * 1024; i++)
    if (sh[i] == b) {
      out[bh * Nc + o] = i;
      if (which == 0) qblk[bh * Nc + i] = o >> 8;
      o++;
    }
}

// ---- K4: block-sparse attention, 64 rows x 4 key-chunks per block ---------
__global__ __launch_bounds__(256, 3) void sparse_kernel(
    const float* __restrict__ q, const float* __restrict__ k, const float* __restrict__ v,
    const int* __restrict__ qidx, const int* __restrict__ kidx, float* __restrict__ att) {
  __shared__ float S[8320];        // main: kb[64][64] | wb[64][64]; combine: 128*65
  float* kb = S;
  float* wb = S + 4096;
  int blk = blockIdx.x;
  int bh = blk >> 6;               // 64 blocks per bh
  int rem = blk & 63;
  int g = rem >> 2, qq = rem & 3;  // bucket, query-quadrant
  int b = bh / Hc, h = bh % Hc;
  int t = threadIdx.x;
  int r = t & 63, cid = t >> 6;
  int nq = qidx[bh * Nc + g * 256 + qq * 64 + r];
  const float* qrow = q + (((size_t)b * Nc + nq) * Hc + h) * Dc;
  float qreg[Dc];
#pragma unroll
  for (int d4 = 0; d4 < 16; d4++) {
    float4 f = ((const float4*)qrow)[d4];
    qreg[4 * d4] = f.x; qreg[4 * d4 + 1] = f.y; qreg[4 * d4 + 2] = f.z; qreg[4 * d4 + 3] = f.w;
  }
  float acc[D1c];
#pragma unroll
  for (int p = 0; p < D1c; p++) acc[p] = 0.f;
  const int* kidxB = kidx + bh * Nc + g * 256;
  for (int tile = 0; tile < 4; tile++) {
    for (int e4 = t; e4 < 64 * 16; e4 += 256) {
      int j = e4 >> 4, d4 = e4 & 15;
      int m = kidxB[tile * 64 + j];
      const float* kr = k + (((size_t)b * Nc + m) * Hc + h) * Dc;
      const float* vr = v + (((size_t)b * Nc + m) * Hc + h) * Dc;
      ((float4*)(kb + j * 64))[d4] = ((const float4*)kr)[d4];
      ((float4*)(wb + j * 64))[d4] = ((const float4*)vr)[d4];
    }
    __syncthreads();
    for (int jj = 0; jj < 16; jj++) {
      int j = cid * 16 + jj;
      float s0 = 0, s1 = 0, s2 = 0, s3 = 0;
      const float* kj = kb + j * 64;
#pragma unroll
      for (int d = 0; d < Dc; d += 4) {
        s0 += qreg[d] * kj[d];
        s1 += qreg[d + 1] * kj[d + 1];
        s2 += qreg[d + 2] * kj[d + 2];
        s3 += qreg[d + 3] * kj[d + 3];
      }
      float e_ = __expf((s0 + s1) + (s2 + s3));
      const float* wj = wb + j * 64;
#pragma unroll
      for (int p = 0; p < Dc; p++) acc[p] += e_ * wj[p];
      acc[Dc] += e_;               // v_aug's all-ones column
    }
    __syncthreads();
  }
  // tree-combine the 4 chunk partials (fixed order -> deterministic)
  if (t >= 128) { float* dst = S + (t - 128) * D1c;
#pragma unroll
    for (int p = 0; p < D1c; p++) dst[p] = acc[p]; }
  __syncthreads();
  if (t < 128) { const float* src = S + t * D1c;
#pragma unroll
    for (int p = 0; p < D1c; p++) acc[p] += src[p]; }
  __syncthreads();
  if (t >= 64 && t < 128) { float* dst = S + (t - 64) * D1c;
#pragma unroll
    for (int p = 0; p < D1c; p++) dst[p] = acc[p]; }
  __syncthreads();
  if (t < 64) {
    const float* src = S + t * D1c;
    float* arow = att + ((size_t)bh * Nc + nq) * D1c;   // scatter to original order
#pragma unroll
    for (int p = 0; p < D1c; p++) arow[p] = acc[p] + src[p];
  }
}

// ---- K5a: partial Gram over 128-row chunks (f32 accum, grid = BH*32) ------
__global__ __launch_bounds__(256) void gram_partial_kernel(
    const float* __restrict__ v, double* __restrict__ part) {
  __shared__ float ch[GCH][D1c];
  int bh = blockIdx.x / NCHUNK, c = blockIdx.x % NCHUNK;
  int b = bh / Hc, h = bh % Hc;
  int t = threadIdx.x;
  for (int e = t; e < GCH * D1c; e += 256) {
    int r = e / D1c, p = e % D1c;
    int n = c * GCH + r;
    ch[r][p] = (p < Dc) ? v[(((size_t)b * Nc + n) * Hc + h) * Dc + p] : 1.0f;
  }
  __syncthreads();
  for (int pi = t; pi < D1c * D1c; pi += 256) {
    int tt = pi / D1c, uu = pi % D1c;
    float a = 0.0f;
    for (int r = 0; r < GCH; r++) a += ch[r][tt] * ch[r][uu];
    part[((size_t)bh * NCHUNK + c) * (D1c * D1c) + pi] = (double)a;
  }
}

// ---- K5b: reduce chunk partials (fixed order -> deterministic) ------------
__global__ __launch_bounds__(256) void gram_reduce_kernel(
    const double* __restrict__ part, double* __restrict__ gram) {
  int idx = blockIdx.x * 256 + threadIdx.x;   // over BH * 4225
  if (idx >= BHc * D1c * D1c) return;
  int bh = idx / (D1c * D1c), pi = idx % (D1c * D1c);
  double s = 0.0;
  for (int c = 0; c < NCHUNK; c++)
    s += part[((size_t)bh * NCHUNK + c) * (D1c * D1c) + pi];
  gram[(size_t)bh * (D1c * D1c) + pi] = s;
}

// ---- K6: power method for spectral norm -----------------------------------
__global__ __launch_bounds__(128) void power_kernel(
    const double* __restrict__ gram, const float* __restrict__ pm, double* __restrict__ sigma) {
  __shared__ double G[D1c * D1c];
  __shared__ double x[D1c], y[D1c];
  __shared__ double nrm;
  int bh = blockIdx.x, t = threadIdx.x;
  for (int e = t; e < D1c * D1c; e += 128) G[e] = gram[(size_t)bh * D1c * D1c + e];
  if (t < D1c) x[t] = (double)pm[bh * D1c + t];
  __syncthreads();
  if (t == 0) {
    double s = 0; for (int i = 0; i < D1c; i++) s += x[i] * x[i];
    nrm = sqrt(s);
  }
  __syncthreads();
  if (t < D1c) x[t] /= nrm;
  for (int it = 0; it < PMITERc; it++) {
    __syncthreads();
    if (t < D1c) {
      double s = 0;
      for (int u = 0; u < D1c; u++) s += G[t * D1c + u] * x[u];
      y[t] = s;
    }
    __syncthreads();
    if (t == 0) {
      double s = 0; for (int i = 0; i < D1c; i++) s += y[i] * y[i];
      nrm = sqrt(s);
    }
    __syncthreads();
    if (t < D1c) x[t] = y[t] / nrm;
  }
  __syncthreads();
  if (t == 0) sigma[bh] = nrm;
}

// ---- K7a: unnormalized P + per-segment partial sums (grid = BH*8) ---------
__global__ __launch_bounds__(256) void p_partial_kernel(
    const float* __restrict__ v, const int* __restrict__ kidx,
    const double* __restrict__ sigma, double* __restrict__ Pun, double* __restrict__ psum) {
  __shared__ double red[256];
  int blk = blockIdx.x;
  int bh = blk >> 3, seg = blk & 7;
  int b = bh / Hc, h = bh % Hc;
  int t = threadIdx.x;
  double sg = sigma[bh];
  double part = 0.0;
  for (int n = seg * 512 + t; n < (seg + 1) * 512; n += 256) {
    int m = kidx[bh * Nc + n];
    const float* vr = v + (((size_t)b * Nc + m) * Hc + h) * Dc;
    double ss = 1.0;  // the appended 1.0 component of v_aug
    for (int d = 0; d < Dc; d++) { double vv = vr[d]; ss += vv * vv; }
    double Pd = sqrt(ss) / sg + (1.0 / (double)Nc);
    Pun[bh * Nc + n] = Pd;
    part += Pd;
  }
  red[t] = part;
  __syncthreads();
  for (int w = 128; w > 0; w >>= 1) {
    if (t < w) red[t] += red[t + w];
    __syncthreads();
  }
  if (t == 0) psum[blk] = red[0];
}

// ---- K7b: normalize + log -------------------------------------------------
__global__ __launch_bounds__(256) void p_final_kernel(
    const double* __restrict__ Pun, const double* __restrict__ psum,
    float* __restrict__ P, float* __restrict__ logP) {
  int idx = blockIdx.x * 256 + threadIdx.x;   // over BH*N
  int bh = idx / Nc;
  double tot = 0.0;
#pragma unroll
  for (int s = 0; s < 8; s++) tot += psum[bh * 8 + s];
  float Pf = (float)(Pun[idx] / tot);
  P[idx] = Pf;
  logP[idx] = logf(Pf);
}

// ---- K8: categorical sampling (argmax gumbel+logP) + fused gather ---------
__global__ __launch_bounds__(256) void sample_kernel(
    const float* __restrict__ logP, const int* __restrict__ kidx,
    const float* __restrict__ P, const float* __restrict__ key, const float* __restrict__ value,
    float* __restrict__ Kpi, float* __restrict__ sigV, int* __restrict__ sblk) {
  __shared__ float sv[256];
  __shared__ int si[256];
  int blk = blockIdx.x;           // bh*S + s
  int bh = blk / Sc, s = blk % Sc;
  int b = bh / Hc, h = bh % Hc;
  int t = threadIdx.x;
  float best = -3.4e38f; int besti = Nc;
  const float* lp = logP + bh * Nc;
  u32 base = ((u32)(s * BHc + bh)) * (u32)Nc;  // flat index into (800,16,4096)
  for (int n = t; n < Nc; n += 256) {
    float val = gumbel_at(base + (u32)n) + lp[n];
    if (val > best || (val == best && n < besti)) { best = val; besti = n; }
  }
  sv[t] = best; si[t] = besti;
  __syncthreads();
  for (int w = 128; w > 0; w >>= 1) {
    if (t < w) {
      float v2 = sv[t + w]; int i2 = si[t + w];
      if (v2 > sv[t] || (v2 == sv[t] && i2 < si[t])) { sv[t] = v2; si[t] = i2; }
    }
    __syncthreads();
  }
  int m = si[0];
  if (t == 0) sblk[blk] = m >> 8;
  int src = kidx[bh * Nc + m];
  float sg = 1.0f / (P[bh * Nc + m] * (float)Sc);
  const float* kr = key + (((size_t)b * Nc + src) * Hc + h) * Dc;
  const float* vr = value + (((size_t)b * Nc + src) * Hc + h) * Dc;
  if (t < Dc) Kpi[(size_t)blk * Dc + t] = kr[t];
  if (t < WST) sigV[(size_t)blk * WST + t] =
      (t < Dc) ? sg * vr[t] : ((t == Dc) ? sg : 0.0f);   // [65..67] = pad
}

// ---- K10: residual attention, 64 rows x 4 sample-chunks per block ---------
__global__ __launch_bounds__(256, 3) void residual_kernel(
    const float* __restrict__ q,
    const float* __restrict__ Kpi, const float* __restrict__ sigV, const int* __restrict__ sblk,
    const int* __restrict__ qblk, const float* __restrict__ att, float* __restrict__ out) {
  __shared__ float S[8448];        // main: kl[64][64] | wl[64][68]; combine: 128*65
  __shared__ int bl[64];
  float* kl = S;
  float* wl = S + 4096;
  int blk = blockIdx.x;
  int bh = blk >> 6;               // 64 row-groups per bh
  int n0 = (blk & 63) * 64;
  int b = bh / Hc, h = bh % Hc;
  int t = threadIdx.x;
  int r = t & 63, cid = t >> 6;
  int n = n0 + r;
  const float* qrow = q + (((size_t)b * Nc + n) * Hc + h) * Dc;
  float qreg[Dc];
#pragma unroll
  for (int d4 = 0; d4 < 16; d4++) {
    float4 f = ((const float4*)qrow)[d4];
    qreg[4 * d4] = f.x; qreg[4 * d4 + 1] = f.y; qreg[4 * d4 + 2] = f.z; qreg[4 * d4 + 3] = f.w;
  }
  int myblk = qblk[bh * Nc + n];
  float acc[D1c];
#pragma unroll
  for (int p = 0; p < D1c; p++) acc[p] = 0.f;
  const float* KpiB = Kpi + (size_t)bh * Sc * Dc;
  const float* sigVB = sigV + (size_t)bh * Sc * WST;
  const int* sblkB = sblk + bh * Sc;
  for (int tile = 0; tile < 13; tile++) {       // 12 tiles of 64 + tail 32
    int base = tile * 64;
    int cnt = (tile < 12) ? 64 : 32;
    for (int e4 = t; e4 < cnt * 16; e4 += 256)     // kl: flat float4 copy
      ((float4*)kl)[e4] = ((const float4*)(KpiB + (size_t)base * Dc))[e4];
    for (int e4 = t; e4 < cnt * 17; e4 += 256)     // wl: flat float4 copy (stride 68)
      ((float4*)wl)[e4] = ((const float4*)(sigVB + (size_t)base * WST))[e4];
    if (t < cnt) bl[t] = sblkB[base + t];
    __syncthreads();
    int per = cnt >> 2;
    for (int jj = 0; jj < per; jj++) {
      int j = cid * per + jj;
      float s0 = 0, s1 = 0, s2 = 0, s3 = 0;
      const float* kj = kl + j * 64;
#pragma unroll
      for (int d = 0; d < Dc; d += 4) {
        s0 += qreg[d] * kj[d];
        s1 += qreg[d + 1] * kj[d + 1];
        s2 += qreg[d + 2] * kj[d + 2];
        s3 += qreg[d + 3] * kj[d + 3];
      }
      float e_ = __expf((s0 + s1) + (s2 + s3));
      float w = (bl[j] == myblk) ? 0.0f : e_;    // mask: sample in query's own block
      const float* wj = wl + j * WST;
#pragma unroll
      for (int p = 0; p < D1c; p++) acc[p] += w * wj[p];
    }
    __syncthreads();
  }
  // tree-combine the 4 chunk partials (fixed order -> deterministic)
  if (t >= 128) { float* dst = S + (t - 128) * D1c;
#pragma unroll
    for (int p = 0; p < D1c; p++) dst[p] = acc[p]; }
  __syncthreads();
  if (t < 128) { const float* src = S + t * D1c;
#pragma unroll
    for (int p = 0; p < D1c; p++) acc[p] += src[p]; }
  __syncthreads();
  if (t >= 64 && t < 128) { float* dst = S + (t - 64) * D1c;
#pragma unroll
    for (int p = 0; p < D1c; p++) dst[p] = acc[p]; }
  __syncthreads();
  if (t < 64) {
    const float* src = S + t * D1c;
#pragma unroll
    for (int p = 0; p < D1c; p++) acc[p] += src[p];
    const float* arow = att + ((size_t)bh * Nc + n) * D1c;
    float denom = arow[Dc] + acc[Dc];
    float* orow = out + ((size_t)bh * Nc + n) * Dc;
#pragma unroll
    for (int d = 0; d < Dc; d++) orow[d] = (arow[d] + acc[d]) / denom;
  }
}

// ---------------------------------------------------------------------------
extern "C" void kernel_launch(void* const* d_in, const int* in_sizes, int n_in,
                              void* d_out, int out_size, void* d_ws, size_t ws_size,
                              hipStream_t stream) {
  const float* q  = (const float*)d_in[0];
  const float* k  = (const float*)d_in[1];
  const float* v  = (const float*)d_in[2];
  const float* pd = (const float*)d_in[3];
  const float* pm = (const float*)d_in[4];
  float* out = (float*)d_out;

  char* w = (char*)d_ws;
  size_t off = 0;
  auto take = [&](size_t nbytes) -> void* {
    void* p = w + off;
    off += (nbytes + 255) & ~(size_t)255;
    return p;
  };
  double* gram = (double*)take((size_t)BHc * D1c * D1c * sizeof(double));
  double* sigm = (double*)take((size_t)BHc * sizeof(double));
  double* Pun  = (double*)take((size_t)BHc * Nc * sizeof(double));
  double* psum = (double*)take((size_t)BHc * 8 * sizeof(double));
  int* hq   = (int*)take((size_t)BHc * Nc * 4);
  int* hk   = (int*)take((size_t)BHc * Nc * 4);
  int* qidx = (int*)take((size_t)BHc * Nc * 4);
  int* kidx = (int*)take((size_t)BHc * Nc * 4);
  int* qblk = (int*)take((size_t)BHc * Nc * 4);
  float* P    = (float*)take((size_t)BHc * Nc * 4);
  float* logP = (float*)take((size_t)BHc * Nc * 4);
  int* sblk = (int*)take((size_t)BHc * Sc * 4);
  float* Kpi  = (float*)take((size_t)BHc * Sc * Dc * 4);
  float* sigV = (float*)take((size_t)BHc * Sc * WST * 4);
  // union region: Gram chunk partials (used first), then att (written after
  // gram_reduce has consumed the partials — stream order guarantees this).
  size_t partBytes = (size_t)BHc * NCHUNK * D1c * D1c * sizeof(double);
  size_t attBytes  = (size_t)BHc * Nc * D1c * 4;
  void* uni = take(partBytes > attBytes ? partBytes : attBytes);
  double* part = (double*)uni;
  float*  att  = (float*)uni;
  (void)ws_size; (void)in_sizes; (void)n_in; (void)out_size;

  hash_kernel<<<2 * BHc * Nc / 256, 256, 0, stream>>>(q, k, pd, hq, hk);
  sort_kernel<<<dim3(BHc, 2), 512, 0, stream>>>(hq, hk, qidx, kidx, qblk);
  gram_partial_kernel<<<BHc * NCHUNK, 256, 0, stream>>>(v, part);
  gram_reduce_kernel<<<(BHc * D1c * D1c + 255) / 256, 256, 0, stream>>>(part, gram);
  power_kernel<<<BHc, 128, 0, stream>>>(gram, pm, sigm);
  p_partial_kernel<<<BHc * 8, 256, 0, stream>>>(v, kidx, sigm, Pun, psum);
  p_final_kernel<<<BHc * Nc / 256, 256, 0, stream>>>(Pun, psum, P, logP);
  sample_kernel<<<BHc * Sc, 256, 0, stream>>>(logP, kidx, P, k, v, Kpi, sigV, sblk);
  sparse_kernel<<<BHc * NBc * 4, 256, 0, stream>>>(q, k, v, qidx, kidx, att);  // writes att (over part)
  residual_kernel<<<BHc * 64, 256, 0, stream>>>(q, Kpi, sigV, sblk, qblk, att, out);
}

// Round 9
// 959.841 us; speedup vs baseline: 1.1193x; 1.0894x over previous
//
#include <hip/hip_runtime.h>
#include <stdint.h>
#include <math.h>

// ---------------------------------------------------------------------------
// CosineHammingAttention — bit-faithful HIP port of the JAX reference.
// B=2 H=8 N=4096 D=64, NUM_PROJS=7, BUCKET=256, SAMPLE=800, PM_ITERS=32
// R2: parallelize Gram.  R3: 64 rows x 4 chunks attention (occupancy fix).
// R5: __expf, sort fuses qblock, p split, sample fuses gather, f32 gram.
// R6/R7: 129-float live set (qreg[64]+acc[65]) always spills (VGPR 84-88,
//     +6MB scratch WRITE_SIZE); launch_bounds didn't change allocator choice.
// R8: split-D/split-P — lane pairs share a row: qreg[32] + acc[33] per
//     thread, dot completed via __shfl_xor(partial,1); 2 sample-chunks.
//     Per-thread MACs unchanged; live set ~80 regs -> no spill.
// ---------------------------------------------------------------------------

typedef unsigned int u32;

namespace {
constexpr int Bc = 2, Hc = 8, BHc = 16;
constexpr int Nc = 4096, Dc = 64, D1c = 65;
constexpr int NBc = 16;      // N / BUCKET
constexpr int Sc = 800;      // SAMPLE
constexpr int PMITERc = 32;
constexpr int GCH = 128;             // Gram rows per chunk
constexpr int NCHUNK = Nc / GCH;     // 32
constexpr int WST = 68;              // padded sigV row stride (16B-aligned rows)
}

__device__ __forceinline__ u32 rotl32(u32 x, u32 d) { return (x << d) | (x >> (32u - d)); }

// Exact JAX threefry2x32 (20 rounds).
__device__ __forceinline__ void threefry2x32(u32 k0, u32 k1, u32 x0, u32 x1, u32& o0, u32& o1) {
  u32 ks2 = k0 ^ k1 ^ 0x1BD11BDAu;
  x0 += k0; x1 += k1;
#define TF_RND(r) { x0 += x1; x1 = rotl32(x1, r); x1 ^= x0; }
  TF_RND(13) TF_RND(15) TF_RND(26) TF_RND(6)
  x0 += k1; x1 += ks2 + 1u;
  TF_RND(17) TF_RND(29) TF_RND(16) TF_RND(24)
  x0 += ks2; x1 += k0 + 2u;
  TF_RND(13) TF_RND(15) TF_RND(26) TF_RND(6)
  x0 += k0; x1 += k1 + 3u;
  TF_RND(17) TF_RND(29) TF_RND(16) TF_RND(24)
  x0 += k1; x1 += ks2 + 4u;
  TF_RND(13) TF_RND(15) TF_RND(26) TF_RND(6)
  x0 += ks2; x1 += k0 + 5u;
#undef TF_RND
  o0 = x0; o1 = x1;
}

// gumbel sample for flat element i of the (800,16,4096) array, key = (0,1234)
// partitionable threefry: bits = out0 ^ out1 of counter (0, i)
__device__ __forceinline__ float gumbel_at(u32 i) {
  u32 o0, o1;
  threefry2x32(0u, 1234u, 0u, i, o0, o1);
  u32 bits = o0 ^ o1;
  u32 fb = (bits >> 9) | 0x3f800000u;
  float u = __uint_as_float(fb) - 1.0f;           // [0,1) on 2^-23 grid
  if (u == 0.0f) u = 1.1754944e-38f;              // max(tiny, u) per jax.random.uniform
  return -__logf(-__logf(u));
}

// ---- K1: LSH hash codes for q and k ---------------------------------------
__global__ __launch_bounds__(256) void hash_kernel(
    const float* __restrict__ q, const float* __restrict__ k,
    const float* __restrict__ pd, int* __restrict__ hq, int* __restrict__ hk) {
  int tid = blockIdx.x * 256 + threadIdx.x;
  int which = tid / (BHc * Nc);
  int rem = tid % (BHc * Nc);
  int bh = rem / Nc, n = rem % Nc;
  int b = bh / Hc, h = bh % Hc;
  const float* x = which ? k : q;
  const float* row = x + (((size_t)b * Nc + n) * Hc + h) * Dc;   // [B,N,H,D]
  const float* pdr = pd + (size_t)bh * Dc * 7;                   // [B,H,D,7]
  double acc[7];
#pragma unroll
  for (int r = 0; r < 7; r++) acc[r] = 0.0;
  for (int d = 0; d < Dc; d++) {
    double vv = (double)row[d];
    const float* pr = pdr + d * 7;
#pragma unroll
    for (int r = 0; r < 7; r++) acc[r] += vv * (double)pr[r];
  }
  int code = 0;
#pragma unroll
  for (int r = 0; r < 7; r++) code |= (acc[r] > 0.0) ? (1 << r) : 0;
  int hash = code ^ (code >> 1);   // _hamming_perm == binary-reflected Gray code
  (which ? hk : hq)[bh * Nc + n] = hash;
}

// ---- K2: stable counting sort, quarter-split; q-branch also writes qblk ---
__global__ __launch_bounds__(512) void sort_kernel(
    const int* __restrict__ hq, const int* __restrict__ hk,
    int* __restrict__ qidx, int* __restrict__ kidx, int* __restrict__ qblk) {
  __shared__ int sh[Nc];
  __shared__ int cnt[4][128];
  __shared__ int off[128];
  int bh = blockIdx.x;
  int which = blockIdx.y;
  const int* hash = which ? hk : hq;
  int* out = which ? kidx : qidx;
  int t = threadIdx.x;
  for (int i = t; i < Nc; i += 512) sh[i] = hash[bh * Nc + i];
  __syncthreads();
  int qr = t >> 7, b = t & 127;      // quarter, bin
  int c = 0;
  for (int i = qr * 1024; i < (qr + 1) * 1024; i++) c += (sh[i] == b);
  cnt[qr][b] = c;
  __syncthreads();
  if (t == 0) {
    int run = 0;
    for (int j = 0; j < 128; j++) {
      int tot = cnt[0][j] + cnt[1][j] + cnt[2][j] + cnt[3][j];
      off[j] = run; run += tot;
    }
  }
  __syncthreads();
  int o = off[b];
  for (int qq = 0; qq < qr; qq++) o += cnt[qq][b];
  for (int i = qr * 1024; i < (qr + 1) * 1024; i++)
    if (sh[i] == b) {
      out[bh * Nc + o] = i;
      if (which == 0) qblk[bh * Nc + i] = o >> 8;
      o++;
    }
}

// ---- K4: block-sparse attention, split-D lane pairs, 2 key-chunks ---------
__global__ __launch_bounds__(256, 4) void sparse_kernel(
    const float* __restrict__ q, const float* __restrict__ k, const float* __restrict__ v,
    const int* __restrict__ qidx, const int* __restrict__ kidx, float* __restrict__ att) {
  __shared__ float S[8320];        // main: kb[64][64] | wb[64][64]; combine: 128*33
  float* kb = S;
  float* wb = S + 4096;
  int blk = blockIdx.x;
  int bh = blk >> 6;               // 64 blocks per bh
  int rem = blk & 63;
  int g = rem >> 2, qq = rem & 3;  // bucket, query-quadrant
  int b = bh / Hc, h = bh % Hc;
  int t = threadIdx.x;
  int half = t & 1;                // d/p half (lane pairs: 2r, 2r+1)
  int row = (t >> 1) & 63;         // query row within the 64-row group
  int chunk = t >> 7;              // key sub-chunk (0/1)
  int p0 = half * 32;
  int nq = qidx[bh * Nc + g * 256 + qq * 64 + row];
  const float* qrow = q + (((size_t)b * Nc + nq) * Hc + h) * Dc + p0;
  float qreg[32];
#pragma unroll
  for (int d4 = 0; d4 < 8; d4++) {
    float4 f = ((const float4*)qrow)[d4];
    qreg[4 * d4] = f.x; qreg[4 * d4 + 1] = f.y; qreg[4 * d4 + 2] = f.z; qreg[4 * d4 + 3] = f.w;
  }
  float acc[33];                   // p = p0 .. p0+32
#pragma unroll
  for (int i = 0; i < 33; i++) acc[i] = 0.f;
  const int* kidxB = kidx + bh * Nc + g * 256;
  for (int tile = 0; tile < 4; tile++) {
    for (int e4 = t; e4 < 64 * 16; e4 += 256) {
      int j = e4 >> 4, d4 = e4 & 15;
      int m = kidxB[tile * 64 + j];
      const float* kr = k + (((size_t)b * Nc + m) * Hc + h) * Dc;
      const float* vr = v + (((size_t)b * Nc + m) * Hc + h) * Dc;
      ((float4*)(kb + j * 64))[d4] = ((const float4*)kr)[d4];
      ((float4*)(wb + j * 64))[d4] = ((const float4*)vr)[d4];
    }
    __syncthreads();
    for (int jj = 0; jj < 32; jj++) {
      int j = chunk * 32 + jj;
      float s0 = 0, s1 = 0, s2 = 0, s3 = 0;
      const float* kj = kb + j * 64 + p0;
#pragma unroll
      for (int d = 0; d < 32; d += 4) {
        s0 += qreg[d] * kj[d];
        s1 += qreg[d + 1] * kj[d + 1];
        s2 += qreg[d + 2] * kj[d + 2];
        s3 += qreg[d + 3] * kj[d + 3];
      }
      float sp = (s0 + s1) + (s2 + s3);
      float dot = sp + __shfl_xor(sp, 1);   // pair lane completes the 64-dim dot
      float e_ = __expf(dot);
      const float* wj = wb + j * 64;
#pragma unroll
      for (int i = 0; i < 32; i++) acc[i] += e_ * wj[p0 + i];
      acc[32] += e_ * (half ? 1.0f : wj[32]);   // half1's p=64 is the ones column
    }
    __syncthreads();
  }
  // combine the 2 chunk partials (fixed order -> deterministic)
  if (t >= 128) {
    float* dst = S + (t - 128) * 33;
#pragma unroll
    for (int i = 0; i < 33; i++) dst[i] = acc[i];
  }
  __syncthreads();
  if (t < 128) {
    const float* src = S + t * 33;
#pragma unroll
    for (int i = 0; i < 33; i++) acc[i] += src[i];
    float* arow = att + ((size_t)bh * Nc + nq) * D1c;   // scatter to original order
    if (half == 0) {
#pragma unroll
      for (int i = 0; i < 32; i++) arow[i] = acc[i];    // p 0..31
    } else {
#pragma unroll
      for (int i = 0; i < 33; i++) arow[32 + i] = acc[i];  // p 32..64
    }
  }
}

// ---- K5a: partial Gram over 128-row chunks (f32 accum, grid = BH*32) ------
__global__ __launch_bounds__(256) void gram_partial_kernel(
    const float* __restrict__ v, double* __restrict__ part) {
  __shared__ float ch[GCH][D1c];
  int bh = blockIdx.x / NCHUNK, c = blockIdx.x % NCHUNK;
  int b = bh / Hc, h = bh % Hc;
  int t = threadIdx.x;
  for (int e = t; e < GCH * D1c; e += 256) {
    int r = e / D1c, p = e % D1c;
    int n = c * GCH + r;
    ch[r][p] = (p < Dc) ? v[(((size_t)b * Nc + n) * Hc + h) * Dc + p] : 1.0f;
  }
  __syncthreads();
  for (int pi = t; pi < D1c * D1c; pi += 256) {
    int tt = pi / D1c, uu = pi % D1c;
    float a = 0.0f;
    for (int r = 0; r < GCH; r++) a += ch[r][tt] * ch[r][uu];
    part[((size_t)bh * NCHUNK + c) * (D1c * D1c) + pi] = (double)a;
  }
}

// ---- K5b: reduce chunk partials (fixed order -> deterministic) ------------
__global__ __launch_bounds__(256) void gram_reduce_kernel(
    const double* __restrict__ part, double* __restrict__ gram) {
  int idx = blockIdx.x * 256 + threadIdx.x;   // over BH * 4225
  if (idx >= BHc * D1c * D1c) return;
  int bh = idx / (D1c * D1c), pi = idx % (D1c * D1c);
  double s = 0.0;
  for (int c = 0; c < NCHUNK; c++)
    s += part[((size_t)bh * NCHUNK + c) * (D1c * D1c) + pi];
  gram[(size_t)bh * (D1c * D1c) + pi] = s;
}

// ---- K6: power method for spectral norm -----------------------------------
__global__ __launch_bounds__(128) void power_kernel(
    const double* __restrict__ gram, const float* __restrict__ pm, double* __restrict__ sigma) {
  __shared__ double G[D1c * D1c];
  __shared__ double x[D1c], y[D1c];
  __shared__ double nrm;
  int bh = blockIdx.x, t = threadIdx.x;
  for (int e = t; e < D1c * D1c; e += 128) G[e] = gram[(size_t)bh * D1c * D1c + e];
  if (t < D1c) x[t] = (double)pm[bh * D1c + t];
  __syncthreads();
  if (t == 0) {
    double s = 0; for (int i = 0; i < D1c; i++) s += x[i] * x[i];
    nrm = sqrt(s);
  }
  __syncthreads();
  if (t < D1c) x[t] /= nrm;
  for (int it = 0; it < PMITERc; it++) {
    __syncthreads();
    if (t < D1c) {
      double s = 0;
      for (int u = 0; u < D1c; u++) s += G[t * D1c + u] * x[u];
      y[t] = s;
    }
    __syncthreads();
    if (t == 0) {
      double s = 0; for (int i = 0; i < D1c; i++) s += y[i] * y[i];
      nrm = sqrt(s);
    }
    __syncthreads();
    if (t < D1c) x[t] = y[t] / nrm;
  }
  __syncthreads();
  if (t == 0) sigma[bh] = nrm;
}

// ---- K7a: unnormalized P + per-segment partial sums (grid = BH*8) ---------
__global__ __launch_bounds__(256) void p_partial_kernel(
    const float* __restrict__ v, const int* __restrict__ kidx,
    const double* __restrict__ sigma, double* __restrict__ Pun, double* __restrict__ psum) {
  __shared__ double red[256];
  int blk = blockIdx.x;
  int bh = blk >> 3, seg = blk & 7;
  int b = bh / Hc, h = bh % Hc;
  int t = threadIdx.x;
  double sg = sigma[bh];
  double part = 0.0;
  for (int n = seg * 512 + t; n < (seg + 1) * 512; n += 256) {
    int m = kidx[bh * Nc + n];
    const float* vr = v + (((size_t)b * Nc + m) * Hc + h) * Dc;
    double ss = 1.0;  // the appended 1.0 component of v_aug
    for (int d = 0; d < Dc; d++) { double vv = vr[d]; ss += vv * vv; }
    double Pd = sqrt(ss) / sg + (1.0 / (double)Nc);
    Pun[bh * Nc + n] = Pd;
    part += Pd;
  }
  red[t] = part;
  __syncthreads();
  for (int w = 128; w > 0; w >>= 1) {
    if (t < w) red[t] += red[t + w];
    __syncthreads();
  }
  if (t == 0) psum[blk] = red[0];
}

// ---- K7b: normalize + log -------------------------------------------------
__global__ __launch_bounds__(256) void p_final_kernel(
    const double* __restrict__ Pun, const double* __restrict__ psum,
    float* __restrict__ P, float* __restrict__ logP) {
  int idx = blockIdx.x * 256 + threadIdx.x;   // over BH*N
  int bh = idx / Nc;
  double tot = 0.0;
#pragma unroll
  for (int s = 0; s < 8; s++) tot += psum[bh * 8 + s];
  float Pf = (float)(Pun[idx] / tot);
  P[idx] = Pf;
  logP[idx] = logf(Pf);
}

// ---- K8: categorical sampling (argmax gumbel+logP) + fused gather ---------
__global__ __launch_bounds__(256) void sample_kernel(
    const float* __restrict__ logP, const int* __restrict__ kidx,
    const float* __restrict__ P, const float* __restrict__ key, const float* __restrict__ value,
    float* __restrict__ Kpi, float* __restrict__ sigV, int* __restrict__ sblk) {
  __shared__ float sv[256];
  __shared__ int si[256];
  int blk = blockIdx.x;           // bh*S + s
  int bh = blk / Sc, s = blk % Sc;
  int b = bh / Hc, h = bh % Hc;
  int t = threadIdx.x;
  float best = -3.4e38f; int besti = Nc;
  const float* lp = logP + bh * Nc;
  u32 base = ((u32)(s * BHc + bh)) * (u32)Nc;  // flat index into (800,16,4096)
  for (int n = t; n < Nc; n += 256) {
    float val = gumbel_at(base + (u32)n) + lp[n];
    if (val > best || (val == best && n < besti)) { best = val; besti = n; }
  }
  sv[t] = best; si[t] = besti;
  __syncthreads();
  for (int w = 128; w > 0; w >>= 1) {
    if (t < w) {
      float v2 = sv[t + w]; int i2 = si[t + w];
      if (v2 > sv[t] || (v2 == sv[t] && i2 < si[t])) { sv[t] = v2; si[t] = i2; }
    }
    __syncthreads();
  }
  int m = si[0];
  if (t == 0) sblk[blk] = m >> 8;
  int src = kidx[bh * Nc + m];
  float sg = 1.0f / (P[bh * Nc + m] * (float)Sc);
  const float* kr = key + (((size_t)b * Nc + src) * Hc + h) * Dc;
  const float* vr = value + (((size_t)b * Nc + src) * Hc + h) * Dc;
  if (t < Dc) Kpi[(size_t)blk * Dc + t] = kr[t];
  if (t < WST) sigV[(size_t)blk * WST + t] =
      (t < Dc) ? sg * vr[t] : ((t == Dc) ? sg : 0.0f);   // [65..67] = pad
}

// ---- K10: residual attention, split-D lane pairs, 2 sample-chunks ---------
__global__ __launch_bounds__(256, 4) void residual_kernel(
    const float* __restrict__ q,
    const float* __restrict__ Kpi, const float* __restrict__ sigV, const int* __restrict__ sblk,
    const int* __restrict__ qblk, const float* __restrict__ att, float* __restrict__ out) {
  __shared__ float S[8448];        // main: kl[64][64] | wl[64][68]; combine: 128*33
  __shared__ int bl[64];
  float* kl = S;
  float* wl = S + 4096;
  int blk = blockIdx.x;
  int bh = blk >> 6;               // 64 row-groups per bh
  int n0 = (blk & 63) * 64;
  int b = bh / Hc, h = bh % Hc;
  int t = threadIdx.x;
  int half = t & 1;                // d/p half (lane pairs: 2r, 2r+1)
  int row = (t >> 1) & 63;         // query row within group
  int chunk = t >> 7;              // sample sub-chunk (0/1)
  int p0 = half * 32;
  int n = n0 + row;
  const float* qrow = q + (((size_t)b * Nc + n) * Hc + h) * Dc + p0;
  float qreg[32];
#pragma unroll
  for (int d4 = 0; d4 < 8; d4++) {
    float4 f = ((const float4*)qrow)[d4];
    qreg[4 * d4] = f.x; qreg[4 * d4 + 1] = f.y; qreg[4 * d4 + 2] = f.z; qreg[4 * d4 + 3] = f.w;
  }
  int myblk = qblk[bh * Nc + n];
  float acc[33];                   // p = p0 .. p0+32 (half1's p=64 is sig col)
#pragma unroll
  for (int i = 0; i < 33; i++) acc[i] = 0.f;
  const float* KpiB = Kpi + (size_t)bh * Sc * Dc;
  const float* sigVB = sigV + (size_t)bh * Sc * WST;
  const int* sblkB = sblk + bh * Sc;
  for (int tile = 0; tile < 13; tile++) {       // 12 tiles of 64 + tail 32
    int base = tile * 64;
    int cnt = (tile < 12) ? 64 : 32;
    for (int e4 = t; e4 < cnt * 16; e4 += 256)     // kl: flat float4 copy
      ((float4*)kl)[e4] = ((const float4*)(KpiB + (size_t)base * Dc))[e4];
    for (int e4 = t; e4 < cnt * 17; e4 += 256)     // wl: flat float4 copy (stride 68)
      ((float4*)wl)[e4] = ((const float4*)(sigVB + (size_t)base * WST))[e4];
    if (t < cnt) bl[t] = sblkB[base + t];
    __syncthreads();
    int per = cnt >> 1;
    for (int jj = 0; jj < per; jj++) {
      int j = chunk * per + jj;
      float s0 = 0, s1 = 0, s2 = 0, s3 = 0;
      const float* kj = kl + j * 64 + p0;
#pragma unroll
      for (int d = 0; d < 32; d += 4) {
        s0 += qreg[d] * kj[d];
        s1 += qreg[d + 1] * kj[d + 1];
        s2 += qreg[d + 2] * kj[d + 2];
        s3 += qreg[d + 3] * kj[d + 3];
      }
      float sp = (s0 + s1) + (s2 + s3);
      float dot = sp + __shfl_xor(sp, 1);   // pair lane completes the 64-dim dot
      float e_ = __expf(dot);
      float w = (bl[j] == myblk) ? 0.0f : e_;    // mask: sample in query's own block
      const float* wj = wl + j * WST + p0;
#pragma unroll
      for (int i = 0; i < 33; i++) acc[i] += w * wj[i];   // half1 i=32 -> p=64 (sig)
    }
    __syncthreads();
  }
  // combine the 2 chunk partials (fixed order -> deterministic)
  if (t >= 128) {
    float* dst = S + (t - 128) * 33;
#pragma unroll
    for (int i = 0; i < 33; i++) dst[i] = acc[i];
  }
  __syncthreads();
  if (t < 128) {
    const float* src = S + t * 33;
#pragma unroll
    for (int i = 0; i < 33; i++) acc[i] += src[i];
    const float* arow = att + ((size_t)bh * Nc + n) * D1c;
    float dloc = arow[64] + acc[32];          // valid denominator only on half1
    float doth = __shfl_xor(dloc, 1);
    float denom = half ? dloc : doth;
    float* orow = out + ((size_t)bh * Nc + n) * Dc + p0;
    if (half == 0) {
#pragma unroll
      for (int i = 0; i < 32; i++) orow[i] = (arow[i] + acc[i]) / denom;
    } else {
#pragma unroll
      for (int i = 0; i < 32; i++) orow[i] = (arow[32 + i] + acc[i]) / denom;
    }
  }
}

// ---------------------------------------------------------------------------
extern "C" void kernel_launch(void* const* d_in, const int* in_sizes, int n_in,
                              void* d_out, int out_size, void* d_ws, size_t ws_size,
                              hipStream_t stream) {
  const float* q  = (const float*)d_in[0];
  const float* k  = (const float*)d_in[1];
  const float* v  = (const float*)d_in[2];
  const float* pd = (const float*)d_in[3];
  const float* pm = (const float*)d_in[4];
  float* out = (float*)d_out;

  char* w = (char*)d_ws;
  size_t off = 0;
  auto take = [&](size_t nbytes) -> void* {
    void* p = w + off;
    off += (nbytes + 255) & ~(size_t)255;
    return p;
  };
  double* gram = (double*)take((size_t)BHc * D1c * D1c * sizeof(double));
  double* sigm = (double*)take((size_t)BHc * sizeof(double));
  double* Pun  = (double*)take((size_t)BHc * Nc * sizeof(double));
  double* psum = (double*)take((size_t)BHc * 8 * sizeof(double));
  int* hq   = (int*)take((size_t)BHc * Nc * 4);
  int* hk   = (int*)take((size_t)BHc * Nc * 4);
  int* qidx = (int*)take((size_t)BHc * Nc * 4);
  int* kidx = (int*)take((size_t)BHc * Nc * 4);
  int* qblk = (int*)take((size_t)BHc * Nc * 4);
  float* P    = (float*)take((size_t)BHc * Nc * 4);
  float* logP = (float*)take((size_t)BHc * Nc * 4);
  int* sblk = (int*)take((size_t)BHc * Sc * 4);
  float* Kpi  = (float*)take((size_t)BHc * Sc * Dc * 4);
  float* sigV = (float*)take((size_t)BHc * Sc * WST * 4);
  // union region: Gram chunk partials (used first), then att (written after
  // gram_reduce has consumed the partials — stream order guarantees this).
  size_t partBytes = (size_t)BHc * NCHUNK * D1c * D1c * sizeof(double);
  size_t attBytes  = (size_t)BHc * Nc * D1c * 4;
  void* uni = take(partBytes > attBytes ? partBytes : attBytes);
  double* part = (double*)uni;
  float*  att  = (float*)uni;
  (void)ws_size; (void)in_sizes; (void)n_in; (void)out_size;

  hash_kernel<<<2 * BHc * Nc / 256, 256, 0, stream>>>(q, k, pd, hq, hk);
  sort_kernel<<<dim3(BHc, 2), 512, 0, stream>>>(hq, hk, qidx, kidx, qblk);
  gram_partial_kernel<<<BHc * NCHUNK, 256, 0, stream>>>(v, part);
  gram_reduce_kernel<<<(BHc * D1c * D1c + 255) / 256, 256, 0, stream>>>(part, gram);
  power_kernel<<<BHc, 128, 0, stream>>>(gram, pm, sigm);
  p_partial_kernel<<<BHc * 8, 256, 0, stream>>>(v, kidx, sigm, Pun, psum);
  p_final_kernel<<<BHc * Nc / 256, 256, 0, stream>>>(Pun, psum, P, logP);
  sample_kernel<<<BHc * Sc, 256, 0, stream>>>(logP, kidx, P, k, v, Kpi, sigV, sblk);
  sparse_kernel<<<BHc * NBc * 4, 256, 0, stream>>>(q, k, v, qidx, kidx, att);  // writes att (over part)
  residual_kernel<<<BHc * 64, 256, 0, stream>>>(q, Kpi, sigV, sblk, qblk, att, out);
}

// Round 10
// 959.828 us; speedup vs baseline: 1.1193x; 1.0000x over previous
//
#include <hip/hip_runtime.h>
#include <stdint.h>
#include <math.h>

// ---------------------------------------------------------------------------
// CosineHammingAttention — bit-faithful HIP port of the JAX reference.
// B=2 H=8 N=4096 D=64, NUM_PROJS=7, BUCKET=256, SAMPLE=800, PM_ITERS=32
// R2: parallelize Gram.  R3: 64 rows x 4 chunks attention (occupancy fix).
// R5: __expf, sort fuses qblock, p split, sample fuses gather, f32 gram.
// R8: split-D/split-P lane pairs (qreg[32]+acc[33], shfl_xor dot) — 388us.
// R9: amdgpu_waves_per_eu(4,4) on sparse/residual: R8 still spilled ~16
//     values (VGPR=64 targeting 8 waves/SIMD, but LDS caps at 4; WRITE_SIZE
//     20.5MB vs 16.4MB output = scratch traffic). max=4 -> 128-VGPR budget.
// ---------------------------------------------------------------------------

typedef unsigned int u32;

namespace {
constexpr int Bc = 2, Hc = 8, BHc = 16;
constexpr int Nc = 4096, Dc = 64, D1c = 65;
constexpr int NBc = 16;      // N / BUCKET
constexpr int Sc = 800;      // SAMPLE
constexpr int PMITERc = 32;
constexpr int GCH = 128;             // Gram rows per chunk
constexpr int NCHUNK = Nc / GCH;     // 32
constexpr int WST = 68;              // padded sigV row stride (16B-aligned rows)
}

__device__ __forceinline__ u32 rotl32(u32 x, u32 d) { return (x << d) | (x >> (32u - d)); }

// Exact JAX threefry2x32 (20 rounds).
__device__ __forceinline__ void threefry2x32(u32 k0, u32 k1, u32 x0, u32 x1, u32& o0, u32& o1) {
  u32 ks2 = k0 ^ k1 ^ 0x1BD11BDAu;
  x0 += k0; x1 += k1;
#define TF_RND(r) { x0 += x1; x1 = rotl32(x1, r); x1 ^= x0; }
  TF_RND(13) TF_RND(15) TF_RND(26) TF_RND(6)
  x0 += k1; x1 += ks2 + 1u;
  TF_RND(17) TF_RND(29) TF_RND(16) TF_RND(24)
  x0 += ks2; x1 += k0 + 2u;
  TF_RND(13) TF_RND(15) TF_RND(26) TF_RND(6)
  x0 += k0; x1 += k1 + 3u;
  TF_RND(17) TF_RND(29) TF_RND(16) TF_RND(24)
  x0 += k1; x1 += ks2 + 4u;
  TF_RND(13) TF_RND(15) TF_RND(26) TF_RND(6)
  x0 += ks2; x1 += k0 + 5u;
#undef TF_RND
  o0 = x0; o1 = x1;
}

// gumbel sample for flat element i of the (800,16,4096) array, key = (0,1234)
// partitionable threefry: bits = out0 ^ out1 of counter (0, i)
__device__ __forceinline__ float gumbel_at(u32 i) {
  u32 o0, o1;
  threefry2x32(0u, 1234u, 0u, i, o0, o1);
  u32 bits = o0 ^ o1;
  u32 fb = (bits >> 9) | 0x3f800000u;
  float u = __uint_as_float(fb) - 1.0f;           // [0,1) on 2^-23 grid
  if (u == 0.0f) u = 1.1754944e-38f;              // max(tiny, u) per jax.random.uniform
  return -__logf(-__logf(u));
}

// ---- K1: LSH hash codes for q and k ---------------------------------------
__global__ __launch_bounds__(256) void hash_kernel(
    const float* __restrict__ q, const float* __restrict__ k,
    const float* __restrict__ pd, int* __restrict__ hq, int* __restrict__ hk) {
  int tid = blockIdx.x * 256 + threadIdx.x;
  int which = tid / (BHc * Nc);
  int rem = tid % (BHc * Nc);
  int bh = rem / Nc, n = rem % Nc;
  int b = bh / Hc, h = bh % Hc;
  const float* x = which ? k : q;
  const float* row = x + (((size_t)b * Nc + n) * Hc + h) * Dc;   // [B,N,H,D]
  const float* pdr = pd + (size_t)bh * Dc * 7;                   // [B,H,D,7]
  double acc[7];
#pragma unroll
  for (int r = 0; r < 7; r++) acc[r] = 0.0;
  for (int d = 0; d < Dc; d++) {
    double vv = (double)row[d];
    const float* pr = pdr + d * 7;
#pragma unroll
    for (int r = 0; r < 7; r++) acc[r] += vv * (double)pr[r];
  }
  int code = 0;
#pragma unroll
  for (int r = 0; r < 7; r++) code |= (acc[r] > 0.0) ? (1 << r) : 0;
  int hash = code ^ (code >> 1);   // _hamming_perm == binary-reflected Gray code
  (which ? hk : hq)[bh * Nc + n] = hash;
}

// ---- K2: stable counting sort, quarter-split; q-branch also writes qblk ---
__global__ __launch_bounds__(512) void sort_kernel(
    const int* __restrict__ hq, const int* __restrict__ hk,
    int* __restrict__ qidx, int* __restrict__ kidx, int* __restrict__ qblk) {
  __shared__ int sh[Nc];
  __shared__ int cnt[4][128];
  __shared__ int off[128];
  int bh = blockIdx.x;
  int which = blockIdx.y;
  const int* hash = which ? hk : hq;
  int* out = which ? kidx : qidx;
  int t = threadIdx.x;
  for (int i = t; i < Nc; i += 512) sh[i] = hash[bh * Nc + i];
  __syncthreads();
  int qr = t >> 7, b = t & 127;      // quarter, bin
  int c = 0;
  for (int i = qr * 1024; i < (qr + 1) * 1024; i++) c += (sh[i] == b);
  cnt[qr][b] = c;
  __syncthreads();
  if (t == 0) {
    int run = 0;
    for (int j = 0; j < 128; j++) {
      int tot = cnt[0][j] + cnt[1][j] + cnt[2][j] + cnt[3][j];
      off[j] = run; run += tot;
    }
  }
  __syncthreads();
  int o = off[b];
  for (int qq = 0; qq < qr; qq++) o += cnt[qq][b];
  for (int i = qr * 1024; i < (qr + 1) * 1024; i++)
    if (sh[i] == b) {
      out[bh * Nc + o] = i;
      if (which == 0) qblk[bh * Nc + i] = o >> 8;
      o++;
    }
}

// ---- K4: block-sparse attention, split-D lane pairs, 2 key-chunks ---------
__global__ __launch_bounds__(256)
__attribute__((amdgpu_waves_per_eu(4, 4)))
void sparse_kernel(
    const float* __restrict__ q, const float* __restrict__ k, const float* __restrict__ v,
    const int* __restrict__ qidx, const int* __restrict__ kidx, float* __restrict__ att) {
  __shared__ float S[8320];        // main: kb[64][64] | wb[64][64]; combine: 128*33
  float* kb = S;
  float* wb = S + 4096;
  int blk = blockIdx.x;
  int bh = blk >> 6;               // 64 blocks per bh
  int rem = blk & 63;
  int g = rem >> 2, qq = rem & 3;  // bucket, query-quadrant
  int b = bh / Hc, h = bh % Hc;
  int t = threadIdx.x;
  int half = t & 1;                // d/p half (lane pairs: 2r, 2r+1)
  int row = (t >> 1) & 63;         // query row within the 64-row group
  int chunk = t >> 7;              // key sub-chunk (0/1)
  int p0 = half * 32;
  int nq = qidx[bh * Nc + g * 256 + qq * 64 + row];
  const float* qrow = q + (((size_t)b * Nc + nq) * Hc + h) * Dc + p0;
  float qreg[32];
#pragma unroll
  for (int d4 = 0; d4 < 8; d4++) {
    float4 f = ((const float4*)qrow)[d4];
    qreg[4 * d4] = f.x; qreg[4 * d4 + 1] = f.y; qreg[4 * d4 + 2] = f.z; qreg[4 * d4 + 3] = f.w;
  }
  float acc[33];                   // p = p0 .. p0+32
#pragma unroll
  for (int i = 0; i < 33; i++) acc[i] = 0.f;
  const int* kidxB = kidx + bh * Nc + g * 256;
  for (int tile = 0; tile < 4; tile++) {
    for (int e4 = t; e4 < 64 * 16; e4 += 256) {
      int j = e4 >> 4, d4 = e4 & 15;
      int m = kidxB[tile * 64 + j];
      const float* kr = k + (((size_t)b * Nc + m) * Hc + h) * Dc;
      const float* vr = v + (((size_t)b * Nc + m) * Hc + h) * Dc;
      ((float4*)(kb + j * 64))[d4] = ((const float4*)kr)[d4];
      ((float4*)(wb + j * 64))[d4] = ((const float4*)vr)[d4];
    }
    __syncthreads();
    for (int jj = 0; jj < 32; jj++) {
      int j = chunk * 32 + jj;
      float s0 = 0, s1 = 0, s2 = 0, s3 = 0;
      const float* kj = kb + j * 64 + p0;
#pragma unroll
      for (int d = 0; d < 32; d += 4) {
        s0 += qreg[d] * kj[d];
        s1 += qreg[d + 1] * kj[d + 1];
        s2 += qreg[d + 2] * kj[d + 2];
        s3 += qreg[d + 3] * kj[d + 3];
      }
      float sp = (s0 + s1) + (s2 + s3);
      float dot = sp + __shfl_xor(sp, 1);   // pair lane completes the 64-dim dot
      float e_ = __expf(dot);
      const float* wj = wb + j * 64;
#pragma unroll
      for (int i = 0; i < 32; i++) acc[i] += e_ * wj[p0 + i];
      acc[32] += e_ * (half ? 1.0f : wj[32]);   // half1's p=64 is the ones column
    }
    __syncthreads();
  }
  // combine the 2 chunk partials (fixed order -> deterministic)
  if (t >= 128) {
    float* dst = S + (t - 128) * 33;
#pragma unroll
    for (int i = 0; i < 33; i++) dst[i] = acc[i];
  }
  __syncthreads();
  if (t < 128) {
    const float* src = S + t * 33;
#pragma unroll
    for (int i = 0; i < 33; i++) acc[i] += src[i];
    float* arow = att + ((size_t)bh * Nc + nq) * D1c;   // scatter to original order
    if (half == 0) {
#pragma unroll
      for (int i = 0; i < 32; i++) arow[i] = acc[i];    // p 0..31
    } else {
#pragma unroll
      for (int i = 0; i < 33; i++) arow[32 + i] = acc[i];  // p 32..64
    }
  }
}

// ---- K5a: partial Gram over 128-row chunks (f32 accum, grid = BH*32) ------
__global__ __launch_bounds__(256) void gram_partial_kernel(
    const float* __restrict__ v, double* __restrict__ part) {
  __shared__ float ch[GCH][D1c];
  int bh = blockIdx.x / NCHUNK, c = blockIdx.x % NCHUNK;
  int b = bh / Hc, h = bh % Hc;
  int t = threadIdx.x;
  for (int e = t; e < GCH * D1c; e += 256) {
    int r = e / D1c, p = e % D1c;
    int n = c * GCH + r;
    ch[r][p] = (p < Dc) ? v[(((size_t)b * Nc + n) * Hc + h) * Dc + p] : 1.0f;
  }
  __syncthreads();
  for (int pi = t; pi < D1c * D1c; pi += 256) {
    int tt = pi / D1c, uu = pi % D1c;
    float a = 0.0f;
    for (int r = 0; r < GCH; r++) a += ch[r][tt] * ch[r][uu];
    part[((size_t)bh * NCHUNK + c) * (D1c * D1c) + pi] = (double)a;
  }
}

// ---- K5b: reduce chunk partials (fixed order -> deterministic) ------------
__global__ __launch_bounds__(256) void gram_reduce_kernel(
    const double* __restrict__ part, double* __restrict__ gram) {
  int idx = blockIdx.x * 256 + threadIdx.x;   // over BH * 4225
  if (idx >= BHc * D1c * D1c) return;
  int bh = idx / (D1c * D1c), pi = idx % (D1c * D1c);
  double s = 0.0;
  for (int c = 0; c < NCHUNK; c++)
    s += part[((size_t)bh * NCHUNK + c) * (D1c * D1c) + pi];
  gram[(size_t)bh * (D1c * D1c) + pi] = s;
}

// ---- K6: power method for spectral norm -----------------------------------
__global__ __launch_bounds__(128) void power_kernel(
    const double* __restrict__ gram, const float* __restrict__ pm, double* __restrict__ sigma) {
  __shared__ double G[D1c * D1c];
  __shared__ double x[D1c], y[D1c];
  __shared__ double nrm;
  int bh = blockIdx.x, t = threadIdx.x;
  for (int e = t; e < D1c * D1c; e += 128) G[e] = gram[(size_t)bh * D1c * D1c + e];
  if (t < D1c) x[t] = (double)pm[bh * D1c + t];
  __syncthreads();
  if (t == 0) {
    double s = 0; for (int i = 0; i < D1c; i++) s += x[i] * x[i];
    nrm = sqrt(s);
  }
  __syncthreads();
  if (t < D1c) x[t] /= nrm;
  for (int it = 0; it < PMITERc; it++) {
    __syncthreads();
    if (t < D1c) {
      double s = 0;
      for (int u = 0; u < D1c; u++) s += G[t * D1c + u] * x[u];
      y[t] = s;
    }
    __syncthreads();
    if (t == 0) {
      double s = 0; for (int i = 0; i < D1c; i++) s += y[i] * y[i];
      nrm = sqrt(s);
    }
    __syncthreads();
    if (t < D1c) x[t] = y[t] / nrm;
  }
  __syncthreads();
  if (t == 0) sigma[bh] = nrm;
}

// ---- K7a: unnormalized P + per-segment partial sums (grid = BH*8) ---------
__global__ __launch_bounds__(256) void p_partial_kernel(
    const float* __restrict__ v, const int* __restrict__ kidx,
    const double* __restrict__ sigma, double* __restrict__ Pun, double* __restrict__ psum) {
  __shared__ double red[256];
  int blk = blockIdx.x;
  int bh = blk >> 3, seg = blk & 7;
  int b = bh / Hc, h = bh % Hc;
  int t = threadIdx.x;
  double sg = sigma[bh];
  double part = 0.0;
  for (int n = seg * 512 + t; n < (seg + 1) * 512; n += 256) {
    int m = kidx[bh * Nc + n];
    const float* vr = v + (((size_t)b * Nc + m) * Hc + h) * Dc;
    double ss = 1.0;  // the appended 1.0 component of v_aug
    for (int d = 0; d < Dc; d++) { double vv = vr[d]; ss += vv * vv; }
    double Pd = sqrt(ss) / sg + (1.0 / (double)Nc);
    Pun[bh * Nc + n] = Pd;
    part += Pd;
  }
  red[t] = part;
  __syncthreads();
  for (int w = 128; w > 0; w >>= 1) {
    if (t < w) red[t] += red[t + w];
    __syncthreads();
  }
  if (t == 0) psum[blk] = red[0];
}

// ---- K7b: normalize + log -------------------------------------------------
__global__ __launch_bounds__(256) void p_final_kernel(
    const double* __restrict__ Pun, const double* __restrict__ psum,
    float* __restrict__ P, float* __restrict__ logP) {
  int idx = blockIdx.x * 256 + threadIdx.x;   // over BH*N
  int bh = idx / Nc;
  double tot = 0.0;
#pragma unroll
  for (int s = 0; s < 8; s++) tot += psum[bh * 8 + s];
  float Pf = (float)(Pun[idx] / tot);
  P[idx] = Pf;
  logP[idx] = logf(Pf);
}

// ---- K8: categorical sampling (argmax gumbel+logP) + fused gather ---------
__global__ __launch_bounds__(256) void sample_kernel(
    const float* __restrict__ logP, const int* __restrict__ kidx,
    const float* __restrict__ P, const float* __restrict__ key, const float* __restrict__ value,
    float* __restrict__ Kpi, float* __restrict__ sigV, int* __restrict__ sblk) {
  __shared__ float sv[256];
  __shared__ int si[256];
  int blk = blockIdx.x;           // bh*S + s
  int bh = blk / Sc, s = blk % Sc;
  int b = bh / Hc, h = bh % Hc;
  int t = threadIdx.x;
  float best = -3.4e38f; int besti = Nc;
  const float* lp = logP + bh * Nc;
  u32 base = ((u32)(s * BHc + bh)) * (u32)Nc;  // flat index into (800,16,4096)
  for (int n = t; n < Nc; n += 256) {
    float val = gumbel_at(base + (u32)n) + lp[n];
    if (val > best || (val == best && n < besti)) { best = val; besti = n; }
  }
  sv[t] = best; si[t] = besti;
  __syncthreads();
  for (int w = 128; w > 0; w >>= 1) {
    if (t < w) {
      float v2 = sv[t + w]; int i2 = si[t + w];
      if (v2 > sv[t] || (v2 == sv[t] && i2 < si[t])) { sv[t] = v2; si[t] = i2; }
    }
    __syncthreads();
  }
  int m = si[0];
  if (t == 0) sblk[blk] = m >> 8;
  int src = kidx[bh * Nc + m];
  float sg = 1.0f / (P[bh * Nc + m] * (float)Sc);
  const float* kr = key + (((size_t)b * Nc + src) * Hc + h) * Dc;
  const float* vr = value + (((size_t)b * Nc + src) * Hc + h) * Dc;
  if (t < Dc) Kpi[(size_t)blk * Dc + t] = kr[t];
  if (t < WST) sigV[(size_t)blk * WST + t] =
      (t < Dc) ? sg * vr[t] : ((t == Dc) ? sg : 0.0f);   // [65..67] = pad
}

// ---- K10: residual attention, split-D lane pairs, 2 sample-chunks ---------
__global__ __launch_bounds__(256)
__attribute__((amdgpu_waves_per_eu(4, 4)))
void residual_kernel(
    const float* __restrict__ q,
    const float* __restrict__ Kpi, const float* __restrict__ sigV, const int* __restrict__ sblk,
    const int* __restrict__ qblk, const float* __restrict__ att, float* __restrict__ out) {
  __shared__ float S[8448];        // main: kl[64][64] | wl[64][68]; combine: 128*33
  __shared__ int bl[64];
  float* kl = S;
  float* wl = S + 4096;
  int blk = blockIdx.x;
  int bh = blk >> 6;               // 64 row-groups per bh
  int n0 = (blk & 63) * 64;
  int b = bh / Hc, h = bh % Hc;
  int t = threadIdx.x;
  int half = t & 1;                // d/p half (lane pairs: 2r, 2r+1)
  int row = (t >> 1) & 63;         // query row within group
  int chunk = t >> 7;              // sample sub-chunk (0/1)
  int p0 = half * 32;
  int n = n0 + row;
  const float* qrow = q + (((size_t)b * Nc + n) * Hc + h) * Dc + p0;
  float qreg[32];
#pragma unroll
  for (int d4 = 0; d4 < 8; d4++) {
    float4 f = ((const float4*)qrow)[d4];
    qreg[4 * d4] = f.x; qreg[4 * d4 + 1] = f.y; qreg[4 * d4 + 2] = f.z; qreg[4 * d4 + 3] = f.w;
  }
  int myblk = qblk[bh * Nc + n];
  float acc[33];                   // p = p0 .. p0+32 (half1's p=64 is sig col)
#pragma unroll
  for (int i = 0; i < 33; i++) acc[i] = 0.f;
  const float* KpiB = Kpi + (size_t)bh * Sc * Dc;
  const float* sigVB = sigV + (size_t)bh * Sc * WST;
  const int* sblkB = sblk + bh * Sc;
  for (int tile = 0; tile < 13; tile++) {       // 12 tiles of 64 + tail 32
    int base = tile * 64;
    int cnt = (tile < 12) ? 64 : 32;
    for (int e4 = t; e4 < cnt * 16; e4 += 256)     // kl: flat float4 copy
      ((float4*)kl)[e4] = ((const float4*)(KpiB + (size_t)base * Dc))[e4];
    for (int e4 = t; e4 < cnt * 17; e4 += 256)     // wl: flat float4 copy (stride 68)
      ((float4*)wl)[e4] = ((const float4*)(sigVB + (size_t)base * WST))[e4];
    if (t < cnt) bl[t] = sblkB[base + t];
    __syncthreads();
    int per = cnt >> 1;
    for (int jj = 0; jj < per; jj++) {
      int j = chunk * per + jj;
      float s0 = 0, s1 = 0, s2 = 0, s3 = 0;
      const float* kj = kl + j * 64 + p0;
#pragma unroll
      for (int d = 0; d < 32; d += 4) {
        s0 += qreg[d] * kj[d];
        s1 += qreg[d + 1] * kj[d + 1];
        s2 += qreg[d + 2] * kj[d + 2];
        s3 += qreg[d + 3] * kj[d + 3];
      }
      float sp = (s0 + s1) + (s2 + s3);
      float dot = sp + __shfl_xor(sp, 1);   // pair lane completes the 64-dim dot
      float e_ = __expf(dot);
      float w = (bl[j] == myblk) ? 0.0f : e_;    // mask: sample in query's own block
      const float* wj = wl + j * WST + p0;
#pragma unroll
      for (int i = 0; i < 33; i++) acc[i] += w * wj[i];   // half1 i=32 -> p=64 (sig)
    }
    __syncthreads();
  }
  // combine the 2 chunk partials (fixed order -> deterministic)
  if (t >= 128) {
    float* dst = S + (t - 128) * 33;
#pragma unroll
    for (int i = 0; i < 33; i++) dst[i] = acc[i];
  }
  __syncthreads();
  if (t < 128) {
    const float* src = S + t * 33;
#pragma unroll
    for (int i = 0; i < 33; i++) acc[i] += src[i];
    const float* arow = att + ((size_t)bh * Nc + n) * D1c;
    float dloc = arow[64] + acc[32];          // valid denominator only on half1
    float doth = __shfl_xor(dloc, 1);
    float denom = half ? dloc : doth;
    float* orow = out + ((size_t)bh * Nc + n) * Dc + p0;
    if (half == 0) {
#pragma unroll
      for (int i = 0; i < 32; i++) orow[i] = (arow[i] + acc[i]) / denom;
    } else {
#pragma unroll
      for (int i = 0; i < 32; i++) orow[i] = (arow[32 + i] + acc[i]) / denom;
    }
  }
}

// ---------------------------------------------------------------------------
extern "C" void kernel_launch(void* const* d_in, const int* in_sizes, int n_in,
                              void* d_out, int out_size, void* d_ws, size_t ws_size,
                              hipStream_t stream) {
  const float* q  = (const float*)d_in[0];
  const float* k  = (const float*)d_in[1];
  const float* v  = (const float*)d_in[2];
  const float* pd = (const float*)d_in[3];
  const float* pm = (const float*)d_in[4];
  float* out = (float*)d_out;

  char* w = (char*)d_ws;
  size_t off = 0;
  auto take = [&](size_t nbytes) -> void* {
    void* p = w + off;
    off += (nbytes + 255) & ~(size_t)255;
    return p;
  };
  double* gram = (double*)take((size_t)BHc * D1c * D1c * sizeof(double));
  double* sigm = (double*)take((size_t)BHc * sizeof(double));
  double* Pun  = (double*)take((size_t)BHc * Nc * sizeof(double));
  double* psum = (double*)take((size_t)BHc * 8 * sizeof(double));
  int* hq   = (int*)take((size_t)BHc * Nc * 4);
  int* hk   = (int*)take((size_t)BHc * Nc * 4);
  int* qidx = (int*)take((size_t)BHc * Nc * 4);
  int* kidx = (int*)take((size_t)BHc * Nc * 4);
  int* qblk = (int*)take((size_t)BHc * Nc * 4);
  float* P    = (float*)take((size_t)BHc * Nc * 4);
  float* logP = (float*)take((size_t)BHc * Nc * 4);
  int* sblk = (int*)take((size_t)BHc * Sc * 4);
  float* Kpi  = (float*)take((size_t)BHc * Sc * Dc * 4);
  float* sigV = (float*)take((size_t)BHc * Sc * WST * 4);
  // union region: Gram chunk partials (used first), then att (written after
  // gram_reduce has consumed the partials — stream order guarantees this).
  size_t partBytes = (size_t)BHc * NCHUNK * D1c * D1c * sizeof(double);
  size_t attBytes  = (size_t)BHc * Nc * D1c * 4;
  void* uni = take(partBytes > attBytes ? partBytes : attBytes);
  double* part = (double*)uni;
  float*  att  = (float*)uni;
  (void)ws_size; (void)in_sizes; (void)n_in; (void)out_size;

  hash_kernel<<<2 * BHc * Nc / 256, 256, 0, stream>>>(q, k, pd, hq, hk);
  sort_kernel<<<dim3(BHc, 2), 512, 0, stream>>>(hq, hk, qidx, kidx, qblk);
  gram_partial_kernel<<<BHc * NCHUNK, 256, 0, stream>>>(v, part);
  gram_reduce_kernel<<<(BHc * D1c * D1c + 255) / 256, 256, 0, stream>>>(part, gram);
  power_kernel<<<BHc, 128, 0, stream>>>(gram, pm, sigm);
  p_partial_kernel<<<BHc * 8, 256, 0, stream>>>(v, kidx, sigm, Pun, psum);
  p_final_kernel<<<BHc * Nc / 256, 256, 0, stream>>>(Pun, psum, P, logP);
  sample_kernel<<<BHc * Sc, 256, 0, stream>>>(logP, kidx, P, k, v, Kpi, sigV, sblk);
  sparse_kernel<<<BHc * NBc * 4, 256, 0, stream>>>(q, k, v, qidx, kidx, att);  // writes att (over part)
  residual_kernel<<<BHc * 64, 256, 0, stream>>>(q, Kpi, sigV, sblk, qblk, att, out);
}

// Round 11
// 869.125 us; speedup vs baseline: 1.2361x; 1.1044x over previous
//
#include <hip/hip_runtime.h>
#include <stdint.h>
#include <math.h>

// ---------------------------------------------------------------------------
// CosineHammingAttention — bit-faithful HIP port of the JAX reference.
// B=2 H=8 N=4096 D=64, NUM_PROJS=7, BUCKET=256, SAMPLE=800, PM_ITERS=32
// R2: parallelize Gram.  R3: 64 rows x 4 chunks attention (occupancy fix).
// R5: __expf, sort fuses qblock, p split, sample fuses gather, f32 gram.
// R8: split-D lane pairs — 388us. R9: waves_per_eu inert; spill small.
// R10: residual is AT the LDS-read BW roofline for ratio-1 blocking
//     (65 LDS floats per 65 FMAs; 27GB LDS reads ~= 347-520us analytic).
//     Eighth-split x 2-row register tiles: 8 lanes/row-pair, each thread
//     owns 8-wide D-slice + 8(9)-wide P-slice of TWO rows -> each LDS read
//     feeds 2 FMAs (traffic halves); dot via 3x shfl_xor; live set ~45
//     regs (no spill); no chunk-combine phase.
// ---------------------------------------------------------------------------

typedef unsigned int u32;

namespace {
constexpr int Bc = 2, Hc = 8, BHc = 16;
constexpr int Nc = 4096, Dc = 64, D1c = 65;
constexpr int NBc = 16;      // N / BUCKET
constexpr int Sc = 800;      // SAMPLE
constexpr int PMITERc = 32;
constexpr int GCH = 128;             // Gram rows per chunk
constexpr int NCHUNK = Nc / GCH;     // 32
constexpr int WST = 68;              // padded sigV row stride (16B-aligned rows)
}

__device__ __forceinline__ u32 rotl32(u32 x, u32 d) { return (x << d) | (x >> (32u - d)); }

// Exact JAX threefry2x32 (20 rounds).
__device__ __forceinline__ void threefry2x32(u32 k0, u32 k1, u32 x0, u32 x1, u32& o0, u32& o1) {
  u32 ks2 = k0 ^ k1 ^ 0x1BD11BDAu;
  x0 += k0; x1 += k1;
#define TF_RND(r) { x0 += x1; x1 = rotl32(x1, r); x1 ^= x0; }
  TF_RND(13) TF_RND(15) TF_RND(26) TF_RND(6)
  x0 += k1; x1 += ks2 + 1u;
  TF_RND(17) TF_RND(29) TF_RND(16) TF_RND(24)
  x0 += ks2; x1 += k0 + 2u;
  TF_RND(13) TF_RND(15) TF_RND(26) TF_RND(6)
  x0 += k0; x1 += k1 + 3u;
  TF_RND(17) TF_RND(29) TF_RND(16) TF_RND(24)
  x0 += k1; x1 += ks2 + 4u;
  TF_RND(13) TF_RND(15) TF_RND(26) TF_RND(6)
  x0 += ks2; x1 += k0 + 5u;
#undef TF_RND
  o0 = x0; o1 = x1;
}

// gumbel sample for flat element i of the (800,16,4096) array, key = (0,1234)
// partitionable threefry: bits = out0 ^ out1 of counter (0, i)
__device__ __forceinline__ float gumbel_at(u32 i) {
  u32 o0, o1;
  threefry2x32(0u, 1234u, 0u, i, o0, o1);
  u32 bits = o0 ^ o1;
  u32 fb = (bits >> 9) | 0x3f800000u;
  float u = __uint_as_float(fb) - 1.0f;           // [0,1) on 2^-23 grid
  if (u == 0.0f) u = 1.1754944e-38f;              // max(tiny, u) per jax.random.uniform
  return -__logf(-__logf(u));
}

// ---- K1: LSH hash codes for q and k ---------------------------------------
__global__ __launch_bounds__(256) void hash_kernel(
    const float* __restrict__ q, const float* __restrict__ k,
    const float* __restrict__ pd, int* __restrict__ hq, int* __restrict__ hk) {
  int tid = blockIdx.x * 256 + threadIdx.x;
  int which = tid / (BHc * Nc);
  int rem = tid % (BHc * Nc);
  int bh = rem / Nc, n = rem % Nc;
  int b = bh / Hc, h = bh % Hc;
  const float* x = which ? k : q;
  const float* row = x + (((size_t)b * Nc + n) * Hc + h) * Dc;   // [B,N,H,D]
  const float* pdr = pd + (size_t)bh * Dc * 7;                   // [B,H,D,7]
  double acc[7];
#pragma unroll
  for (int r = 0; r < 7; r++) acc[r] = 0.0;
  for (int d = 0; d < Dc; d++) {
    double vv = (double)row[d];
    const float* pr = pdr + d * 7;
#pragma unroll
    for (int r = 0; r < 7; r++) acc[r] += vv * (double)pr[r];
  }
  int code = 0;
#pragma unroll
  for (int r = 0; r < 7; r++) code |= (acc[r] > 0.0) ? (1 << r) : 0;
  int hash = code ^ (code >> 1);   // _hamming_perm == binary-reflected Gray code
  (which ? hk : hq)[bh * Nc + n] = hash;
}

// ---- K2: stable counting sort, quarter-split; q-branch also writes qblk ---
__global__ __launch_bounds__(512) void sort_kernel(
    const int* __restrict__ hq, const int* __restrict__ hk,
    int* __restrict__ qidx, int* __restrict__ kidx, int* __restrict__ qblk) {
  __shared__ int sh[Nc];
  __shared__ int cnt[4][128];
  __shared__ int off[128];
  int bh = blockIdx.x;
  int which = blockIdx.y;
  const int* hash = which ? hk : hq;
  int* out = which ? kidx : qidx;
  int t = threadIdx.x;
  for (int i = t; i < Nc; i += 512) sh[i] = hash[bh * Nc + i];
  __syncthreads();
  int qr = t >> 7, b = t & 127;      // quarter, bin
  int c = 0;
  for (int i = qr * 1024; i < (qr + 1) * 1024; i++) c += (sh[i] == b);
  cnt[qr][b] = c;
  __syncthreads();
  if (t == 0) {
    int run = 0;
    for (int j = 0; j < 128; j++) {
      int tot = cnt[0][j] + cnt[1][j] + cnt[2][j] + cnt[3][j];
      off[j] = run; run += tot;
    }
  }
  __syncthreads();
  int o = off[b];
  for (int qq = 0; qq < qr; qq++) o += cnt[qq][b];
  for (int i = qr * 1024; i < (qr + 1) * 1024; i++)
    if (sh[i] == b) {
      out[bh * Nc + o] = i;
      if (which == 0) qblk[bh * Nc + i] = o >> 8;
      o++;
    }
}

// ---- K4: block-sparse attention, eighth-split 2-row register tiles --------
__global__ __launch_bounds__(256) void sparse_kernel(
    const float* __restrict__ q, const float* __restrict__ k, const float* __restrict__ v,
    const int* __restrict__ qidx, const int* __restrict__ kidx, float* __restrict__ att) {
  __shared__ float S[8192];        // kb[64][64] | wb[64][64]
  float* kb = S;
  float* wb = S + 4096;
  int blk = blockIdx.x;
  int bh = blk >> 6;               // 64 blocks per bh
  int rem = blk & 63;
  int g = rem >> 2, qq = rem & 3;  // bucket, query-quadrant
  int b = bh / Hc, h = bh % Hc;
  int t = threadIdx.x;
  int le = t & 7;                  // D-/P-eighth
  int rp = t >> 3;                 // row pair 0..31
  int e0 = le * 8;
  int nq0 = qidx[bh * Nc + g * 256 + qq * 64 + rp * 2];
  int nq1 = qidx[bh * Nc + g * 256 + qq * 64 + rp * 2 + 1];
  const float* q0 = q + (((size_t)b * Nc + nq0) * Hc + h) * Dc + e0;
  const float* q1 = q + (((size_t)b * Nc + nq1) * Hc + h) * Dc + e0;
  float qa[8], qb[8];
  {
    float4 f0 = ((const float4*)q0)[0], f1 = ((const float4*)q0)[1];
    qa[0] = f0.x; qa[1] = f0.y; qa[2] = f0.z; qa[3] = f0.w;
    qa[4] = f1.x; qa[5] = f1.y; qa[6] = f1.z; qa[7] = f1.w;
    float4 g0 = ((const float4*)q1)[0], g1 = ((const float4*)q1)[1];
    qb[0] = g0.x; qb[1] = g0.y; qb[2] = g0.z; qb[3] = g0.w;
    qb[4] = g1.x; qb[5] = g1.y; qb[6] = g1.z; qb[7] = g1.w;
  }
  float acc0[9], acc1[9];
#pragma unroll
  for (int i = 0; i < 9; i++) { acc0[i] = 0.f; acc1[i] = 0.f; }
  const int* kidxB = kidx + bh * Nc + g * 256;
  for (int tile = 0; tile < 4; tile++) {
    for (int e4 = t; e4 < 64 * 16; e4 += 256) {
      int j = e4 >> 4, d4 = e4 & 15;
      int m = kidxB[tile * 64 + j];
      const float* kr = k + (((size_t)b * Nc + m) * Hc + h) * Dc;
      const float* vr = v + (((size_t)b * Nc + m) * Hc + h) * Dc;
      ((float4*)(kb + j * 64))[d4] = ((const float4*)kr)[d4];
      ((float4*)(wb + j * 64))[d4] = ((const float4*)vr)[d4];
    }
    __syncthreads();
    for (int j = 0; j < 64; j++) {
      const float* kj = kb + j * 64 + e0;
      float4 k0 = ((const float4*)kj)[0], k1 = ((const float4*)kj)[1];
      float s0 = qa[0] * k0.x + qa[1] * k0.y + qa[2] * k0.z + qa[3] * k0.w
               + qa[4] * k1.x + qa[5] * k1.y + qa[6] * k1.z + qa[7] * k1.w;
      float s1 = qb[0] * k0.x + qb[1] * k0.y + qb[2] * k0.z + qb[3] * k0.w
               + qb[4] * k1.x + qb[5] * k1.y + qb[6] * k1.z + qb[7] * k1.w;
      s0 += __shfl_xor(s0, 1); s0 += __shfl_xor(s0, 2); s0 += __shfl_xor(s0, 4);
      s1 += __shfl_xor(s1, 1); s1 += __shfl_xor(s1, 2); s1 += __shfl_xor(s1, 4);
      float e_0 = __expf(s0), e_1 = __expf(s1);
      const float* wj = wb + j * 64 + e0;
      float4 w0 = ((const float4*)wj)[0], w1 = ((const float4*)wj)[1];
      float w8 = (le == 7) ? 1.0f : wj[8];   // col 64 is the implicit ones column
      acc0[0] += e_0 * w0.x; acc0[1] += e_0 * w0.y; acc0[2] += e_0 * w0.z; acc0[3] += e_0 * w0.w;
      acc0[4] += e_0 * w1.x; acc0[5] += e_0 * w1.y; acc0[6] += e_0 * w1.z; acc0[7] += e_0 * w1.w;
      acc0[8] += e_0 * w8;
      acc1[0] += e_1 * w0.x; acc1[1] += e_1 * w0.y; acc1[2] += e_1 * w0.z; acc1[3] += e_1 * w0.w;
      acc1[4] += e_1 * w1.x; acc1[5] += e_1 * w1.y; acc1[6] += e_1 * w1.z; acc1[7] += e_1 * w1.w;
      acc1[8] += e_1 * w8;
    }
    __syncthreads();
  }
  float* a0 = att + ((size_t)bh * Nc + nq0) * D1c + e0;
  float* a1 = att + ((size_t)bh * Nc + nq1) * D1c + e0;
#pragma unroll
  for (int i = 0; i < 8; i++) { a0[i] = acc0[i]; a1[i] = acc1[i]; }
  if (le == 7) { a0[8] = acc0[8]; a1[8] = acc1[8]; }   // col 64 (denominator)
}

// ---- K5a: partial Gram over 128-row chunks (f32 accum, grid = BH*32) ------
__global__ __launch_bounds__(256) void gram_partial_kernel(
    const float* __restrict__ v, double* __restrict__ part) {
  __shared__ float ch[GCH][D1c];
  int bh = blockIdx.x / NCHUNK, c = blockIdx.x % NCHUNK;
  int b = bh / Hc, h = bh % Hc;
  int t = threadIdx.x;
  for (int e = t; e < GCH * D1c; e += 256) {
    int r = e / D1c, p = e % D1c;
    int n = c * GCH + r;
    ch[r][p] = (p < Dc) ? v[(((size_t)b * Nc + n) * Hc + h) * Dc + p] : 1.0f;
  }
  __syncthreads();
  for (int pi = t; pi < D1c * D1c; pi += 256) {
    int tt = pi / D1c, uu = pi % D1c;
    float a = 0.0f;
    for (int r = 0; r < GCH; r++) a += ch[r][tt] * ch[r][uu];
    part[((size_t)bh * NCHUNK + c) * (D1c * D1c) + pi] = (double)a;
  }
}

// ---- K5b: reduce chunk partials (fixed order -> deterministic) ------------
__global__ __launch_bounds__(256) void gram_reduce_kernel(
    const double* __restrict__ part, double* __restrict__ gram) {
  int idx = blockIdx.x * 256 + threadIdx.x;   // over BH * 4225
  if (idx >= BHc * D1c * D1c) return;
  int bh = idx / (D1c * D1c), pi = idx % (D1c * D1c);
  double s = 0.0;
  for (int c = 0; c < NCHUNK; c++)
    s += part[((size_t)bh * NCHUNK + c) * (D1c * D1c) + pi];
  gram[(size_t)bh * (D1c * D1c) + pi] = s;
}

// ---- K6: power method for spectral norm -----------------------------------
__global__ __launch_bounds__(128) void power_kernel(
    const double* __restrict__ gram, const float* __restrict__ pm, double* __restrict__ sigma) {
  __shared__ double G[D1c * D1c];
  __shared__ double x[D1c], y[D1c];
  __shared__ double nrm;
  int bh = blockIdx.x, t = threadIdx.x;
  for (int e = t; e < D1c * D1c; e += 128) G[e] = gram[(size_t)bh * D1c * D1c + e];
  if (t < D1c) x[t] = (double)pm[bh * D1c + t];
  __syncthreads();
  if (t == 0) {
    double s = 0; for (int i = 0; i < D1c; i++) s += x[i] * x[i];
    nrm = sqrt(s);
  }
  __syncthreads();
  if (t < D1c) x[t] /= nrm;
  for (int it = 0; it < PMITERc; it++) {
    __syncthreads();
    if (t < D1c) {
      double s = 0;
      for (int u = 0; u < D1c; u++) s += G[t * D1c + u] * x[u];
      y[t] = s;
    }
    __syncthreads();
    if (t == 0) {
      double s = 0; for (int i = 0; i < D1c; i++) s += y[i] * y[i];
      nrm = sqrt(s);
    }
    __syncthreads();
    if (t < D1c) x[t] = y[t] / nrm;
  }
  __syncthreads();
  if (t == 0) sigma[bh] = nrm;
}

// ---- K7a: unnormalized P + per-segment partial sums (grid = BH*8) ---------
__global__ __launch_bounds__(256) void p_partial_kernel(
    const float* __restrict__ v, const int* __restrict__ kidx,
    const double* __restrict__ sigma, double* __restrict__ Pun, double* __restrict__ psum) {
  __shared__ double red[256];
  int blk = blockIdx.x;
  int bh = blk >> 3, seg = blk & 7;
  int b = bh / Hc, h = bh % Hc;
  int t = threadIdx.x;
  double sg = sigma[bh];
  double part = 0.0;
  for (int n = seg * 512 + t; n < (seg + 1) * 512; n += 256) {
    int m = kidx[bh * Nc + n];
    const float* vr = v + (((size_t)b * Nc + m) * Hc + h) * Dc;
    double ss = 1.0;  // the appended 1.0 component of v_aug
    for (int d = 0; d < Dc; d++) { double vv = vr[d]; ss += vv * vv; }
    double Pd = sqrt(ss) / sg + (1.0 / (double)Nc);
    Pun[bh * Nc + n] = Pd;
    part += Pd;
  }
  red[t] = part;
  __syncthreads();
  for (int w = 128; w > 0; w >>= 1) {
    if (t < w) red[t] += red[t + w];
    __syncthreads();
  }
  if (t == 0) psum[blk] = red[0];
}

// ---- K7b: normalize + log -------------------------------------------------
__global__ __launch_bounds__(256) void p_final_kernel(
    const double* __restrict__ Pun, const double* __restrict__ psum,
    float* __restrict__ P, float* __restrict__ logP) {
  int idx = blockIdx.x * 256 + threadIdx.x;   // over BH*N
  int bh = idx / Nc;
  double tot = 0.0;
#pragma unroll
  for (int s = 0; s < 8; s++) tot += psum[bh * 8 + s];
  float Pf = (float)(Pun[idx] / tot);
  P[idx] = Pf;
  logP[idx] = logf(Pf);
}

// ---- K8: categorical sampling (argmax gumbel+logP) + fused gather ---------
__global__ __launch_bounds__(256) void sample_kernel(
    const float* __restrict__ logP, const int* __restrict__ kidx,
    const float* __restrict__ P, const float* __restrict__ key, const float* __restrict__ value,
    float* __restrict__ Kpi, float* __restrict__ sigV, int* __restrict__ sblk) {
  __shared__ float sv[256];
  __shared__ int si[256];
  int blk = blockIdx.x;           // bh*S + s
  int bh = blk / Sc, s = blk % Sc;
  int b = bh / Hc, h = bh % Hc;
  int t = threadIdx.x;
  float best = -3.4e38f; int besti = Nc;
  const float* lp = logP + bh * Nc;
  u32 base = ((u32)(s * BHc + bh)) * (u32)Nc;  // flat index into (800,16,4096)
  for (int n = t; n < Nc; n += 256) {
    float val = gumbel_at(base + (u32)n) + lp[n];
    if (val > best || (val == best && n < besti)) { best = val; besti = n; }
  }
  sv[t] = best; si[t] = besti;
  __syncthreads();
  for (int w = 128; w > 0; w >>= 1) {
    if (t < w) {
      float v2 = sv[t + w]; int i2 = si[t + w];
      if (v2 > sv[t] || (v2 == sv[t] && i2 < si[t])) { sv[t] = v2; si[t] = i2; }
    }
    __syncthreads();
  }
  int m = si[0];
  if (t == 0) sblk[blk] = m >> 8;
  int src = kidx[bh * Nc + m];
  float sg = 1.0f / (P[bh * Nc + m] * (float)Sc);
  const float* kr = key + (((size_t)b * Nc + src) * Hc + h) * Dc;
  const float* vr = value + (((size_t)b * Nc + src) * Hc + h) * Dc;
  if (t < Dc) Kpi[(size_t)blk * Dc + t] = kr[t];
  if (t < WST) sigV[(size_t)blk * WST + t] =
      (t < Dc) ? sg * vr[t] : ((t == Dc) ? sg : 0.0f);   // [65..67] = pad
}

// ---- K10: residual attention, eighth-split 2-row register tiles -----------
__global__ __launch_bounds__(256) void residual_kernel(
    const float* __restrict__ q,
    const float* __restrict__ Kpi, const float* __restrict__ sigV, const int* __restrict__ sblk,
    const int* __restrict__ qblk, const float* __restrict__ att, float* __restrict__ out) {
  __shared__ float S[8448];        // kl[64][64] | wl[64][68]
  __shared__ int bl[64];
  float* kl = S;
  float* wl = S + 4096;
  int blk = blockIdx.x;
  int bh = blk >> 6;               // 64 row-groups per bh
  int n0 = (blk & 63) * 64;
  int b = bh / Hc, h = bh % Hc;
  int t = threadIdx.x;
  int le = t & 7;                  // D-/P-eighth
  int rp = t >> 3;                 // row pair 0..31
  int e0 = le * 8;
  int n_0 = n0 + rp * 2, n_1 = n_0 + 1;
  const float* q0 = q + (((size_t)b * Nc + n_0) * Hc + h) * Dc + e0;
  const float* q1 = q + (((size_t)b * Nc + n_1) * Hc + h) * Dc + e0;
  float qa[8], qb[8];
  {
    float4 f0 = ((const float4*)q0)[0], f1 = ((const float4*)q0)[1];
    qa[0] = f0.x; qa[1] = f0.y; qa[2] = f0.z; qa[3] = f0.w;
    qa[4] = f1.x; qa[5] = f1.y; qa[6] = f1.z; qa[7] = f1.w;
    float4 g0 = ((const float4*)q1)[0], g1 = ((const float4*)q1)[1];
    qb[0] = g0.x; qb[1] = g0.y; qb[2] = g0.z; qb[3] = g0.w;
    qb[4] = g1.x; qb[5] = g1.y; qb[6] = g1.z; qb[7] = g1.w;
  }
  int myblk0 = qblk[bh * Nc + n_0], myblk1 = qblk[bh * Nc + n_1];
  float acc0[9], acc1[9];
#pragma unroll
  for (int i = 0; i < 9; i++) { acc0[i] = 0.f; acc1[i] = 0.f; }
  const float* KpiB = Kpi + (size_t)bh * Sc * Dc;
  const float* sigVB = sigV + (size_t)bh * Sc * WST;
  const int* sblkB = sblk + bh * Sc;
  for (int tile = 0; tile < 13; tile++) {       // 12 tiles of 64 + tail 32
    int base = tile * 64;
    int cnt = (tile < 12) ? 64 : 32;
    for (int e4 = t; e4 < cnt * 16; e4 += 256)     // kl: flat float4 copy
      ((float4*)kl)[e4] = ((const float4*)(KpiB + (size_t)base * Dc))[e4];
    for (int e4 = t; e4 < cnt * 17; e4 += 256)     // wl: flat float4 copy (stride 68)
      ((float4*)wl)[e4] = ((const float4*)(sigVB + (size_t)base * WST))[e4];
    if (t < cnt) bl[t] = sblkB[base + t];
    __syncthreads();
    for (int j = 0; j < cnt; j++) {
      const float* kj = kl + j * 64 + e0;
      float4 k0 = ((const float4*)kj)[0], k1 = ((const float4*)kj)[1];
      float s0 = qa[0] * k0.x + qa[1] * k0.y + qa[2] * k0.z + qa[3] * k0.w
               + qa[4] * k1.x + qa[5] * k1.y + qa[6] * k1.z + qa[7] * k1.w;
      float s1 = qb[0] * k0.x + qb[1] * k0.y + qb[2] * k0.z + qb[3] * k0.w
               + qb[4] * k1.x + qb[5] * k1.y + qb[6] * k1.z + qb[7] * k1.w;
      s0 += __shfl_xor(s0, 1); s0 += __shfl_xor(s0, 2); s0 += __shfl_xor(s0, 4);
      s1 += __shfl_xor(s1, 1); s1 += __shfl_xor(s1, 2); s1 += __shfl_xor(s1, 4);
      float e_0 = __expf(s0), e_1 = __expf(s1);
      int bj = bl[j];
      float w0 = (bj == myblk0) ? 0.0f : e_0;   // mask: sample in query's own block
      float w1 = (bj == myblk1) ? 0.0f : e_1;
      const float* wj = wl + j * WST + e0;
      float4 w0v = ((const float4*)wj)[0], w1v = ((const float4*)wj)[1];
      float w8 = wj[8];                          // le==7: col 64 = sig column
      acc0[0] += w0 * w0v.x; acc0[1] += w0 * w0v.y; acc0[2] += w0 * w0v.z; acc0[3] += w0 * w0v.w;
      acc0[4] += w0 * w1v.x; acc0[5] += w0 * w1v.y; acc0[6] += w0 * w1v.z; acc0[7] += w0 * w1v.w;
      acc0[8] += w0 * w8;
      acc1[0] += w1 * w0v.x; acc1[1] += w1 * w0v.y; acc1[2] += w1 * w0v.z; acc1[3] += w1 * w0v.w;
      acc1[4] += w1 * w1v.x; acc1[5] += w1 * w1v.y; acc1[6] += w1 * w1v.z; acc1[7] += w1 * w1v.w;
      acc1[8] += w1 * w8;
    }
    __syncthreads();
  }
  const float* ar0 = att + ((size_t)bh * Nc + n_0) * D1c;
  const float* ar1 = att + ((size_t)bh * Nc + n_1) * D1c;
  // denominator lives in le==7's acc[8] (col 64); broadcast within the 8-lane group
  float cand0 = ar0[Dc] + acc0[8];
  float cand1 = ar1[Dc] + acc1[8];
  int lane = t & 63;
  float den0 = __shfl(cand0, lane | 7);
  float den1 = __shfl(cand1, lane | 7);
  float* o0 = out + ((size_t)bh * Nc + n_0) * Dc + e0;
  float* o1 = out + ((size_t)bh * Nc + n_1) * Dc + e0;
#pragma unroll
  for (int i = 0; i < 8; i++) {
    o0[i] = (ar0[e0 + i] + acc0[i]) / den0;
    o1[i] = (ar1[e0 + i] + acc1[i]) / den1;
  }
}

// ---------------------------------------------------------------------------
extern "C" void kernel_launch(void* const* d_in, const int* in_sizes, int n_in,
                              void* d_out, int out_size, void* d_ws, size_t ws_size,
                              hipStream_t stream) {
  const float* q  = (const float*)d_in[0];
  const float* k  = (const float*)d_in[1];
  const float* v  = (const float*)d_in[2];
  const float* pd = (const float*)d_in[3];
  const float* pm = (const float*)d_in[4];
  float* out = (float*)d_out;

  char* w = (char*)d_ws;
  size_t off = 0;
  auto take = [&](size_t nbytes) -> void* {
    void* p = w + off;
    off += (nbytes + 255) & ~(size_t)255;
    return p;
  };
  double* gram = (double*)take((size_t)BHc * D1c * D1c * sizeof(double));
  double* sigm = (double*)take((size_t)BHc * sizeof(double));
  double* Pun  = (double*)take((size_t)BHc * Nc * sizeof(double));
  double* psum = (double*)take((size_t)BHc * 8 * sizeof(double));
  int* hq   = (int*)take((size_t)BHc * Nc * 4);
  int* hk   = (int*)take((size_t)BHc * Nc * 4);
  int* qidx = (int*)take((size_t)BHc * Nc * 4);
  int* kidx = (int*)take((size_t)BHc * Nc * 4);
  int* qblk = (int*)take((size_t)BHc * Nc * 4);
  float* P    = (float*)take((size_t)BHc * Nc * 4);
  float* logP = (float*)take((size_t)BHc * Nc * 4);
  int* sblk = (int*)take((size_t)BHc * Sc * 4);
  float* Kpi  = (float*)take((size_t)BHc * Sc * Dc * 4);
  float* sigV = (float*)take((size_t)BHc * Sc * WST * 4);
  // union region: Gram chunk partials (used first), then att (written after
  // gram_reduce has consumed the partials — stream order guarantees this).
  size_t partBytes = (size_t)BHc * NCHUNK * D1c * D1c * sizeof(double);
  size_t attBytes  = (size_t)BHc * Nc * D1c * 4;
  void* uni = take(partBytes > attBytes ? partBytes : attBytes);
  double* part = (double*)uni;
  float*  att  = (float*)uni;
  (void)ws_size; (void)in_sizes; (void)n_in; (void)out_size;

  hash_kernel<<<2 * BHc * Nc / 256, 256, 0, stream>>>(q, k, pd, hq, hk);
  sort_kernel<<<dim3(BHc, 2), 512, 0, stream>>>(hq, hk, qidx, kidx, qblk);
  gram_partial_kernel<<<BHc * NCHUNK, 256, 0, stream>>>(v, part);
  gram_reduce_kernel<<<(BHc * D1c * D1c + 255) / 256, 256, 0, stream>>>(part, gram);
  power_kernel<<<BHc, 128, 0, stream>>>(gram, pm, sigm);
  p_partial_kernel<<<BHc * 8, 256, 0, stream>>>(v, kidx, sigm, Pun, psum);
  p_final_kernel<<<BHc * Nc / 256, 256, 0, stream>>>(Pun, psum, P, logP);
  sample_kernel<<<BHc * Sc, 256, 0, stream>>>(logP, kidx, P, k, v, Kpi, sigV, sblk);
  sparse_kernel<<<BHc * NBc * 4, 256, 0, stream>>>(q, k, v, qidx, kidx, att);  // writes att (over part)
  residual_kernel<<<BHc * 64, 256, 0, stream>>>(q, Kpi, sigV, sblk, qblk, att, out);
}

// Round 12
// 545.551 us; speedup vs baseline: 1.9692x; 1.5931x over previous
//
#include <hip/hip_runtime.h>
#include <stdint.h>
#include <math.h>

// ---------------------------------------------------------------------------
// CosineHammingAttention — bit-faithful HIP port of the JAX reference.
// B=2 H=8 N=4096 D=64, NUM_PROJS=7, BUCKET=256, SAMPLE=800, PM_ITERS=32
// R2: parallelize Gram.  R3: 64 rows x 4 chunks attention.
// R5: __expf, sort fuses qblock, p split, sample fuses gather, f32 gram.
// R8-R10: f32 VALU attention boxed at 380-440us between LDS-BW roofline
//     (R8: 69.6 TB/s) and VALU+shfl floor (R10: L*log2L shuffle tax).
// R11: residual -> MFMA (bf16). S^T = K*Q^T via mfma_f32_16x16x32_bf16
//     (C-layout col=lane&15 -> q-row), exp+mask on fragments, P->LDS in
//     A-layout, O = P*W with W pre-transposed bf16 (80 cols, 65..79 = 0).
//     All LDS rows padded to 72 bf16 (144B) vs bank conflicts. Error budget:
//     bf16 QK ~2e-3 abs on S, bf16 P/W ~2e-3 rel, correlated num/denom.
// ---------------------------------------------------------------------------

typedef unsigned int u32;
typedef __attribute__((ext_vector_type(8))) short bf16x8;
typedef __attribute__((ext_vector_type(4))) float f32x4;

namespace {
constexpr int Bc = 2, Hc = 8, BHc = 16;
constexpr int Nc = 4096, Dc = 64, D1c = 65;
constexpr int NBc = 16;      // N / BUCKET
constexpr int Sc = 800;      // SAMPLE
constexpr int PMITERc = 32;
constexpr int GCH = 128;             // Gram rows per chunk
constexpr int NCHUNK = Nc / GCH;     // 32
}

__device__ __forceinline__ u32 rotl32(u32 x, u32 d) { return (x << d) | (x >> (32u - d)); }

__device__ __forceinline__ unsigned short f2bf(float f) {  // RNE f32 -> bf16
  u32 u = __float_as_uint(f);
  u += 0x7FFFu + ((u >> 16) & 1u);
  return (unsigned short)(u >> 16);
}

// Exact JAX threefry2x32 (20 rounds).
__device__ __forceinline__ void threefry2x32(u32 k0, u32 k1, u32 x0, u32 x1, u32& o0, u32& o1) {
  u32 ks2 = k0 ^ k1 ^ 0x1BD11BDAu;
  x0 += k0; x1 += k1;
#define TF_RND(r) { x0 += x1; x1 = rotl32(x1, r); x1 ^= x0; }
  TF_RND(13) TF_RND(15) TF_RND(26) TF_RND(6)
  x0 += k1; x1 += ks2 + 1u;
  TF_RND(17) TF_RND(29) TF_RND(16) TF_RND(24)
  x0 += ks2; x1 += k0 + 2u;
  TF_RND(13) TF_RND(15) TF_RND(26) TF_RND(6)
  x0 += k0; x1 += k1 + 3u;
  TF_RND(17) TF_RND(29) TF_RND(16) TF_RND(24)
  x0 += k1; x1 += ks2 + 4u;
  TF_RND(13) TF_RND(15) TF_RND(26) TF_RND(6)
  x0 += ks2; x1 += k0 + 5u;
#undef TF_RND
  o0 = x0; o1 = x1;
}

// gumbel sample for flat element i of the (800,16,4096) array, key = (0,1234)
__device__ __forceinline__ float gumbel_at(u32 i) {
  u32 o0, o1;
  threefry2x32(0u, 1234u, 0u, i, o0, o1);
  u32 bits = o0 ^ o1;
  u32 fb = (bits >> 9) | 0x3f800000u;
  float u = __uint_as_float(fb) - 1.0f;           // [0,1) on 2^-23 grid
  if (u == 0.0f) u = 1.1754944e-38f;              // max(tiny, u) per jax.random.uniform
  return -__logf(-__logf(u));
}

// ---- K1: LSH hash codes for q and k ---------------------------------------
__global__ __launch_bounds__(256) void hash_kernel(
    const float* __restrict__ q, const float* __restrict__ k,
    const float* __restrict__ pd, int* __restrict__ hq, int* __restrict__ hk) {
  int tid = blockIdx.x * 256 + threadIdx.x;
  int which = tid / (BHc * Nc);
  int rem = tid % (BHc * Nc);
  int bh = rem / Nc, n = rem % Nc;
  int b = bh / Hc, h = bh % Hc;
  const float* x = which ? k : q;
  const float* row = x + (((size_t)b * Nc + n) * Hc + h) * Dc;   // [B,N,H,D]
  const float* pdr = pd + (size_t)bh * Dc * 7;                   // [B,H,D,7]
  double acc[7];
#pragma unroll
  for (int r = 0; r < 7; r++) acc[r] = 0.0;
  for (int d = 0; d < Dc; d++) {
    double vv = (double)row[d];
    const float* pr = pdr + d * 7;
#pragma unroll
    for (int r = 0; r < 7; r++) acc[r] += vv * (double)pr[r];
  }
  int code = 0;
#pragma unroll
  for (int r = 0; r < 7; r++) code |= (acc[r] > 0.0) ? (1 << r) : 0;
  int hash = code ^ (code >> 1);   // _hamming_perm == binary-reflected Gray code
  (which ? hk : hq)[bh * Nc + n] = hash;
}

// ---- K2: stable counting sort, quarter-split; q-branch also writes qblk ---
__global__ __launch_bounds__(512) void sort_kernel(
    const int* __restrict__ hq, const int* __restrict__ hk,
    int* __restrict__ qidx, int* __restrict__ kidx, int* __restrict__ qblk) {
  __shared__ int sh[Nc];
  __shared__ int cnt[4][128];
  __shared__ int off[128];
  int bh = blockIdx.x;
  int which = blockIdx.y;
  const int* hash = which ? hk : hq;
  int* out = which ? kidx : qidx;
  int t = threadIdx.x;
  for (int i = t; i < Nc; i += 512) sh[i] = hash[bh * Nc + i];
  __syncthreads();
  int qr = t >> 7, b = t & 127;      // quarter, bin
  int c = 0;
  for (int i = qr * 1024; i < (qr + 1) * 1024; i++) c += (sh[i] == b);
  cnt[qr][b] = c;
  __syncthreads();
  if (t == 0) {
    int run = 0;
    for (int j = 0; j < 128; j++) {
      int tot = cnt[0][j] + cnt[1][j] + cnt[2][j] + cnt[3][j];
      off[j] = run; run += tot;
    }
  }
  __syncthreads();
  int o = off[b];
  for (int qq = 0; qq < qr; qq++) o += cnt[qq][b];
  for (int i = qr * 1024; i < (qr + 1) * 1024; i++)
    if (sh[i] == b) {
      out[bh * Nc + o] = i;
      if (which == 0) qblk[bh * Nc + i] = o >> 8;
      o++;
    }
}

// ---- K4: block-sparse attention, eighth-split 2-row register tiles --------
__global__ __launch_bounds__(256) void sparse_kernel(
    const float* __restrict__ q, const float* __restrict__ k, const float* __restrict__ v,
    const int* __restrict__ qidx, const int* __restrict__ kidx, float* __restrict__ att) {
  __shared__ float S[8192];        // kb[64][64] | wb[64][64]
  float* kb = S;
  float* wb = S + 4096;
  int blk = blockIdx.x;
  int bh = blk >> 6;               // 64 blocks per bh
  int rem = blk & 63;
  int g = rem >> 2, qq = rem & 3;  // bucket, query-quadrant
  int b = bh / Hc, h = bh % Hc;
  int t = threadIdx.x;
  int le = t & 7;                  // D-/P-eighth
  int rp = t >> 3;                 // row pair 0..31
  int e0 = le * 8;
  int nq0 = qidx[bh * Nc + g * 256 + qq * 64 + rp * 2];
  int nq1 = qidx[bh * Nc + g * 256 + qq * 64 + rp * 2 + 1];
  const float* q0 = q + (((size_t)b * Nc + nq0) * Hc + h) * Dc + e0;
  const float* q1 = q + (((size_t)b * Nc + nq1) * Hc + h) * Dc + e0;
  float qa[8], qb[8];
  {
    float4 f0 = ((const float4*)q0)[0], f1 = ((const float4*)q0)[1];
    qa[0] = f0.x; qa[1] = f0.y; qa[2] = f0.z; qa[3] = f0.w;
    qa[4] = f1.x; qa[5] = f1.y; qa[6] = f1.z; qa[7] = f1.w;
    float4 g0 = ((const float4*)q1)[0], g1 = ((const float4*)q1)[1];
    qb[0] = g0.x; qb[1] = g0.y; qb[2] = g0.z; qb[3] = g0.w;
    qb[4] = g1.x; qb[5] = g1.y; qb[6] = g1.z; qb[7] = g1.w;
  }
  float acc0[9], acc1[9];
#pragma unroll
  for (int i = 0; i < 9; i++) { acc0[i] = 0.f; acc1[i] = 0.f; }
  const int* kidxB = kidx + bh * Nc + g * 256;
  for (int tile = 0; tile < 4; tile++) {
    for (int e4 = t; e4 < 64 * 16; e4 += 256) {
      int j = e4 >> 4, d4 = e4 & 15;
      int m = kidxB[tile * 64 + j];
      const float* kr = k + (((size_t)b * Nc + m) * Hc + h) * Dc;
      const float* vr = v + (((size_t)b * Nc + m) * Hc + h) * Dc;
      ((float4*)(kb + j * 64))[d4] = ((const float4*)kr)[d4];
      ((float4*)(wb + j * 64))[d4] = ((const float4*)vr)[d4];
    }
    __syncthreads();
    for (int j = 0; j < 64; j++) {
      const float* kj = kb + j * 64 + e0;
      float4 k0 = ((const float4*)kj)[0], k1 = ((const float4*)kj)[1];
      float s0 = qa[0] * k0.x + qa[1] * k0.y + qa[2] * k0.z + qa[3] * k0.w
               + qa[4] * k1.x + qa[5] * k1.y + qa[6] * k1.z + qa[7] * k1.w;
      float s1 = qb[0] * k0.x + qb[1] * k0.y + qb[2] * k0.z + qb[3] * k0.w
               + qb[4] * k1.x + qb[5] * k1.y + qb[6] * k1.z + qb[7] * k1.w;
      s0 += __shfl_xor(s0, 1); s0 += __shfl_xor(s0, 2); s0 += __shfl_xor(s0, 4);
      s1 += __shfl_xor(s1, 1); s1 += __shfl_xor(s1, 2); s1 += __shfl_xor(s1, 4);
      float e_0 = __expf(s0), e_1 = __expf(s1);
      const float* wj = wb + j * 64 + e0;
      float4 w0 = ((const float4*)wj)[0], w1 = ((const float4*)wj)[1];
      float w8 = (le == 7) ? 1.0f : wj[8];   // col 64 is the implicit ones column
      acc0[0] += e_0 * w0.x; acc0[1] += e_0 * w0.y; acc0[2] += e_0 * w0.z; acc0[3] += e_0 * w0.w;
      acc0[4] += e_0 * w1.x; acc0[5] += e_0 * w1.y; acc0[6] += e_0 * w1.z; acc0[7] += e_0 * w1.w;
      acc0[8] += e_0 * w8;
      acc1[0] += e_1 * w0.x; acc1[1] += e_1 * w0.y; acc1[2] += e_1 * w0.z; acc1[3] += e_1 * w0.w;
      acc1[4] += e_1 * w1.x; acc1[5] += e_1 * w1.y; acc1[6] += e_1 * w1.z; acc1[7] += e_1 * w1.w;
      acc1[8] += e_1 * w8;
    }
    __syncthreads();
  }
  float* a0 = att + ((size_t)bh * Nc + nq0) * D1c + e0;
  float* a1 = att + ((size_t)bh * Nc + nq1) * D1c + e0;
#pragma unroll
  for (int i = 0; i < 8; i++) { a0[i] = acc0[i]; a1[i] = acc1[i]; }
  if (le == 7) { a0[8] = acc0[8]; a1[8] = acc1[8]; }   // col 64 (denominator)
}

// ---- K5a: partial Gram over 128-row chunks (f32 accum, grid = BH*32) ------
__global__ __launch_bounds__(256) void gram_partial_kernel(
    const float* __restrict__ v, double* __restrict__ part) {
  __shared__ float ch[GCH][D1c];
  int bh = blockIdx.x / NCHUNK, c = blockIdx.x % NCHUNK;
  int b = bh / Hc, h = bh % Hc;
  int t = threadIdx.x;
  for (int e = t; e < GCH * D1c; e += 256) {
    int r = e / D1c, p = e % D1c;
    int n = c * GCH + r;
    ch[r][p] = (p < Dc) ? v[(((size_t)b * Nc + n) * Hc + h) * Dc + p] : 1.0f;
  }
  __syncthreads();
  for (int pi = t; pi < D1c * D1c; pi += 256) {
    int tt = pi / D1c, uu = pi % D1c;
    float a = 0.0f;
    for (int r = 0; r < GCH; r++) a += ch[r][tt] * ch[r][uu];
    part[((size_t)bh * NCHUNK + c) * (D1c * D1c) + pi] = (double)a;
  }
}

// ---- K5b: reduce chunk partials (fixed order -> deterministic) ------------
__global__ __launch_bounds__(256) void gram_reduce_kernel(
    const double* __restrict__ part, double* __restrict__ gram) {
  int idx = blockIdx.x * 256 + threadIdx.x;   // over BH * 4225
  if (idx >= BHc * D1c * D1c) return;
  int bh = idx / (D1c * D1c), pi = idx % (D1c * D1c);
  double s = 0.0;
  for (int c = 0; c < NCHUNK; c++)
    s += part[((size_t)bh * NCHUNK + c) * (D1c * D1c) + pi];
  gram[(size_t)bh * (D1c * D1c) + pi] = s;
}

// ---- K6: power method for spectral norm -----------------------------------
__global__ __launch_bounds__(128) void power_kernel(
    const double* __restrict__ gram, const float* __restrict__ pm, double* __restrict__ sigma) {
  __shared__ double G[D1c * D1c];
  __shared__ double x[D1c], y[D1c];
  __shared__ double nrm;
  int bh = blockIdx.x, t = threadIdx.x;
  for (int e = t; e < D1c * D1c; e += 128) G[e] = gram[(size_t)bh * D1c * D1c + e];
  if (t < D1c) x[t] = (double)pm[bh * D1c + t];
  __syncthreads();
  if (t == 0) {
    double s = 0; for (int i = 0; i < D1c; i++) s += x[i] * x[i];
    nrm = sqrt(s);
  }
  __syncthreads();
  if (t < D1c) x[t] /= nrm;
  for (int it = 0; it < PMITERc; it++) {
    __syncthreads();
    if (t < D1c) {
      double s = 0;
      for (int u = 0; u < D1c; u++) s += G[t * D1c + u] * x[u];
      y[t] = s;
    }
    __syncthreads();
    if (t == 0) {
      double s = 0; for (int i = 0; i < D1c; i++) s += y[i] * y[i];
      nrm = sqrt(s);
    }
    __syncthreads();
    if (t < D1c) x[t] = y[t] / nrm;
  }
  __syncthreads();
  if (t == 0) sigma[bh] = nrm;
}

// ---- K7a: unnormalized P + per-segment partial sums (grid = BH*8) ---------
__global__ __launch_bounds__(256) void p_partial_kernel(
    const float* __restrict__ v, const int* __restrict__ kidx,
    const double* __restrict__ sigma, double* __restrict__ Pun, double* __restrict__ psum) {
  __shared__ double red[256];
  int blk = blockIdx.x;
  int bh = blk >> 3, seg = blk & 7;
  int b = bh / Hc, h = bh % Hc;
  int t = threadIdx.x;
  double sg = sigma[bh];
  double part = 0.0;
  for (int n = seg * 512 + t; n < (seg + 1) * 512; n += 256) {
    int m = kidx[bh * Nc + n];
    const float* vr = v + (((size_t)b * Nc + m) * Hc + h) * Dc;
    double ss = 1.0;  // the appended 1.0 component of v_aug
    for (int d = 0; d < Dc; d++) { double vv = vr[d]; ss += vv * vv; }
    double Pd = sqrt(ss) / sg + (1.0 / (double)Nc);
    Pun[bh * Nc + n] = Pd;
    part += Pd;
  }
  red[t] = part;
  __syncthreads();
  for (int w = 128; w > 0; w >>= 1) {
    if (t < w) red[t] += red[t + w];
    __syncthreads();
  }
  if (t == 0) psum[blk] = red[0];
}

// ---- K7b: normalize + log -------------------------------------------------
__global__ __launch_bounds__(256) void p_final_kernel(
    const double* __restrict__ Pun, const double* __restrict__ psum,
    float* __restrict__ P, float* __restrict__ logP) {
  int idx = blockIdx.x * 256 + threadIdx.x;   // over BH*N
  int bh = idx / Nc;
  double tot = 0.0;
#pragma unroll
  for (int s = 0; s < 8; s++) tot += psum[bh * 8 + s];
  float Pf = (float)(Pun[idx] / tot);
  P[idx] = Pf;
  logP[idx] = logf(Pf);
}

// ---- K8: categorical sampling + fused gather (bf16 K / transposed bf16 W) -
__global__ __launch_bounds__(256) void sample_kernel(
    const float* __restrict__ logP, const int* __restrict__ kidx,
    const float* __restrict__ P, const float* __restrict__ key, const float* __restrict__ value,
    unsigned short* __restrict__ Khg,   // [BH][800][64] bf16
    unsigned short* __restrict__ WhTg,  // [BH][80][800] bf16 (transposed, cols 65..79 = 0)
    int* __restrict__ sblk) {
  __shared__ float sv[256];
  __shared__ int si[256];
  int blk = blockIdx.x;           // bh*S + s
  int bh = blk / Sc, s = blk % Sc;
  int b = bh / Hc, h = bh % Hc;
  int t = threadIdx.x;
  float best = -3.4e38f; int besti = Nc;
  const float* lp = logP + bh * Nc;
  u32 base = ((u32)(s * BHc + bh)) * (u32)Nc;  // flat index into (800,16,4096)
  for (int n = t; n < Nc; n += 256) {
    float val = gumbel_at(base + (u32)n) + lp[n];
    if (val > best || (val == best && n < besti)) { best = val; besti = n; }
  }
  sv[t] = best; si[t] = besti;
  __syncthreads();
  for (int w = 128; w > 0; w >>= 1) {
    if (t < w) {
      float v2 = sv[t + w]; int i2 = si[t + w];
      if (v2 > sv[t] || (v2 == sv[t] && i2 < si[t])) { sv[t] = v2; si[t] = i2; }
    }
    __syncthreads();
  }
  int m = si[0];
  if (t == 0) sblk[blk] = m >> 8;
  int src = kidx[bh * Nc + m];
  float sg = 1.0f / (P[bh * Nc + m] * (float)Sc);
  const float* kr = key + (((size_t)b * Nc + src) * Hc + h) * Dc;
  const float* vr = value + (((size_t)b * Nc + src) * Hc + h) * Dc;
  if (t < Dc) Khg[((size_t)bh * Sc + s) * 64 + t] = f2bf(kr[t]);
  if (t < 80) {
    float val = (t < Dc) ? sg * vr[t] : ((t == Dc) ? sg : 0.0f);
    WhTg[((size_t)bh * 80 + t) * Sc + s] = f2bf(val);
  }
}

// ---- K10: residual attention via MFMA (bf16) ------------------------------
// Per block: 64 q-rows, 4 waves (16 rows each). Per 64-sample tile:
//   S^T = K * Q^T  (A = K from LDS, B = Q in-register frags),
//   P = mask(exp(S^T)) -> bf16 -> LDS (A-layout for PV),
//   O += P * WhT      (B = WhT from LDS).
// mfma_f32_16x16x32_bf16 layouts: A row=lane&15, k=(lane>>4)*8+e (contig 8);
// B col=lane&15, k=(lane>>4)*8+e; C/D col=lane&15, row=(lane>>4)*4+i (m89).
__global__ __launch_bounds__(256) void residual_kernel(
    const float* __restrict__ q,
    const unsigned short* __restrict__ Khg, const unsigned short* __restrict__ WhTg,
    const int* __restrict__ sblk,
    const int* __restrict__ qblk, const float* __restrict__ att, float* __restrict__ out) {
  __shared__ unsigned short sm[14976];  // Kh[64][72] | WhT[80][72] | P[64][72]
  __shared__ int bl[64];
  unsigned short* KhL = sm;             // 4608
  unsigned short* WTL = sm + 4608;      // 5760
  unsigned short* PL  = sm + 10368;     // 4608
  int blk = blockIdx.x;
  int bh = blk >> 6;
  int n0 = (blk & 63) * 64;
  int b = bh / Hc, h = bh % Hc;
  int t = threadIdx.x;
  int w = t >> 6, l = t & 63;
  int l15 = l & 15, l4 = l >> 4;
  // Q fragments (B-operand): row = n0+16w+l15, d = kb*32 + l4*8 + e
  int nq = n0 + 16 * w + l15;
  const float* qrow = q + (((size_t)b * Nc + nq) * Hc + h) * Dc;
  bf16x8 qf[2];
#pragma unroll
  for (int kb = 0; kb < 2; kb++) {
    const float* srcq = qrow + kb * 32 + l4 * 8;
    float4 f0 = ((const float4*)srcq)[0];
    float4 f1 = ((const float4*)srcq)[1];
    bf16x8 vq;
    vq[0] = (short)f2bf(f0.x); vq[1] = (short)f2bf(f0.y);
    vq[2] = (short)f2bf(f0.z); vq[3] = (short)f2bf(f0.w);
    vq[4] = (short)f2bf(f1.x); vq[5] = (short)f2bf(f1.y);
    vq[6] = (short)f2bf(f1.z); vq[7] = (short)f2bf(f1.w);
    qf[kb] = vq;
  }
  int qb = qblk[bh * Nc + nq];
  f32x4 oacc[5];
#pragma unroll
  for (int nt = 0; nt < 5; nt++) oacc[nt] = (f32x4){0.f, 0.f, 0.f, 0.f};
  const unsigned short* KhB = Khg + (size_t)bh * Sc * 64;
  const unsigned short* WTB = WhTg + (size_t)bh * 80 * Sc;
  const int* sblkB = sblk + bh * Sc;
  for (int tile = 0; tile < 13; tile++) {
    int s0 = tile * 64;
    int cnt = (tile < 12) ? 64 : 32;
    // stage Kh: cnt rows x 64 bf16 (16B chunks)
    for (int idx = t; idx < cnt * 8; idx += 256) {
      int r = idx >> 3, sg = idx & 7;
      *(uint4*)&KhL[r * 72 + sg * 8] = *(const uint4*)&KhB[(size_t)(s0 + r) * 64 + sg * 8];
    }
    // stage WhT: 80 rows x cnt bf16
    int ssh = (cnt == 64) ? 3 : 2;
    int segs = cnt >> 3;
    for (int idx = t; idx < 80 * segs; idx += 256) {
      int c = idx >> ssh, sg = idx & (segs - 1);
      *(uint4*)&WTL[c * 72 + sg * 8] = *(const uint4*)&WTB[(size_t)c * Sc + s0 + sg * 8];
    }
    if (t < cnt) bl[t] = sblkB[s0 + t];
    __syncthreads();
    // QK^T: S^T (samples x 16 rows), K-dim = D = 64 (2 blocks)
    int mtn = cnt >> 4;
    f32x4 sacc[4];
#pragma unroll
    for (int mt = 0; mt < 4; mt++) sacc[mt] = (f32x4){0.f, 0.f, 0.f, 0.f};
#pragma unroll
    for (int kb = 0; kb < 2; kb++) {
#pragma unroll
      for (int mt = 0; mt < 4; mt++) {
        if (mt >= mtn) break;
        bf16x8 ka = *(const bf16x8*)&KhL[(mt * 16 + l15) * 72 + kb * 32 + l4 * 8];
        sacc[mt] = __builtin_amdgcn_mfma_f32_16x16x32_bf16(ka, qf[kb], sacc[mt], 0, 0, 0);
      }
    }
    // exp + mask -> P bf16 -> LDS (row = 16w+l15, samples contiguous)
#pragma unroll
    for (int mt = 0; mt < 4; mt++) {
      if (mt >= mtn) break;
      int sb = mt * 16 + l4 * 4;
      unsigned short p0 = (bl[sb + 0] == qb) ? 0 : f2bf(__expf(sacc[mt][0]));
      unsigned short p1 = (bl[sb + 1] == qb) ? 0 : f2bf(__expf(sacc[mt][1]));
      unsigned short p2 = (bl[sb + 2] == qb) ? 0 : f2bf(__expf(sacc[mt][2]));
      unsigned short p3 = (bl[sb + 3] == qb) ? 0 : f2bf(__expf(sacc[mt][3]));
      uint2 pk;
      pk.x = (u32)p0 | ((u32)p1 << 16);
      pk.y = (u32)p2 | ((u32)p3 << 16);
      *(uint2*)&PL[(16 * w + l15) * 72 + sb] = pk;
    }
    // PV: O += P * WhT  (K-dim = samples, cnt/32 blocks)
    int kbn = cnt >> 5;
#pragma unroll
    for (int kb = 0; kb < 2; kb++) {
      if (kb >= kbn) break;
      bf16x8 pa = *(const bf16x8*)&PL[(16 * w + l15) * 72 + kb * 32 + l4 * 8];
#pragma unroll
      for (int nt = 0; nt < 5; nt++) {
        bf16x8 wb = *(const bf16x8*)&WTL[(nt * 16 + l15) * 72 + kb * 32 + l4 * 8];
        oacc[nt] = __builtin_amdgcn_mfma_f32_16x16x32_bf16(pa, wb, oacc[nt], 0, 0, 0);
      }
    }
    __syncthreads();
  }
  // epilogue: C layout -> row = n0+16w+l4*4+i, col = nt*16+l15
  float den[4];
#pragma unroll
  for (int i = 0; i < 4; i++) {
    int n = n0 + 16 * w + l4 * 4 + i;
    const float* arow = att + ((size_t)bh * Nc + n) * D1c;
    float cand = (l15 == 0) ? (arow[Dc] + oacc[4][i]) : 0.f;
    den[i] = __shfl(cand, l & 48);   // broadcast from col-64 lane of this group
  }
#pragma unroll
  for (int i = 0; i < 4; i++) {
    int n = n0 + 16 * w + l4 * 4 + i;
    const float* arow = att + ((size_t)bh * Nc + n) * D1c;
    float* orow = out + ((size_t)bh * Nc + n) * Dc;
#pragma unroll
    for (int nt = 0; nt < 4; nt++) {
      int c = nt * 16 + l15;
      orow[c] = (arow[c] + oacc[nt][i]) / den[i];
    }
  }
}

// ---------------------------------------------------------------------------
extern "C" void kernel_launch(void* const* d_in, const int* in_sizes, int n_in,
                              void* d_out, int out_size, void* d_ws, size_t ws_size,
                              hipStream_t stream) {
  const float* q  = (const float*)d_in[0];
  const float* k  = (const float*)d_in[1];
  const float* v  = (const float*)d_in[2];
  const float* pd = (const float*)d_in[3];
  const float* pm = (const float*)d_in[4];
  float* out = (float*)d_out;

  char* w = (char*)d_ws;
  size_t off = 0;
  auto take = [&](size_t nbytes) -> void* {
    void* p = w + off;
    off += (nbytes + 255) & ~(size_t)255;
    return p;
  };
  double* gram = (double*)take((size_t)BHc * D1c * D1c * sizeof(double));
  double* sigm = (double*)take((size_t)BHc * sizeof(double));
  double* Pun  = (double*)take((size_t)BHc * Nc * sizeof(double));
  double* psum = (double*)take((size_t)BHc * 8 * sizeof(double));
  int* hq   = (int*)take((size_t)BHc * Nc * 4);
  int* hk   = (int*)take((size_t)BHc * Nc * 4);
  int* qidx = (int*)take((size_t)BHc * Nc * 4);
  int* kidx = (int*)take((size_t)BHc * Nc * 4);
  int* qblk = (int*)take((size_t)BHc * Nc * 4);
  float* P    = (float*)take((size_t)BHc * Nc * 4);
  float* logP = (float*)take((size_t)BHc * Nc * 4);
  int* sblk = (int*)take((size_t)BHc * Sc * 4);
  unsigned short* Khg  = (unsigned short*)take((size_t)BHc * Sc * 64 * 2);
  unsigned short* WhTg = (unsigned short*)take((size_t)BHc * 80 * Sc * 2);
  // union region: Gram chunk partials (used first), then att (written after
  // gram_reduce has consumed the partials — stream order guarantees this).
  size_t partBytes = (size_t)BHc * NCHUNK * D1c * D1c * sizeof(double);
  size_t attBytes  = (size_t)BHc * Nc * D1c * 4;
  void* uni = take(partBytes > attBytes ? partBytes : attBytes);
  double* part = (double*)uni;
  float*  att  = (float*)uni;
  (void)ws_size; (void)in_sizes; (void)n_in; (void)out_size;

  hash_kernel<<<2 * BHc * Nc / 256, 256, 0, stream>>>(q, k, pd, hq, hk);
  sort_kernel<<<dim3(BHc, 2), 512, 0, stream>>>(hq, hk, qidx, kidx, qblk);
  gram_partial_kernel<<<BHc * NCHUNK, 256, 0, stream>>>(v, part);
  gram_reduce_kernel<<<(BHc * D1c * D1c + 255) / 256, 256, 0, stream>>>(part, gram);
  power_kernel<<<BHc, 128, 0, stream>>>(gram, pm, sigm);
  p_partial_kernel<<<BHc * 8, 256, 0, stream>>>(v, kidx, sigm, Pun, psum);
  p_final_kernel<<<BHc * Nc / 256, 256, 0, stream>>>(Pun, psum, P, logP);
  sample_kernel<<<BHc * Sc, 256, 0, stream>>>(logP, kidx, P, k, v, Khg, WhTg, sblk);
  sparse_kernel<<<BHc * NBc * 4, 256, 0, stream>>>(q, k, v, qidx, kidx, att);  // writes att (over part)
  residual_kernel<<<BHc * 64, 256, 0, stream>>>(q, Khg, WhTg, sblk, qblk, att, out);
}

// Round 14
// 453.336 us; speedup vs baseline: 2.3698x; 1.2034x over previous
//
#include <hip/hip_runtime.h>
#include <stdint.h>
#include <math.h>

// ---------------------------------------------------------------------------
// CosineHammingAttention — bit-faithful HIP port of the JAX reference.
// B=2 H=8 N=4096 D=64, NUM_PROJS=7, BUCKET=256, SAMPLE=800, PM_ITERS=32
// R2: parallelize Gram.  R3/R8/R10: f32 attention ladder (boxed ~400us).
// R11: residual -> MFMA bf16 (S^T = K*Q^T, P->LDS A-layout, O = P*WhT,
//     rows padded to 72 bf16) — 869->546us, absmax 3.9e-3.
// R12: sparse -> same MFMA structure. Gathered K staged bf16 [64][72];
//     V^T staged bf16 [80][72] via in-LDS transpose (rows 64..79 constant:
//     64 = ones column, 65..79 = 0). Same fragment maps as R11 residual.
// R13: identical resubmit (infra failure, no signal).
// ---------------------------------------------------------------------------

typedef unsigned int u32;
typedef __attribute__((ext_vector_type(8))) short bf16x8;
typedef __attribute__((ext_vector_type(4))) float f32x4;

namespace {
constexpr int Bc = 2, Hc = 8, BHc = 16;
constexpr int Nc = 4096, Dc = 64, D1c = 65;
constexpr int NBc = 16;      // N / BUCKET
constexpr int Sc = 800;      // SAMPLE
constexpr int PMITERc = 32;
constexpr int GCH = 128;             // Gram rows per chunk
constexpr int NCHUNK = Nc / GCH;     // 32
}

__device__ __forceinline__ u32 rotl32(u32 x, u32 d) { return (x << d) | (x >> (32u - d)); }

__device__ __forceinline__ unsigned short f2bf(float f) {  // RNE f32 -> bf16
  u32 u = __float_as_uint(f);
  u += 0x7FFFu + ((u >> 16) & 1u);
  return (unsigned short)(u >> 16);
}

// Exact JAX threefry2x32 (20 rounds).
__device__ __forceinline__ void threefry2x32(u32 k0, u32 k1, u32 x0, u32 x1, u32& o0, u32& o1) {
  u32 ks2 = k0 ^ k1 ^ 0x1BD11BDAu;
  x0 += k0; x1 += k1;
#define TF_RND(r) { x0 += x1; x1 = rotl32(x1, r); x1 ^= x0; }
  TF_RND(13) TF_RND(15) TF_RND(26) TF_RND(6)
  x0 += k1; x1 += ks2 + 1u;
  TF_RND(17) TF_RND(29) TF_RND(16) TF_RND(24)
  x0 += ks2; x1 += k0 + 2u;
  TF_RND(13) TF_RND(15) TF_RND(26) TF_RND(6)
  x0 += k0; x1 += k1 + 3u;
  TF_RND(17) TF_RND(29) TF_RND(16) TF_RND(24)
  x0 += k1; x1 += ks2 + 4u;
  TF_RND(13) TF_RND(15) TF_RND(26) TF_RND(6)
  x0 += ks2; x1 += k0 + 5u;
#undef TF_RND
  o0 = x0; o1 = x1;
}

// gumbel sample for flat element i of the (800,16,4096) array, key = (0,1234)
__device__ __forceinline__ float gumbel_at(u32 i) {
  u32 o0, o1;
  threefry2x32(0u, 1234u, 0u, i, o0, o1);
  u32 bits = o0 ^ o1;
  u32 fb = (bits >> 9) | 0x3f800000u;
  float u = __uint_as_float(fb) - 1.0f;           // [0,1) on 2^-23 grid
  if (u == 0.0f) u = 1.1754944e-38f;              // max(tiny, u) per jax.random.uniform
  return -__logf(-__logf(u));
}

// ---- K1: LSH hash codes for q and k ---------------------------------------
__global__ __launch_bounds__(256) void hash_kernel(
    const float* __restrict__ q, const float* __restrict__ k,
    const float* __restrict__ pd, int* __restrict__ hq, int* __restrict__ hk) {
  int tid = blockIdx.x * 256 + threadIdx.x;
  int which = tid / (BHc * Nc);
  int rem = tid % (BHc * Nc);
  int bh = rem / Nc, n = rem % Nc;
  int b = bh / Hc, h = bh % Hc;
  const float* x = which ? k : q;
  const float* row = x + (((size_t)b * Nc + n) * Hc + h) * Dc;   // [B,N,H,D]
  const float* pdr = pd + (size_t)bh * Dc * 7;                   // [B,H,D,7]
  double acc[7];
#pragma unroll
  for (int r = 0; r < 7; r++) acc[r] = 0.0;
  for (int d = 0; d < Dc; d++) {
    double vv = (double)row[d];
    const float* pr = pdr + d * 7;
#pragma unroll
    for (int r = 0; r < 7; r++) acc[r] += vv * (double)pr[r];
  }
  int code = 0;
#pragma unroll
  for (int r = 0; r < 7; r++) code |= (acc[r] > 0.0) ? (1 << r) : 0;
  int hash = code ^ (code >> 1);   // _hamming_perm == binary-reflected Gray code
  (which ? hk : hq)[bh * Nc + n] = hash;
}

// ---- K2: stable counting sort, quarter-split; q-branch also writes qblk ---
__global__ __launch_bounds__(512) void sort_kernel(
    const int* __restrict__ hq, const int* __restrict__ hk,
    int* __restrict__ qidx, int* __restrict__ kidx, int* __restrict__ qblk) {
  __shared__ int sh[Nc];
  __shared__ int cnt[4][128];
  __shared__ int off[128];
  int bh = blockIdx.x;
  int which = blockIdx.y;
  const int* hash = which ? hk : hq;
  int* out = which ? kidx : qidx;
  int t = threadIdx.x;
  for (int i = t; i < Nc; i += 512) sh[i] = hash[bh * Nc + i];
  __syncthreads();
  int qr = t >> 7, b = t & 127;      // quarter, bin
  int c = 0;
  for (int i = qr * 1024; i < (qr + 1) * 1024; i++) c += (sh[i] == b);
  cnt[qr][b] = c;
  __syncthreads();
  if (t == 0) {
    int run = 0;
    for (int j = 0; j < 128; j++) {
      int tot = cnt[0][j] + cnt[1][j] + cnt[2][j] + cnt[3][j];
      off[j] = run; run += tot;
    }
  }
  __syncthreads();
  int o = off[b];
  for (int qq = 0; qq < qr; qq++) o += cnt[qq][b];
  for (int i = qr * 1024; i < (qr + 1) * 1024; i++)
    if (sh[i] == b) {
      out[bh * Nc + o] = i;
      if (which == 0) qblk[bh * Nc + i] = o >> 8;
      o++;
    }
}

// ---- K4: block-sparse attention via MFMA (bf16) ---------------------------
// Block = (bh, bucket g, quadrant qq): 64 q-rows x 256 keys (4 tiles of 64).
// Per tile: stage gathered K bf16 [64][72], V^T bf16 [80][72] (rows 64..79
// constant: 64 = ones, 65..79 = 0). S^T = K*Q^T -> exp -> P bf16 (A-layout)
// -> O += P*W^T. Fragment maps identical to R11 residual (ref-checked).
__global__ __launch_bounds__(256) void sparse_kernel(
    const float* __restrict__ q, const float* __restrict__ k, const float* __restrict__ v,
    const int* __restrict__ qidx, const int* __restrict__ kidx, float* __restrict__ att) {
  __shared__ unsigned short sm[14976];  // Kh[64][72] | WT[80][72] | P[64][72]
  unsigned short* KhL = sm;             // 4608
  unsigned short* WTL = sm + 4608;      // 5760
  unsigned short* PL  = sm + 10368;     // 4608
  int blk = blockIdx.x;
  int bh = blk >> 6;
  int rem = blk & 63;
  int g = rem >> 2, qq = rem & 3;
  int b = bh / Hc, h = bh % Hc;
  int t = threadIdx.x;
  int w = t >> 6, l = t & 63;
  int l15 = l & 15, l4 = l >> 4;
  // Q fragments (B-operand): q-row-in-group = 16w + l15 (sorted order)
  int qpos = g * 256 + qq * 64 + 16 * w + l15;
  int nq = qidx[bh * Nc + qpos];
  const float* qrow = q + (((size_t)b * Nc + nq) * Hc + h) * Dc;
  bf16x8 qf[2];
#pragma unroll
  for (int kb = 0; kb < 2; kb++) {
    const float* srcq = qrow + kb * 32 + l4 * 8;
    float4 f0 = ((const float4*)srcq)[0];
    float4 f1 = ((const float4*)srcq)[1];
    bf16x8 vq;
    vq[0] = (short)f2bf(f0.x); vq[1] = (short)f2bf(f0.y);
    vq[2] = (short)f2bf(f0.z); vq[3] = (short)f2bf(f0.w);
    vq[4] = (short)f2bf(f1.x); vq[5] = (short)f2bf(f1.y);
    vq[6] = (short)f2bf(f1.z); vq[7] = (short)f2bf(f1.w);
    qf[kb] = vq;
  }
  f32x4 oacc[5];
#pragma unroll
  for (int nt = 0; nt < 5; nt++) oacc[nt] = (f32x4){0.f, 0.f, 0.f, 0.f};
  // constant WT rows: 64 = ones column of v_aug, 65..79 = 0 (once; staging
  // only touches rows 0..63)
  for (int idx = t; idx < 16 * 64; idx += 256) {
    int r = idx >> 6, s = idx & 63;
    WTL[(64 + r) * 72 + s] = (r == 0) ? (unsigned short)0x3F80 : (unsigned short)0;
  }
  const int* kidxB = kidx + bh * Nc + g * 256;
  for (int tile = 0; tile < 4; tile++) {
    __syncthreads();   // previous tile's LDS fully consumed
    for (int idx = t; idx < 64 * 16; idx += 256) {
      int j = idx >> 4, d4 = idx & 15;
      int m = kidxB[tile * 64 + j];
      const float* kr = k + (((size_t)b * Nc + m) * Hc + h) * Dc;
      const float* vr = v + (((size_t)b * Nc + m) * Hc + h) * Dc;
      float4 kv = ((const float4*)kr)[d4];
      uint2 pk;
      pk.x = (u32)f2bf(kv.x) | ((u32)f2bf(kv.y) << 16);
      pk.y = (u32)f2bf(kv.z) | ((u32)f2bf(kv.w) << 16);
      *(uint2*)&KhL[j * 72 + 4 * d4] = pk;
      float4 vv = ((const float4*)vr)[d4];
      WTL[(4 * d4 + 0) * 72 + j] = f2bf(vv.x);   // in-LDS transpose
      WTL[(4 * d4 + 1) * 72 + j] = f2bf(vv.y);
      WTL[(4 * d4 + 2) * 72 + j] = f2bf(vv.z);
      WTL[(4 * d4 + 3) * 72 + j] = f2bf(vv.w);
    }
    __syncthreads();
    // S^T = K * Q^T  (M = key, N = q, K-dim = D = 64)
    f32x4 sacc[4];
#pragma unroll
    for (int mt = 0; mt < 4; mt++) sacc[mt] = (f32x4){0.f, 0.f, 0.f, 0.f};
#pragma unroll
    for (int kb = 0; kb < 2; kb++) {
#pragma unroll
      for (int mt = 0; mt < 4; mt++) {
        bf16x8 ka = *(const bf16x8*)&KhL[(mt * 16 + l15) * 72 + kb * 32 + l4 * 8];
        sacc[mt] = __builtin_amdgcn_mfma_f32_16x16x32_bf16(ka, qf[kb], sacc[mt], 0, 0, 0);
      }
    }
    // exp -> P bf16 -> LDS (row = q-row 16w+l15, col = key; same-wave RAW ok)
#pragma unroll
    for (int mt = 0; mt < 4; mt++) {
      int sb = mt * 16 + l4 * 4;
      unsigned short p0 = f2bf(__expf(sacc[mt][0]));
      unsigned short p1 = f2bf(__expf(sacc[mt][1]));
      unsigned short p2 = f2bf(__expf(sacc[mt][2]));
      unsigned short p3 = f2bf(__expf(sacc[mt][3]));
      uint2 pk;
      pk.x = (u32)p0 | ((u32)p1 << 16);
      pk.y = (u32)p2 | ((u32)p3 << 16);
      *(uint2*)&PL[(16 * w + l15) * 72 + sb] = pk;
    }
    // PV: O += P * WT  (K-dim = 64 keys, 2 blocks)
#pragma unroll
    for (int kb = 0; kb < 2; kb++) {
      bf16x8 pa = *(const bf16x8*)&PL[(16 * w + l15) * 72 + kb * 32 + l4 * 8];
#pragma unroll
      for (int nt = 0; nt < 5; nt++) {
        bf16x8 wb = *(const bf16x8*)&WTL[(nt * 16 + l15) * 72 + kb * 32 + l4 * 8];
        oacc[nt] = __builtin_amdgcn_mfma_f32_16x16x32_bf16(pa, wb, oacc[nt], 0, 0, 0);
      }
    }
  }
  // epilogue: C row = q-row-in-group 16w + l4*4 + i, col = nt*16 + l15;
  // scatter to original order via qidx
#pragma unroll
  for (int i = 0; i < 4; i++) {
    int qrw = 16 * w + l4 * 4 + i;
    int nqi = qidx[bh * Nc + g * 256 + qq * 64 + qrw];
    float* arow = att + ((size_t)bh * Nc + nqi) * D1c;
#pragma unroll
    for (int nt = 0; nt < 4; nt++) arow[nt * 16 + l15] = oacc[nt][i];
    if (l15 == 0) arow[Dc] = oacc[4][i];   // col 64 = denominator
  }
}

// ---- K5a: partial Gram over 128-row chunks (f32 accum, grid = BH*32) ------
__global__ __launch_bounds__(256) void gram_partial_kernel(
    const float* __restrict__ v, double* __restrict__ part) {
  __shared__ float ch[GCH][D1c];
  int bh = blockIdx.x / NCHUNK, c = blockIdx.x % NCHUNK;
  int b = bh / Hc, h = bh % Hc;
  int t = threadIdx.x;
  for (int e = t; e < GCH * D1c; e += 256) {
    int r = e / D1c, p = e % D1c;
    int n = c * GCH + r;
    ch[r][p] = (p < Dc) ? v[(((size_t)b * Nc + n) * Hc + h) * Dc + p] : 1.0f;
  }
  __syncthreads();
  for (int pi = t; pi < D1c * D1c; pi += 256) {
    int tt = pi / D1c, uu = pi % D1c;
    float a = 0.0f;
    for (int r = 0; r < GCH; r++) a += ch[r][tt] * ch[r][uu];
    part[((size_t)bh * NCHUNK + c) * (D1c * D1c) + pi] = (double)a;
  }
}

// ---- K5b: reduce chunk partials (fixed order -> deterministic) ------------
__global__ __launch_bounds__(256) void gram_reduce_kernel(
    const double* __restrict__ part, double* __restrict__ gram) {
  int idx = blockIdx.x * 256 + threadIdx.x;   // over BH * 4225
  if (idx >= BHc * D1c * D1c) return;
  int bh = idx / (D1c * D1c), pi = idx % (D1c * D1c);
  double s = 0.0;
  for (int c = 0; c < NCHUNK; c++)
    s += part[((size_t)bh * NCHUNK + c) * (D1c * D1c) + pi];
  gram[(size_t)bh * (D1c * D1c) + pi] = s;
}

// ---- K6: power method for spectral norm -----------------------------------
__global__ __launch_bounds__(128) void power_kernel(
    const double* __restrict__ gram, const float* __restrict__ pm, double* __restrict__ sigma) {
  __shared__ double G[D1c * D1c];
  __shared__ double x[D1c], y[D1c];
  __shared__ double nrm;
  int bh = blockIdx.x, t = threadIdx.x;
  for (int e = t; e < D1c * D1c; e += 128) G[e] = gram[(size_t)bh * D1c * D1c + e];
  if (t < D1c) x[t] = (double)pm[bh * D1c + t];
  __syncthreads();
  if (t == 0) {
    double s = 0; for (int i = 0; i < D1c; i++) s += x[i] * x[i];
    nrm = sqrt(s);
  }
  __syncthreads();
  if (t < D1c) x[t] /= nrm;
  for (int it = 0; it < PMITERc; it++) {
    __syncthreads();
    if (t < D1c) {
      double s = 0;
      for (int u = 0; u < D1c; u++) s += G[t * D1c + u] * x[u];
      y[t] = s;
    }
    __syncthreads();
    if (t == 0) {
      double s = 0; for (int i = 0; i < D1c; i++) s += y[i] * y[i];
      nrm = sqrt(s);
    }
    __syncthreads();
    if (t < D1c) x[t] = y[t] / nrm;
  }
  __syncthreads();
  if (t == 0) sigma[bh] = nrm;
}

// ---- K7a: unnormalized P + per-segment partial sums (grid = BH*8) ---------
__global__ __launch_bounds__(256) void p_partial_kernel(
    const float* __restrict__ v, const int* __restrict__ kidx,
    const double* __restrict__ sigma, double* __restrict__ Pun, double* __restrict__ psum) {
  __shared__ double red[256];
  int blk = blockIdx.x;
  int bh = blk >> 3, seg = blk & 7;
  int b = bh / Hc, h = bh % Hc;
  int t = threadIdx.x;
  double sg = sigma[bh];
  double part = 0.0;
  for (int n = seg * 512 + t; n < (seg + 1) * 512; n += 256) {
    int m = kidx[bh * Nc + n];
    const float* vr = v + (((size_t)b * Nc + m) * Hc + h) * Dc;
    double ss = 1.0;  // the appended 1.0 component of v_aug
    for (int d = 0; d < Dc; d++) { double vv = vr[d]; ss += vv * vv; }
    double Pd = sqrt(ss) / sg + (1.0 / (double)Nc);
    Pun[bh * Nc + n] = Pd;
    part += Pd;
  }
  red[t] = part;
  __syncthreads();
  for (int w = 128; w > 0; w >>= 1) {
    if (t < w) red[t] += red[t + w];
    __syncthreads();
  }
  if (t == 0) psum[blk] = red[0];
}

// ---- K7b: normalize + log -------------------------------------------------
__global__ __launch_bounds__(256) void p_final_kernel(
    const double* __restrict__ Pun, const double* __restrict__ psum,
    float* __restrict__ P, float* __restrict__ logP) {
  int idx = blockIdx.x * 256 + threadIdx.x;   // over BH*N
  int bh = idx / Nc;
  double tot = 0.0;
#pragma unroll
  for (int s = 0; s < 8; s++) tot += psum[bh * 8 + s];
  float Pf = (float)(Pun[idx] / tot);
  P[idx] = Pf;
  logP[idx] = logf(Pf);
}

// ---- K8: categorical sampling + fused gather (bf16 K / transposed bf16 W) -
__global__ __launch_bounds__(256) void sample_kernel(
    const float* __restrict__ logP, const int* __restrict__ kidx,
    const float* __restrict__ P, const float* __restrict__ key, const float* __restrict__ value,
    unsigned short* __restrict__ Khg,   // [BH][800][64] bf16
    unsigned short* __restrict__ WhTg,  // [BH][80][800] bf16 (transposed, cols 65..79 = 0)
    int* __restrict__ sblk) {
  __shared__ float sv[256];
  __shared__ int si[256];
  int blk = blockIdx.x;           // bh*S + s
  int bh = blk / Sc, s = blk % Sc;
  int b = bh / Hc, h = bh % Hc;
  int t = threadIdx.x;
  float best = -3.4e38f; int besti = Nc;
  const float* lp = logP + bh * Nc;
  u32 base = ((u32)(s * BHc + bh)) * (u32)Nc;  // flat index into (800,16,4096)
  for (int n = t; n < Nc; n += 256) {
    float val = gumbel_at(base + (u32)n) + lp[n];
    if (val > best || (val == best && n < besti)) { best = val; besti = n; }
  }
  sv[t] = best; si[t] = besti;
  __syncthreads();
  for (int w = 128; w > 0; w >>= 1) {
    if (t < w) {
      float v2 = sv[t + w]; int i2 = si[t + w];
      if (v2 > sv[t] || (v2 == sv[t] && i2 < si[t])) { sv[t] = v2; si[t] = i2; }
    }
    __syncthreads();
  }
  int m = si[0];
  if (t == 0) sblk[blk] = m >> 8;
  int src = kidx[bh * Nc + m];
  float sg = 1.0f / (P[bh * Nc + m] * (float)Sc);
  const float* kr = key + (((size_t)b * Nc + src) * Hc + h) * Dc;
  const float* vr = value + (((size_t)b * Nc + src) * Hc + h) * Dc;
  if (t < Dc) Khg[((size_t)bh * Sc + s) * 64 + t] = f2bf(kr[t]);
  if (t < 80) {
    float val = (t < Dc) ? sg * vr[t] : ((t == Dc) ? sg : 0.0f);
    WhTg[((size_t)bh * 80 + t) * Sc + s] = f2bf(val);
  }
}

// ---- K10: residual attention via MFMA (bf16) ------------------------------
__global__ __launch_bounds__(256) void residual_kernel(
    const float* __restrict__ q,
    const unsigned short* __restrict__ Khg, const unsigned short* __restrict__ WhTg,
    const int* __restrict__ sblk,
    const int* __restrict__ qblk, const float* __restrict__ att, float* __restrict__ out) {
  __shared__ unsigned short sm[14976];  // Kh[64][72] | WhT[80][72] | P[64][72]
  __shared__ int bl[64];
  unsigned short* KhL = sm;             // 4608
  unsigned short* WTL = sm + 4608;      // 5760
  unsigned short* PL  = sm + 10368;     // 4608
  int blk = blockIdx.x;
  int bh = blk >> 6;
  int n0 = (blk & 63) * 64;
  int b = bh / Hc, h = bh % Hc;
  int t = threadIdx.x;
  int w = t >> 6, l = t & 63;
  int l15 = l & 15, l4 = l >> 4;
  int nq = n0 + 16 * w + l15;
  const float* qrow = q + (((size_t)b * Nc + nq) * Hc + h) * Dc;
  bf16x8 qf[2];
#pragma unroll
  for (int kb = 0; kb < 2; kb++) {
    const float* srcq = qrow + kb * 32 + l4 * 8;
    float4 f0 = ((const float4*)srcq)[0];
    float4 f1 = ((const float4*)srcq)[1];
    bf16x8 vq;
    vq[0] = (short)f2bf(f0.x); vq[1] = (short)f2bf(f0.y);
    vq[2] = (short)f2bf(f0.z); vq[3] = (short)f2bf(f0.w);
    vq[4] = (short)f2bf(f1.x); vq[5] = (short)f2bf(f1.y);
    vq[6] = (short)f2bf(f1.z); vq[7] = (short)f2bf(f1.w);
    qf[kb] = vq;
  }
  int qb = qblk[bh * Nc + nq];
  f32x4 oacc[5];
#pragma unroll
  for (int nt = 0; nt < 5; nt++) oacc[nt] = (f32x4){0.f, 0.f, 0.f, 0.f};
  const unsigned short* KhB = Khg + (size_t)bh * Sc * 64;
  const unsigned short* WTB = WhTg + (size_t)bh * 80 * Sc;
  const int* sblkB = sblk + bh * Sc;
  for (int tile = 0; tile < 13; tile++) {
    int s0 = tile * 64;
    int cnt = (tile < 12) ? 64 : 32;
    for (int idx = t; idx < cnt * 8; idx += 256) {
      int r = idx >> 3, sg = idx & 7;
      *(uint4*)&KhL[r * 72 + sg * 8] = *(const uint4*)&KhB[(size_t)(s0 + r) * 64 + sg * 8];
    }
    int ssh = (cnt == 64) ? 3 : 2;
    int segs = cnt >> 3;
    for (int idx = t; idx < 80 * segs; idx += 256) {
      int c = idx >> ssh, sg = idx & (segs - 1);
      *(uint4*)&WTL[c * 72 + sg * 8] = *(const uint4*)&WTB[(size_t)c * Sc + s0 + sg * 8];
    }
    if (t < cnt) bl[t] = sblkB[s0 + t];
    __syncthreads();
    int mtn = cnt >> 4;
    f32x4 sacc[4];
#pragma unroll
    for (int mt = 0; mt < 4; mt++) sacc[mt] = (f32x4){0.f, 0.f, 0.f, 0.f};
#pragma unroll
    for (int kb = 0; kb < 2; kb++) {
#pragma unroll
      for (int mt = 0; mt < 4; mt++) {
        if (mt >= mtn) break;
        bf16x8 ka = *(const bf16x8*)&KhL[(mt * 16 + l15) * 72 + kb * 32 + l4 * 8];
        sacc[mt] = __builtin_amdgcn_mfma_f32_16x16x32_bf16(ka, qf[kb], sacc[mt], 0, 0, 0);
      }
    }
#pragma unroll
    for (int mt = 0; mt < 4; mt++) {
      if (mt >= mtn) break;
      int sb = mt * 16 + l4 * 4;
      unsigned short p0 = (bl[sb + 0] == qb) ? 0 : f2bf(__expf(sacc[mt][0]));
      unsigned short p1 = (bl[sb + 1] == qb) ? 0 : f2bf(__expf(sacc[mt][1]));
      unsigned short p2 = (bl[sb + 2] == qb) ? 0 : f2bf(__expf(sacc[mt][2]));
      unsigned short p3 = (bl[sb + 3] == qb) ? 0 : f2bf(__expf(sacc[mt][3]));
      uint2 pk;
      pk.x = (u32)p0 | ((u32)p1 << 16);
      pk.y = (u32)p2 | ((u32)p3 << 16);
      *(uint2*)&PL[(16 * w + l15) * 72 + sb] = pk;
    }
    int kbn = cnt >> 5;
#pragma unroll
    for (int kb = 0; kb < 2; kb++) {
      if (kb >= kbn) break;
      bf16x8 pa = *(const bf16x8*)&PL[(16 * w + l15) * 72 + kb * 32 + l4 * 8];
#pragma unroll
      for (int nt = 0; nt < 5; nt++) {
        bf16x8 wb = *(const bf16x8*)&WTL[(nt * 16 + l15) * 72 + kb * 32 + l4 * 8];
        oacc[nt] = __builtin_amdgcn_mfma_f32_16x16x32_bf16(pa, wb, oacc[nt], 0, 0, 0);
      }
    }
    __syncthreads();
  }
  float den[4];
#pragma unroll
  for (int i = 0; i < 4; i++) {
    int n = n0 + 16 * w + l4 * 4 + i;
    const float* arow = att + ((size_t)bh * Nc + n) * D1c;
    float cand = (l15 == 0) ? (arow[Dc] + oacc[4][i]) : 0.f;
    den[i] = __shfl(cand, l & 48);   // broadcast from col-64 lane of this group
  }
#pragma unroll
  for (int i = 0; i < 4; i++) {
    int n = n0 + 16 * w + l4 * 4 + i;
    const float* arow = att + ((size_t)bh * Nc + n) * D1c;
    float* orow = out + ((size_t)bh * Nc + n) * Dc;
#pragma unroll
    for (int nt = 0; nt < 4; nt++) {
      int c = nt * 16 + l15;
      orow[c] = (arow[c] + oacc[nt][i]) / den[i];
    }
  }
}

// ---------------------------------------------------------------------------
extern "C" void kernel_launch(void* const* d_in, const int* in_sizes, int n_in,
                              void* d_out, int out_size, void* d_ws, size_t ws_size,
                              hipStream_t stream) {
  const float* q  = (const float*)d_in[0];
  const float* k  = (const float*)d_in[1];
  const float* v  = (const float*)d_in[2];
  const float* pd = (const float*)d_in[3];
  const float* pm = (const float*)d_in[4];
  float* out = (float*)d_out;

  char* w = (char*)d_ws;
  size_t off = 0;
  auto take = [&](size_t nbytes) -> void* {
    void* p = w + off;
    off += (nbytes + 255) & ~(size_t)255;
    return p;
  };
  double* gram = (double*)take((size_t)BHc * D1c * D1c * sizeof(double));
  double* sigm = (double*)take((size_t)BHc * sizeof(double));
  double* Pun  = (double*)take((size_t)BHc * Nc * sizeof(double));
  double* psum = (double*)take((size_t)BHc * 8 * sizeof(double));
  int* hq   = (int*)take((size_t)BHc * Nc * 4);
  int* hk   = (int*)take((size_t)BHc * Nc * 4);
  int* qidx = (int*)take((size_t)BHc * Nc * 4);
  int* kidx = (int*)take((size_t)BHc * Nc * 4);
  int* qblk = (int*)take((size_t)BHc * Nc * 4);
  float* P    = (float*)take((size_t)BHc * Nc * 4);
  float* logP = (float*)take((size_t)BHc * Nc * 4);
  int* sblk = (int*)take((size_t)BHc * Sc * 4);
  unsigned short* Khg  = (unsigned short*)take((size_t)BHc * Sc * 64 * 2);
  unsigned short* WhTg = (unsigned short*)take((size_t)BHc * 80 * Sc * 2);
  // union region: Gram chunk partials (used first), then att (written after
  // gram_reduce has consumed the partials — stream order guarantees this).
  size_t partBytes = (size_t)BHc * NCHUNK * D1c * D1c * sizeof(double);
  size_t attBytes  = (size_t)BHc * Nc * D1c * 4;
  void* uni = take(partBytes > attBytes ? partBytes : attBytes);
  double* part = (double*)uni;
  float*  att  = (float*)uni;
  (void)ws_size; (void)in_sizes; (void)n_in; (void)out_size;

  hash_kernel<<<2 * BHc * Nc / 256, 256, 0, stream>>>(q, k, pd, hq, hk);
  sort_kernel<<<dim3(BHc, 2), 512, 0, stream>>>(hq, hk, qidx, kidx, qblk);
  gram_partial_kernel<<<BHc * NCHUNK, 256, 0, stream>>>(v, part);
  gram_reduce_kernel<<<(BHc * D1c * D1c + 255) / 256, 256, 0, stream>>>(part, gram);
  power_kernel<<<BHc, 128, 0, stream>>>(gram, pm, sigm);
  p_partial_kernel<<<BHc * 8, 256, 0, stream>>>(v, kidx, sigm, Pun, psum);
  p_final_kernel<<<BHc * Nc / 256, 256, 0, stream>>>(Pun, psum, P, logP);
  sample_kernel<<<BHc * Sc, 256, 0, stream>>>(logP, kidx, P, k, v, Khg, WhTg, sblk);
  sparse_kernel<<<BHc * NBc * 4, 256, 0, stream>>>(q, k, v, qidx, kidx, att);  // writes att (over part)
  residual_kernel<<<BHc * 64, 256, 0, stream>>>(q, Khg, WhTg, sblk, qblk, att, out);
}

// Round 17
// 452.359 us; speedup vs baseline: 2.3749x; 1.0022x over previous
//
#include <hip/hip_runtime.h>
#include <stdint.h>
#include <math.h>

// ---------------------------------------------------------------------------
// CosineHammingAttention — bit-faithful HIP port of the JAX reference.
// B=2 H=8 N=4096 D=64, NUM_PROJS=7, BUCKET=256, SAMPLE=800, PM_ITERS=32
// R2: parallelize Gram.  R3/R8/R10: f32 attention ladder (boxed ~400us).
// R11: residual -> MFMA bf16 — 869->546us, absmax 3.9e-3.
// R12: sparse -> MFMA bf16 — 546->453us (PASSED, profiled).
// R14: sample one-log transform + LDS staging — timed out TWICE (different
//     failure mode from earlier instant infra errors; audit finds no hang).
// R16: DISAMBIGUATE: exact R12 math everywhere; only change vs known-good
//     R12 = sample_kernel stages logP into LDS (removes chained global-load
//     latency). One-log transform and invP reverted.
// ---------------------------------------------------------------------------

typedef unsigned int u32;
typedef __attribute__((ext_vector_type(8))) short bf16x8;
typedef __attribute__((ext_vector_type(4))) float f32x4;

namespace {
constexpr int Bc = 2, Hc = 8, BHc = 16;
constexpr int Nc = 4096, Dc = 64, D1c = 65;
constexpr int NBc = 16;      // N / BUCKET
constexpr int Sc = 800;      // SAMPLE
constexpr int PMITERc = 32;
constexpr int GCH = 128;             // Gram rows per chunk
constexpr int NCHUNK = Nc / GCH;     // 32
}

__device__ __forceinline__ u32 rotl32(u32 x, u32 d) { return (x << d) | (x >> (32u - d)); }

__device__ __forceinline__ unsigned short f2bf(float f) {  // RNE f32 -> bf16
  u32 u = __float_as_uint(f);
  u += 0x7FFFu + ((u >> 16) & 1u);
  return (unsigned short)(u >> 16);
}

// Exact JAX threefry2x32 (20 rounds).
__device__ __forceinline__ void threefry2x32(u32 k0, u32 k1, u32 x0, u32 x1, u32& o0, u32& o1) {
  u32 ks2 = k0 ^ k1 ^ 0x1BD11BDAu;
  x0 += k0; x1 += k1;
#define TF_RND(r) { x0 += x1; x1 = rotl32(x1, r); x1 ^= x0; }
  TF_RND(13) TF_RND(15) TF_RND(26) TF_RND(6)
  x0 += k1; x1 += ks2 + 1u;
  TF_RND(17) TF_RND(29) TF_RND(16) TF_RND(24)
  x0 += ks2; x1 += k0 + 2u;
  TF_RND(13) TF_RND(15) TF_RND(26) TF_RND(6)
  x0 += k0; x1 += k1 + 3u;
  TF_RND(17) TF_RND(29) TF_RND(16) TF_RND(24)
  x0 += k1; x1 += ks2 + 4u;
  TF_RND(13) TF_RND(15) TF_RND(26) TF_RND(6)
  x0 += ks2; x1 += k0 + 5u;
#undef TF_RND
  o0 = x0; o1 = x1;
}

// gumbel sample for flat element i of the (800,16,4096) array, key = (0,1234)
__device__ __forceinline__ float gumbel_at(u32 i) {
  u32 o0, o1;
  threefry2x32(0u, 1234u, 0u, i, o0, o1);
  u32 bits = o0 ^ o1;
  u32 fb = (bits >> 9) | 0x3f800000u;
  float u = __uint_as_float(fb) - 1.0f;           // [0,1) on 2^-23 grid
  if (u == 0.0f) u = 1.1754944e-38f;              // max(tiny, u) per jax.random.uniform
  return -__logf(-__logf(u));
}

// ---- K1: LSH hash codes for q and k ---------------------------------------
__global__ __launch_bounds__(256) void hash_kernel(
    const float* __restrict__ q, const float* __restrict__ k,
    const float* __restrict__ pd, int* __restrict__ hq, int* __restrict__ hk) {
  int tid = blockIdx.x * 256 + threadIdx.x;
  int which = tid / (BHc * Nc);
  int rem = tid % (BHc * Nc);
  int bh = rem / Nc, n = rem % Nc;
  int b = bh / Hc, h = bh % Hc;
  const float* x = which ? k : q;
  const float* row = x + (((size_t)b * Nc + n) * Hc + h) * Dc;   // [B,N,H,D]
  const float* pdr = pd + (size_t)bh * Dc * 7;                   // [B,H,D,7]
  double acc[7];
#pragma unroll
  for (int r = 0; r < 7; r++) acc[r] = 0.0;
  for (int d = 0; d < Dc; d++) {
    double vv = (double)row[d];
    const float* pr = pdr + d * 7;
#pragma unroll
    for (int r = 0; r < 7; r++) acc[r] += vv * (double)pr[r];
  }
  int code = 0;
#pragma unroll
  for (int r = 0; r < 7; r++) code |= (acc[r] > 0.0) ? (1 << r) : 0;
  int hash = code ^ (code >> 1);   // _hamming_perm == binary-reflected Gray code
  (which ? hk : hq)[bh * Nc + n] = hash;
}

// ---- K2: stable counting sort, quarter-split; q-branch also writes qblk ---
__global__ __launch_bounds__(512) void sort_kernel(
    const int* __restrict__ hq, const int* __restrict__ hk,
    int* __restrict__ qidx, int* __restrict__ kidx, int* __restrict__ qblk) {
  __shared__ int sh[Nc];
  __shared__ int cnt[4][128];
  __shared__ int off[128];
  int bh = blockIdx.x;
  int which = blockIdx.y;
  const int* hash = which ? hk : hq;
  int* out = which ? kidx : qidx;
  int t = threadIdx.x;
  for (int i = t; i < Nc; i += 512) sh[i] = hash[bh * Nc + i];
  __syncthreads();
  int qr = t >> 7, b = t & 127;      // quarter, bin
  int c = 0;
  for (int i = qr * 1024; i < (qr + 1) * 1024; i++) c += (sh[i] == b);
  cnt[qr][b] = c;
  __syncthreads();
  if (t == 0) {
    int run = 0;
    for (int j = 0; j < 128; j++) {
      int tot = cnt[0][j] + cnt[1][j] + cnt[2][j] + cnt[3][j];
      off[j] = run; run += tot;
    }
  }
  __syncthreads();
  int o = off[b];
  for (int qq = 0; qq < qr; qq++) o += cnt[qq][b];
  for (int i = qr * 1024; i < (qr + 1) * 1024; i++)
    if (sh[i] == b) {
      out[bh * Nc + o] = i;
      if (which == 0) qblk[bh * Nc + i] = o >> 8;
      o++;
    }
}

// ---- K4: block-sparse attention via MFMA (bf16) ---------------------------
__global__ __launch_bounds__(256) void sparse_kernel(
    const float* __restrict__ q, const float* __restrict__ k, const float* __restrict__ v,
    const int* __restrict__ qidx, const int* __restrict__ kidx, float* __restrict__ att) {
  __shared__ unsigned short sm[14976];  // Kh[64][72] | WT[80][72] | P[64][72]
  unsigned short* KhL = sm;             // 4608
  unsigned short* WTL = sm + 4608;      // 5760
  unsigned short* PL  = sm + 10368;     // 4608
  int blk = blockIdx.x;
  int bh = blk >> 6;
  int rem = blk & 63;
  int g = rem >> 2, qq = rem & 3;
  int b = bh / Hc, h = bh % Hc;
  int t = threadIdx.x;
  int w = t >> 6, l = t & 63;
  int l15 = l & 15, l4 = l >> 4;
  // Q fragments (B-operand): q-row-in-group = 16w + l15 (sorted order)
  int qpos = g * 256 + qq * 64 + 16 * w + l15;
  int nq = qidx[bh * Nc + qpos];
  const float* qrow = q + (((size_t)b * Nc + nq) * Hc + h) * Dc;
  bf16x8 qf[2];
#pragma unroll
  for (int kb = 0; kb < 2; kb++) {
    const float* srcq = qrow + kb * 32 + l4 * 8;
    float4 f0 = ((const float4*)srcq)[0];
    float4 f1 = ((const float4*)srcq)[1];
    bf16x8 vq;
    vq[0] = (short)f2bf(f0.x); vq[1] = (short)f2bf(f0.y);
    vq[2] = (short)f2bf(f0.z); vq[3] = (short)f2bf(f0.w);
    vq[4] = (short)f2bf(f1.x); vq[5] = (short)f2bf(f1.y);
    vq[6] = (short)f2bf(f1.z); vq[7] = (short)f2bf(f1.w);
    qf[kb] = vq;
  }
  f32x4 oacc[5];
#pragma unroll
  for (int nt = 0; nt < 5; nt++) oacc[nt] = (f32x4){0.f, 0.f, 0.f, 0.f};
  // constant WT rows: 64 = ones column of v_aug, 65..79 = 0
  for (int idx = t; idx < 16 * 64; idx += 256) {
    int r = idx >> 6, s = idx & 63;
    WTL[(64 + r) * 72 + s] = (r == 0) ? (unsigned short)0x3F80 : (unsigned short)0;
  }
  const int* kidxB = kidx + bh * Nc + g * 256;
  for (int tile = 0; tile < 4; tile++) {
    __syncthreads();   // previous tile's LDS fully consumed
    for (int idx = t; idx < 64 * 16; idx += 256) {
      int j = idx >> 4, d4 = idx & 15;
      int m = kidxB[tile * 64 + j];
      const float* kr = k + (((size_t)b * Nc + m) * Hc + h) * Dc;
      const float* vr = v + (((size_t)b * Nc + m) * Hc + h) * Dc;
      float4 kv = ((const float4*)kr)[d4];
      uint2 pk;
      pk.x = (u32)f2bf(kv.x) | ((u32)f2bf(kv.y) << 16);
      pk.y = (u32)f2bf(kv.z) | ((u32)f2bf(kv.w) << 16);
      *(uint2*)&KhL[j * 72 + 4 * d4] = pk;
      float4 vv = ((const float4*)vr)[d4];
      WTL[(4 * d4 + 0) * 72 + j] = f2bf(vv.x);   // in-LDS transpose
      WTL[(4 * d4 + 1) * 72 + j] = f2bf(vv.y);
      WTL[(4 * d4 + 2) * 72 + j] = f2bf(vv.z);
      WTL[(4 * d4 + 3) * 72 + j] = f2bf(vv.w);
    }
    __syncthreads();
    // S^T = K * Q^T  (M = key, N = q, K-dim = D = 64)
    f32x4 sacc[4];
#pragma unroll
    for (int mt = 0; mt < 4; mt++) sacc[mt] = (f32x4){0.f, 0.f, 0.f, 0.f};
#pragma unroll
    for (int kb = 0; kb < 2; kb++) {
#pragma unroll
      for (int mt = 0; mt < 4; mt++) {
        bf16x8 ka = *(const bf16x8*)&KhL[(mt * 16 + l15) * 72 + kb * 32 + l4 * 8];
        sacc[mt] = __builtin_amdgcn_mfma_f32_16x16x32_bf16(ka, qf[kb], sacc[mt], 0, 0, 0);
      }
    }
    // exp -> P bf16 -> LDS (row = q-row 16w+l15, col = key)
#pragma unroll
    for (int mt = 0; mt < 4; mt++) {
      int sb = mt * 16 + l4 * 4;
      unsigned short p0 = f2bf(__expf(sacc[mt][0]));
      unsigned short p1 = f2bf(__expf(sacc[mt][1]));
      unsigned short p2 = f2bf(__expf(sacc[mt][2]));
      unsigned short p3 = f2bf(__expf(sacc[mt][3]));
      uint2 pk;
      pk.x = (u32)p0 | ((u32)p1 << 16);
      pk.y = (u32)p2 | ((u32)p3 << 16);
      *(uint2*)&PL[(16 * w + l15) * 72 + sb] = pk;
    }
    // PV: O += P * WT  (K-dim = 64 keys, 2 blocks)
#pragma unroll
    for (int kb = 0; kb < 2; kb++) {
      bf16x8 pa = *(const bf16x8*)&PL[(16 * w + l15) * 72 + kb * 32 + l4 * 8];
#pragma unroll
      for (int nt = 0; nt < 5; nt++) {
        bf16x8 wb = *(const bf16x8*)&WTL[(nt * 16 + l15) * 72 + kb * 32 + l4 * 8];
        oacc[nt] = __builtin_amdgcn_mfma_f32_16x16x32_bf16(pa, wb, oacc[nt], 0, 0, 0);
      }
    }
  }
  // epilogue: scatter to original order via qidx
#pragma unroll
  for (int i = 0; i < 4; i++) {
    int qrw = 16 * w + l4 * 4 + i;
    int nqi = qidx[bh * Nc + g * 256 + qq * 64 + qrw];
    float* arow = att + ((size_t)bh * Nc + nqi) * D1c;
#pragma unroll
    for (int nt = 0; nt < 4; nt++) arow[nt * 16 + l15] = oacc[nt][i];
    if (l15 == 0) arow[Dc] = oacc[4][i];   // col 64 = denominator
  }
}

// ---- K5a: partial Gram over 128-row chunks (f32 accum, grid = BH*32) ------
__global__ __launch_bounds__(256) void gram_partial_kernel(
    const float* __restrict__ v, double* __restrict__ part) {
  __shared__ float ch[GCH][D1c];
  int bh = blockIdx.x / NCHUNK, c = blockIdx.x % NCHUNK;
  int b = bh / Hc, h = bh % Hc;
  int t = threadIdx.x;
  for (int e = t; e < GCH * D1c; e += 256) {
    int r = e / D1c, p = e % D1c;
    int n = c * GCH + r;
    ch[r][p] = (p < Dc) ? v[(((size_t)b * Nc + n) * Hc + h) * Dc + p] : 1.0f;
  }
  __syncthreads();
  for (int pi = t; pi < D1c * D1c; pi += 256) {
    int tt = pi / D1c, uu = pi % D1c;
    float a = 0.0f;
    for (int r = 0; r < GCH; r++) a += ch[r][tt] * ch[r][uu];
    part[((size_t)bh * NCHUNK + c) * (D1c * D1c) + pi] = (double)a;
  }
}

// ---- K5b: reduce chunk partials (fixed order -> deterministic) ------------
__global__ __launch_bounds__(256) void gram_reduce_kernel(
    const double* __restrict__ part, double* __restrict__ gram) {
  int idx = blockIdx.x * 256 + threadIdx.x;   // over BH * 4225
  if (idx >= BHc * D1c * D1c) return;
  int bh = idx / (D1c * D1c), pi = idx % (D1c * D1c);
  double s = 0.0;
  for (int c = 0; c < NCHUNK; c++)
    s += part[((size_t)bh * NCHUNK + c) * (D1c * D1c) + pi];
  gram[(size_t)bh * (D1c * D1c) + pi] = s;
}

// ---- K6: power method for spectral norm -----------------------------------
__global__ __launch_bounds__(128) void power_kernel(
    const double* __restrict__ gram, const float* __restrict__ pm, double* __restrict__ sigma) {
  __shared__ double G[D1c * D1c];
  __shared__ double x[D1c], y[D1c];
  __shared__ double nrm;
  int bh = blockIdx.x, t = threadIdx.x;
  for (int e = t; e < D1c * D1c; e += 128) G[e] = gram[(size_t)bh * D1c * D1c + e];
  if (t < D1c) x[t] = (double)pm[bh * D1c + t];
  __syncthreads();
  if (t == 0) {
    double s = 0; for (int i = 0; i < D1c; i++) s += x[i] * x[i];
    nrm = sqrt(s);
  }
  __syncthreads();
  if (t < D1c) x[t] /= nrm;
  for (int it = 0; it < PMITERc; it++) {
    __syncthreads();
    if (t < D1c) {
      double s = 0;
      for (int u = 0; u < D1c; u++) s += G[t * D1c + u] * x[u];
      y[t] = s;
    }
    __syncthreads();
    if (t == 0) {
      double s = 0; for (int i = 0; i < D1c; i++) s += y[i] * y[i];
      nrm = sqrt(s);
    }
    __syncthreads();
    if (t < D1c) x[t] = y[t] / nrm;
  }
  __syncthreads();
  if (t == 0) sigma[bh] = nrm;
}

// ---- K7a: unnormalized P + per-segment partial sums (grid = BH*8) ---------
__global__ __launch_bounds__(256) void p_partial_kernel(
    const float* __restrict__ v, const int* __restrict__ kidx,
    const double* __restrict__ sigma, double* __restrict__ Pun, double* __restrict__ psum) {
  __shared__ double red[256];
  int blk = blockIdx.x;
  int bh = blk >> 3, seg = blk & 7;
  int b = bh / Hc, h = bh % Hc;
  int t = threadIdx.x;
  double sg = sigma[bh];
  double part = 0.0;
  for (int n = seg * 512 + t; n < (seg + 1) * 512; n += 256) {
    int m = kidx[bh * Nc + n];
    const float* vr = v + (((size_t)b * Nc + m) * Hc + h) * Dc;
    double ss = 1.0;  // the appended 1.0 component of v_aug
    for (int d = 0; d < Dc; d++) { double vv = vr[d]; ss += vv * vv; }
    double Pd = sqrt(ss) / sg + (1.0 / (double)Nc);
    Pun[bh * Nc + n] = Pd;
    part += Pd;
  }
  red[t] = part;
  __syncthreads();
  for (int w = 128; w > 0; w >>= 1) {
    if (t < w) red[t] += red[t + w];
    __syncthreads();
  }
  if (t == 0) psum[blk] = red[0];
}

// ---- K7b: normalize + log (exact R12 semantics) ---------------------------
__global__ __launch_bounds__(256) void p_final_kernel(
    const double* __restrict__ Pun, const double* __restrict__ psum,
    float* __restrict__ P, float* __restrict__ logP) {
  int idx = blockIdx.x * 256 + threadIdx.x;   // over BH*N
  int bh = idx / Nc;
  double tot = 0.0;
#pragma unroll
  for (int s = 0; s < 8; s++) tot += psum[bh * 8 + s];
  float Pf = (float)(Pun[idx] / tot);
  P[idx] = Pf;
  logP[idx] = logf(Pf);
}

// ---- K8: categorical sampling (R12 math) + LDS-staged logP + fused gather -
__global__ __launch_bounds__(256) void sample_kernel(
    const float* __restrict__ logP, const int* __restrict__ kidx,
    const float* __restrict__ P, const float* __restrict__ key, const float* __restrict__ value,
    unsigned short* __restrict__ Khg,   // [BH][800][64] bf16
    unsigned short* __restrict__ WhTg,  // [BH][80][800] bf16 (transposed, cols 65..79 = 0)
    int* __restrict__ sblk) {
  __shared__ float lpl[Nc];       // 16 KB staged logP
  __shared__ float sv[256];
  __shared__ int si[256];
  int blk = blockIdx.x;           // bh*S + s
  int bh = blk / Sc, s = blk % Sc;
  int b = bh / Hc, h = bh % Hc;
  int t = threadIdx.x;
  const float* lpg = logP + bh * Nc;
  for (int it = 0; it < 16; it++) lpl[t + it * 256] = lpg[t + it * 256];
  __syncthreads();
  float best = -3.4e38f; int besti = Nc;
  u32 base = ((u32)(s * BHc + bh)) * (u32)Nc;  // flat index into (800,16,4096)
  for (int it = 0; it < 16; it++) {
    int n = t + it * 256;
    float val = gumbel_at(base + (u32)n) + lpl[n];
    if (val > best || (val == best && n < besti)) { best = val; besti = n; }
  }
  sv[t] = best; si[t] = besti;
  __syncthreads();
  for (int w = 128; w > 0; w >>= 1) {
    if (t < w) {
      float v2 = sv[t + w]; int i2 = si[t + w];
      if (v2 > sv[t] || (v2 == sv[t] && i2 < si[t])) { sv[t] = v2; si[t] = i2; }
    }
    __syncthreads();
  }
  int m = si[0];
  if (t == 0) sblk[blk] = m >> 8;
  int src = kidx[bh * Nc + m];
  float sg = 1.0f / (P[bh * Nc + m] * (float)Sc);
  const float* kr = key + (((size_t)b * Nc + src) * Hc + h) * Dc;
  const float* vr = value + (((size_t)b * Nc + src) * Hc + h) * Dc;
  if (t < Dc) Khg[((size_t)bh * Sc + s) * 64 + t] = f2bf(kr[t]);
  if (t < 80) {
    float val = (t < Dc) ? sg * vr[t] : ((t == Dc) ? sg : 0.0f);
    WhTg[((size_t)bh * 80 + t) * Sc + s] = f2bf(val);
  }
}

// ---- K10: residual attention via MFMA (bf16) ------------------------------
__global__ __launch_bounds__(256) void residual_kernel(
    const float* __restrict__ q,
    const unsigned short* __restrict__ Khg, const unsigned short* __restrict__ WhTg,
    const int* __restrict__ sblk,
    const int* __restrict__ qblk, const float* __restrict__ att, float* __restrict__ out) {
  __shared__ unsigned short sm[14976];  // Kh[64][72] | WhT[80][72] | P[64][72]
  __shared__ int bl[64];
  unsigned short* KhL = sm;             // 4608
  unsigned short* WTL = sm + 4608;      // 5760
  unsigned short* PL  = sm + 10368;     // 4608
  int blk = blockIdx.x;
  int bh = blk >> 6;
  int n0 = (blk & 63) * 64;
  int b = bh / Hc, h = bh % Hc;
  int t = threadIdx.x;
  int w = t >> 6, l = t & 63;
  int l15 = l & 15, l4 = l >> 4;
  int nq = n0 + 16 * w + l15;
  const float* qrow = q + (((size_t)b * Nc + nq) * Hc + h) * Dc;
  bf16x8 qf[2];
#pragma unroll
  for (int kb = 0; kb < 2; kb++) {
    const float* srcq = qrow + kb * 32 + l4 * 8;
    float4 f0 = ((const float4*)srcq)[0];
    float4 f1 = ((const float4*)srcq)[1];
    bf16x8 vq;
    vq[0] = (short)f2bf(f0.x); vq[1] = (short)f2bf(f0.y);
    vq[2] = (short)f2bf(f0.z); vq[3] = (short)f2bf(f0.w);
    vq[4] = (short)f2bf(f1.x); vq[5] = (short)f2bf(f1.y);
    vq[6] = (short)f2bf(f1.z); vq[7] = (short)f2bf(f1.w);
    qf[kb] = vq;
  }
  int qb = qblk[bh * Nc + nq];
  f32x4 oacc[5];
#pragma unroll
  for (int nt = 0; nt < 5; nt++) oacc[nt] = (f32x4){0.f, 0.f, 0.f, 0.f};
  const unsigned short* KhB = Khg + (size_t)bh * Sc * 64;
  const unsigned short* WTB = WhTg + (size_t)bh * 80 * Sc;
  const int* sblkB = sblk + bh * Sc;
  for (int tile = 0; tile < 13; tile++) {
    int s0 = tile * 64;
    int cnt = (tile < 12) ? 64 : 32;
    for (int idx = t; idx < cnt * 8; idx += 256) {
      int r = idx >> 3, sg = idx & 7;
      *(uint4*)&KhL[r * 72 + sg * 8] = *(const uint4*)&KhB[(size_t)(s0 + r) * 64 + sg * 8];
    }
    int ssh = (cnt == 64) ? 3 : 2;
    int segs = cnt >> 3;
    for (int idx = t; idx < 80 * segs; idx += 256) {
      int c = idx >> ssh, sg = idx & (segs - 1);
      *(uint4*)&WTL[c * 72 + sg * 8] = *(const uint4*)&WTB[(size_t)c * Sc + s0 + sg * 8];
    }
    if (t < cnt) bl[t] = sblkB[s0 + t];
    __syncthreads();
    int mtn = cnt >> 4;
    f32x4 sacc[4];
#pragma unroll
    for (int mt = 0; mt < 4; mt++) sacc[mt] = (f32x4){0.f, 0.f, 0.f, 0.f};
#pragma unroll
    for (int kb = 0; kb < 2; kb++) {
#pragma unroll
      for (int mt = 0; mt < 4; mt++) {
        if (mt >= mtn) break;
        bf16x8 ka = *(const bf16x8*)&KhL[(mt * 16 + l15) * 72 + kb * 32 + l4 * 8];
        sacc[mt] = __builtin_amdgcn_mfma_f32_16x16x32_bf16(ka, qf[kb], sacc[mt], 0, 0, 0);
      }
    }
#pragma unroll
    for (int mt = 0; mt < 4; mt++) {
      if (mt >= mtn) break;
      int sb = mt * 16 + l4 * 4;
      unsigned short p0 = (bl[sb + 0] == qb) ? 0 : f2bf(__expf(sacc[mt][0]));
      unsigned short p1 = (bl[sb + 1] == qb) ? 0 : f2bf(__expf(sacc[mt][1]));
      unsigned short p2 = (bl[sb + 2] == qb) ? 0 : f2bf(__expf(sacc[mt][2]));
      unsigned short p3 = (bl[sb + 3] == qb) ? 0 : f2bf(__expf(sacc[mt][3]));
      uint2 pk;
      pk.x = (u32)p0 | ((u32)p1 << 16);
      pk.y = (u32)p2 | ((u32)p3 << 16);
      *(uint2*)&PL[(16 * w + l15) * 72 + sb] = pk;
    }
    int kbn = cnt >> 5;
#pragma unroll
    for (int kb = 0; kb < 2; kb++) {
      if (kb >= kbn) break;
      bf16x8 pa = *(const bf16x8*)&PL[(16 * w + l15) * 72 + kb * 32 + l4 * 8];
#pragma unroll
      for (int nt = 0; nt < 5; nt++) {
        bf16x8 wb = *(const bf16x8*)&WTL[(nt * 16 + l15) * 72 + kb * 32 + l4 * 8];
        oacc[nt] = __builtin_amdgcn_mfma_f32_16x16x32_bf16(pa, wb, oacc[nt], 0, 0, 0);
      }
    }
    __syncthreads();
  }
  float den[4];
#pragma unroll
  for (int i = 0; i < 4; i++) {
    int n = n0 + 16 * w + l4 * 4 + i;
    const float* arow = att + ((size_t)bh * Nc + n) * D1c;
    float cand = (l15 == 0) ? (arow[Dc] + oacc[4][i]) : 0.f;
    den[i] = __shfl(cand, l & 48);   // broadcast from col-64 lane of this group
  }
#pragma unroll
  for (int i = 0; i < 4; i++) {
    int n = n0 + 16 * w + l4 * 4 + i;
    const float* arow = att + ((size_t)bh * Nc + n) * D1c;
    float* orow = out + ((size_t)bh * Nc + n) * Dc;
#pragma unroll
    for (int nt = 0; nt < 4; nt++) {
      int c = nt * 16 + l15;
      orow[c] = (arow[c] + oacc[nt][i]) / den[i];
    }
  }
}

// ---------------------------------------------------------------------------
extern "C" void kernel_launch(void* const* d_in, const int* in_sizes, int n_in,
                              void* d_out, int out_size, void* d_ws, size_t ws_size,
                              hipStream_t stream) {
  const float* q  = (const float*)d_in[0];
  const float* k  = (const float*)d_in[1];
  const float* v  = (const float*)d_in[2];
  const float* pd = (const float*)d_in[3];
  const float* pm = (const float*)d_in[4];
  float* out = (float*)d_out;

  char* w = (char*)d_ws;
  size_t off = 0;
  auto take = [&](size_t nbytes) -> void* {
    void* p = w + off;
    off += (nbytes + 255) & ~(size_t)255;
    return p;
  };
  double* gram = (double*)take((size_t)BHc * D1c * D1c * sizeof(double));
  double* sigm = (double*)take((size_t)BHc * sizeof(double));
  double* Pun  = (double*)take((size_t)BHc * Nc * sizeof(double));
  double* psum = (double*)take((size_t)BHc * 8 * sizeof(double));
  int* hq   = (int*)take((size_t)BHc * Nc * 4);
  int* hk   = (int*)take((size_t)BHc * Nc * 4);
  int* qidx = (int*)take((size_t)BHc * Nc * 4);
  int* kidx = (int*)take((size_t)BHc * Nc * 4);
  int* qblk = (int*)take((size_t)BHc * Nc * 4);
  float* P    = (float*)take((size_t)BHc * Nc * 4);
  float* logP = (float*)take((size_t)BHc * Nc * 4);
  int* sblk = (int*)take((size_t)BHc * Sc * 4);
  unsigned short* Khg  = (unsigned short*)take((size_t)BHc * Sc * 64 * 2);
  unsigned short* WhTg = (unsigned short*)take((size_t)BHc * 80 * Sc * 2);
  // union region: Gram chunk partials (used first), then att (written after
  // gram_reduce has consumed the partials — stream order guarantees this).
  size_t partBytes = (size_t)BHc * NCHUNK * D1c * D1c * sizeof(double);
  size_t attBytes  = (size_t)BHc * Nc * D1c * 4;
  void* uni = take(partBytes > attBytes ? partBytes : attBytes);
  double* part = (double*)uni;
  float*  att  = (float*)uni;
  (void)ws_size; (void)in_sizes; (void)n_in; (void)out_size;

  hash_kernel<<<2 * BHc * Nc / 256, 256, 0, stream>>>(q, k, pd, hq, hk);
  sort_kernel<<<dim3(BHc, 2), 512, 0, stream>>>(hq, hk, qidx, kidx, qblk);
  gram_partial_kernel<<<BHc * NCHUNK, 256, 0, stream>>>(v, part);
  gram_reduce_kernel<<<(BHc * D1c * D1c + 255) / 256, 256, 0, stream>>>(part, gram);
  power_kernel<<<BHc, 128, 0, stream>>>(gram, pm, sigm);
  p_partial_kernel<<<BHc * 8, 256, 0, stream>>>(v, kidx, sigm, Pun, psum);
  p_final_kernel<<<BHc * Nc / 256, 256, 0, stream>>>(Pun, psum, P, logP);
  sample_kernel<<<BHc * Sc, 256, 0, stream>>>(logP, kidx, P, k, v, Khg, WhTg, sblk);
  sparse_kernel<<<BHc * NBc * 4, 256, 0, stream>>>(q, k, v, qidx, kidx, att);  // writes att (over part)
  residual_kernel<<<BHc * 64, 256, 0, stream>>>(q, Khg, WhTg, sblk, qblk, att, out);
}

// Round 18
// 434.324 us; speedup vs baseline: 2.4735x; 1.0415x over previous
//
#include <hip/hip_runtime.h>
#include <stdint.h>
#include <math.h>

// ---------------------------------------------------------------------------
// CosineHammingAttention — bit-faithful HIP port of the JAX reference.
// B=2 H=8 N=4096 D=64, NUM_PROJS=7, BUCKET=256, SAMPLE=800, PM_ITERS=32
// R2: parallelize Gram.  R3/R8/R10: f32 attention ladder (boxed ~400us).
// R11: residual -> MFMA bf16 — 869->546us.  R12: sparse -> MFMA — 453us.
// R16: LDS-staged logP in sample = NULL (172->171; VALU-issue bound, not
//     load-latency bound). Container recovered (R14/15 timeouts were infra
//     or pragma-related).
// R17: one-log transform retry on proven R16 base, NO unroll pragmas:
//     argmax(g+logP) == argmax(log2(u)*invP)  (monotone: -exp(-x) map;
//     u=0 -> -inf never wins, ref's tiny-clamp candidate ~-13 also never
//     wins). p_final emits invP; everything else byte-identical to R16.
// ---------------------------------------------------------------------------

typedef unsigned int u32;
typedef __attribute__((ext_vector_type(8))) short bf16x8;
typedef __attribute__((ext_vector_type(4))) float f32x4;

namespace {
constexpr int Bc = 2, Hc = 8, BHc = 16;
constexpr int Nc = 4096, Dc = 64, D1c = 65;
constexpr int NBc = 16;      // N / BUCKET
constexpr int Sc = 800;      // SAMPLE
constexpr int PMITERc = 32;
constexpr int GCH = 128;             // Gram rows per chunk
constexpr int NCHUNK = Nc / GCH;     // 32
}

__device__ __forceinline__ u32 rotl32(u32 x, u32 d) { return (x << d) | (x >> (32u - d)); }

__device__ __forceinline__ unsigned short f2bf(float f) {  // RNE f32 -> bf16
  u32 u = __float_as_uint(f);
  u += 0x7FFFu + ((u >> 16) & 1u);
  return (unsigned short)(u >> 16);
}

// Exact JAX threefry2x32 (20 rounds).
__device__ __forceinline__ void threefry2x32(u32 k0, u32 k1, u32 x0, u32 x1, u32& o0, u32& o1) {
  u32 ks2 = k0 ^ k1 ^ 0x1BD11BDAu;
  x0 += k0; x1 += k1;
#define TF_RND(r) { x0 += x1; x1 = rotl32(x1, r); x1 ^= x0; }
  TF_RND(13) TF_RND(15) TF_RND(26) TF_RND(6)
  x0 += k1; x1 += ks2 + 1u;
  TF_RND(17) TF_RND(29) TF_RND(16) TF_RND(24)
  x0 += ks2; x1 += k0 + 2u;
  TF_RND(13) TF_RND(15) TF_RND(26) TF_RND(6)
  x0 += k0; x1 += k1 + 3u;
  TF_RND(17) TF_RND(29) TF_RND(16) TF_RND(24)
  x0 += k1; x1 += ks2 + 4u;
  TF_RND(13) TF_RND(15) TF_RND(26) TF_RND(6)
  x0 += ks2; x1 += k0 + 5u;
#undef TF_RND
  o0 = x0; o1 = x1;
}

// ---- K1: LSH hash codes for q and k ---------------------------------------
__global__ __launch_bounds__(256) void hash_kernel(
    const float* __restrict__ q, const float* __restrict__ k,
    const float* __restrict__ pd, int* __restrict__ hq, int* __restrict__ hk) {
  int tid = blockIdx.x * 256 + threadIdx.x;
  int which = tid / (BHc * Nc);
  int rem = tid % (BHc * Nc);
  int bh = rem / Nc, n = rem % Nc;
  int b = bh / Hc, h = bh % Hc;
  const float* x = which ? k : q;
  const float* row = x + (((size_t)b * Nc + n) * Hc + h) * Dc;   // [B,N,H,D]
  const float* pdr = pd + (size_t)bh * Dc * 7;                   // [B,H,D,7]
  double acc[7];
#pragma unroll
  for (int r = 0; r < 7; r++) acc[r] = 0.0;
  for (int d = 0; d < Dc; d++) {
    double vv = (double)row[d];
    const float* pr = pdr + d * 7;
#pragma unroll
    for (int r = 0; r < 7; r++) acc[r] += vv * (double)pr[r];
  }
  int code = 0;
#pragma unroll
  for (int r = 0; r < 7; r++) code |= (acc[r] > 0.0) ? (1 << r) : 0;
  int hash = code ^ (code >> 1);   // _hamming_perm == binary-reflected Gray code
  (which ? hk : hq)[bh * Nc + n] = hash;
}

// ---- K2: stable counting sort, quarter-split; q-branch also writes qblk ---
__global__ __launch_bounds__(512) void sort_kernel(
    const int* __restrict__ hq, const int* __restrict__ hk,
    int* __restrict__ qidx, int* __restrict__ kidx, int* __restrict__ qblk) {
  __shared__ int sh[Nc];
  __shared__ int cnt[4][128];
  __shared__ int off[128];
  int bh = blockIdx.x;
  int which = blockIdx.y;
  const int* hash = which ? hk : hq;
  int* out = which ? kidx : qidx;
  int t = threadIdx.x;
  for (int i = t; i < Nc; i += 512) sh[i] = hash[bh * Nc + i];
  __syncthreads();
  int qr = t >> 7, b = t & 127;      // quarter, bin
  int c = 0;
  for (int i = qr * 1024; i < (qr + 1) * 1024; i++) c += (sh[i] == b);
  cnt[qr][b] = c;
  __syncthreads();
  if (t == 0) {
    int run = 0;
    for (int j = 0; j < 128; j++) {
      int tot = cnt[0][j] + cnt[1][j] + cnt[2][j] + cnt[3][j];
      off[j] = run; run += tot;
    }
  }
  __syncthreads();
  int o = off[b];
  for (int qq = 0; qq < qr; qq++) o += cnt[qq][b];
  for (int i = qr * 1024; i < (qr + 1) * 1024; i++)
    if (sh[i] == b) {
      out[bh * Nc + o] = i;
      if (which == 0) qblk[bh * Nc + i] = o >> 8;
      o++;
    }
}

// ---- K4: block-sparse attention via MFMA (bf16) ---------------------------
__global__ __launch_bounds__(256) void sparse_kernel(
    const float* __restrict__ q, const float* __restrict__ k, const float* __restrict__ v,
    const int* __restrict__ qidx, const int* __restrict__ kidx, float* __restrict__ att) {
  __shared__ unsigned short sm[14976];  // Kh[64][72] | WT[80][72] | P[64][72]
  unsigned short* KhL = sm;             // 4608
  unsigned short* WTL = sm + 4608;      // 5760
  unsigned short* PL  = sm + 10368;     // 4608
  int blk = blockIdx.x;
  int bh = blk >> 6;
  int rem = blk & 63;
  int g = rem >> 2, qq = rem & 3;
  int b = bh / Hc, h = bh % Hc;
  int t = threadIdx.x;
  int w = t >> 6, l = t & 63;
  int l15 = l & 15, l4 = l >> 4;
  // Q fragments (B-operand): q-row-in-group = 16w + l15 (sorted order)
  int qpos = g * 256 + qq * 64 + 16 * w + l15;
  int nq = qidx[bh * Nc + qpos];
  const float* qrow = q + (((size_t)b * Nc + nq) * Hc + h) * Dc;
  bf16x8 qf[2];
#pragma unroll
  for (int kb = 0; kb < 2; kb++) {
    const float* srcq = qrow + kb * 32 + l4 * 8;
    float4 f0 = ((const float4*)srcq)[0];
    float4 f1 = ((const float4*)srcq)[1];
    bf16x8 vq;
    vq[0] = (short)f2bf(f0.x); vq[1] = (short)f2bf(f0.y);
    vq[2] = (short)f2bf(f0.z); vq[3] = (short)f2bf(f0.w);
    vq[4] = (short)f2bf(f1.x); vq[5] = (short)f2bf(f1.y);
    vq[6] = (short)f2bf(f1.z); vq[7] = (short)f2bf(f1.w);
    qf[kb] = vq;
  }
  f32x4 oacc[5];
#pragma unroll
  for (int nt = 0; nt < 5; nt++) oacc[nt] = (f32x4){0.f, 0.f, 0.f, 0.f};
  // constant WT rows: 64 = ones column of v_aug, 65..79 = 0
  for (int idx = t; idx < 16 * 64; idx += 256) {
    int r = idx >> 6, s = idx & 63;
    WTL[(64 + r) * 72 + s] = (r == 0) ? (unsigned short)0x3F80 : (unsigned short)0;
  }
  const int* kidxB = kidx + bh * Nc + g * 256;
  for (int tile = 0; tile < 4; tile++) {
    __syncthreads();   // previous tile's LDS fully consumed
    for (int idx = t; idx < 64 * 16; idx += 256) {
      int j = idx >> 4, d4 = idx & 15;
      int m = kidxB[tile * 64 + j];
      const float* kr = k + (((size_t)b * Nc + m) * Hc + h) * Dc;
      const float* vr = v + (((size_t)b * Nc + m) * Hc + h) * Dc;
      float4 kv = ((const float4*)kr)[d4];
      uint2 pk;
      pk.x = (u32)f2bf(kv.x) | ((u32)f2bf(kv.y) << 16);
      pk.y = (u32)f2bf(kv.z) | ((u32)f2bf(kv.w) << 16);
      *(uint2*)&KhL[j * 72 + 4 * d4] = pk;
      float4 vv = ((const float4*)vr)[d4];
      WTL[(4 * d4 + 0) * 72 + j] = f2bf(vv.x);   // in-LDS transpose
      WTL[(4 * d4 + 1) * 72 + j] = f2bf(vv.y);
      WTL[(4 * d4 + 2) * 72 + j] = f2bf(vv.z);
      WTL[(4 * d4 + 3) * 72 + j] = f2bf(vv.w);
    }
    __syncthreads();
    // S^T = K * Q^T  (M = key, N = q, K-dim = D = 64)
    f32x4 sacc[4];
#pragma unroll
    for (int mt = 0; mt < 4; mt++) sacc[mt] = (f32x4){0.f, 0.f, 0.f, 0.f};
#pragma unroll
    for (int kb = 0; kb < 2; kb++) {
#pragma unroll
      for (int mt = 0; mt < 4; mt++) {
        bf16x8 ka = *(const bf16x8*)&KhL[(mt * 16 + l15) * 72 + kb * 32 + l4 * 8];
        sacc[mt] = __builtin_amdgcn_mfma_f32_16x16x32_bf16(ka, qf[kb], sacc[mt], 0, 0, 0);
      }
    }
    // exp -> P bf16 -> LDS (row = q-row 16w+l15, col = key)
#pragma unroll
    for (int mt = 0; mt < 4; mt++) {
      int sb = mt * 16 + l4 * 4;
      unsigned short p0 = f2bf(__expf(sacc[mt][0]));
      unsigned short p1 = f2bf(__expf(sacc[mt][1]));
      unsigned short p2 = f2bf(__expf(sacc[mt][2]));
      unsigned short p3 = f2bf(__expf(sacc[mt][3]));
      uint2 pk;
      pk.x = (u32)p0 | ((u32)p1 << 16);
      pk.y = (u32)p2 | ((u32)p3 << 16);
      *(uint2*)&PL[(16 * w + l15) * 72 + sb] = pk;
    }
    // PV: O += P * WT  (K-dim = 64 keys, 2 blocks)
#pragma unroll
    for (int kb = 0; kb < 2; kb++) {
      bf16x8 pa = *(const bf16x8*)&PL[(16 * w + l15) * 72 + kb * 32 + l4 * 8];
#pragma unroll
      for (int nt = 0; nt < 5; nt++) {
        bf16x8 wb = *(const bf16x8*)&WTL[(nt * 16 + l15) * 72 + kb * 32 + l4 * 8];
        oacc[nt] = __builtin_amdgcn_mfma_f32_16x16x32_bf16(pa, wb, oacc[nt], 0, 0, 0);
      }
    }
  }
  // epilogue: scatter to original order via qidx
#pragma unroll
  for (int i = 0; i < 4; i++) {
    int qrw = 16 * w + l4 * 4 + i;
    int nqi = qidx[bh * Nc + g * 256 + qq * 64 + qrw];
    float* arow = att + ((size_t)bh * Nc + nqi) * D1c;
#pragma unroll
    for (int nt = 0; nt < 4; nt++) arow[nt * 16 + l15] = oacc[nt][i];
    if (l15 == 0) arow[Dc] = oacc[4][i];   // col 64 = denominator
  }
}

// ---- K5a: partial Gram over 128-row chunks (f32 accum, grid = BH*32) ------
__global__ __launch_bounds__(256) void gram_partial_kernel(
    const float* __restrict__ v, double* __restrict__ part) {
  __shared__ float ch[GCH][D1c];
  int bh = blockIdx.x / NCHUNK, c = blockIdx.x % NCHUNK;
  int b = bh / Hc, h = bh % Hc;
  int t = threadIdx.x;
  for (int e = t; e < GCH * D1c; e += 256) {
    int r = e / D1c, p = e % D1c;
    int n = c * GCH + r;
    ch[r][p] = (p < Dc) ? v[(((size_t)b * Nc + n) * Hc + h) * Dc + p] : 1.0f;
  }
  __syncthreads();
  for (int pi = t; pi < D1c * D1c; pi += 256) {
    int tt = pi / D1c, uu = pi % D1c;
    float a = 0.0f;
    for (int r = 0; r < GCH; r++) a += ch[r][tt] * ch[r][uu];
    part[((size_t)bh * NCHUNK + c) * (D1c * D1c) + pi] = (double)a;
  }
}

// ---- K5b: reduce chunk partials (fixed order -> deterministic) ------------
__global__ __launch_bounds__(256) void gram_reduce_kernel(
    const double* __restrict__ part, double* __restrict__ gram) {
  int idx = blockIdx.x * 256 + threadIdx.x;   // over BH * 4225
  if (idx >= BHc * D1c * D1c) return;
  int bh = idx / (D1c * D1c), pi = idx % (D1c * D1c);
  double s = 0.0;
  for (int c = 0; c < NCHUNK; c++)
    s += part[((size_t)bh * NCHUNK + c) * (D1c * D1c) + pi];
  gram[(size_t)bh * (D1c * D1c) + pi] = s;
}

// ---- K6: power method for spectral norm -----------------------------------
__global__ __launch_bounds__(128) void power_kernel(
    const double* __restrict__ gram, const float* __restrict__ pm, double* __restrict__ sigma) {
  __shared__ double G[D1c * D1c];
  __shared__ double x[D1c], y[D1c];
  __shared__ double nrm;
  int bh = blockIdx.x, t = threadIdx.x;
  for (int e = t; e < D1c * D1c; e += 128) G[e] = gram[(size_t)bh * D1c * D1c + e];
  if (t < D1c) x[t] = (double)pm[bh * D1c + t];
  __syncthreads();
  if (t == 0) {
    double s = 0; for (int i = 0; i < D1c; i++) s += x[i] * x[i];
    nrm = sqrt(s);
  }
  __syncthreads();
  if (t < D1c) x[t] /= nrm;
  for (int it = 0; it < PMITERc; it++) {
    __syncthreads();
    if (t < D1c) {
      double s = 0;
      for (int u = 0; u < D1c; u++) s += G[t * D1c + u] * x[u];
      y[t] = s;
    }
    __syncthreads();
    if (t == 0) {
      double s = 0; for (int i = 0; i < D1c; i++) s += y[i] * y[i];
      nrm = sqrt(s);
    }
    __syncthreads();
    if (t < D1c) x[t] = y[t] / nrm;
  }
  __syncthreads();
  if (t == 0) sigma[bh] = nrm;
}

// ---- K7a: unnormalized P + per-segment partial sums (grid = BH*8) ---------
__global__ __launch_bounds__(256) void p_partial_kernel(
    const float* __restrict__ v, const int* __restrict__ kidx,
    const double* __restrict__ sigma, double* __restrict__ Pun, double* __restrict__ psum) {
  __shared__ double red[256];
  int blk = blockIdx.x;
  int bh = blk >> 3, seg = blk & 7;
  int b = bh / Hc, h = bh % Hc;
  int t = threadIdx.x;
  double sg = sigma[bh];
  double part = 0.0;
  for (int n = seg * 512 + t; n < (seg + 1) * 512; n += 256) {
    int m = kidx[bh * Nc + n];
    const float* vr = v + (((size_t)b * Nc + m) * Hc + h) * Dc;
    double ss = 1.0;  // the appended 1.0 component of v_aug
    for (int d = 0; d < Dc; d++) { double vv = vr[d]; ss += vv * vv; }
    double Pd = sqrt(ss) / sg + (1.0 / (double)Nc);
    Pun[bh * Nc + n] = Pd;
    part += Pd;
  }
  red[t] = part;
  __syncthreads();
  for (int w = 128; w > 0; w >>= 1) {
    if (t < w) red[t] += red[t + w];
    __syncthreads();
  }
  if (t == 0) psum[blk] = red[0];
}

// ---- K7b: normalize; emit P and 1/P (for the one-log gumbel argmax) -------
__global__ __launch_bounds__(256) void p_final_kernel(
    const double* __restrict__ Pun, const double* __restrict__ psum,
    float* __restrict__ P, float* __restrict__ invP) {
  int idx = blockIdx.x * 256 + threadIdx.x;   // over BH*N
  int bh = idx / Nc;
  double tot = 0.0;
#pragma unroll
  for (int s = 0; s < 8; s++) tot += psum[bh * 8 + s];
  double pu = Pun[idx];
  P[idx] = (float)(pu / tot);
  invP[idx] = (float)(tot / pu);
}

// ---- K8: categorical sampling (argmax log2(u)*invP) + fused gather --------
// argmax_n (gumbel_n + log P_n) == argmax_n (log2(u_n) * invP_n): strictly
// monotone map x -> -exp(-x). u=0 -> -inf, never selected (ref's tiny-clamp
// candidate ~ -13 also never beats the ~+8 max of 4096 gumbels).
__global__ __launch_bounds__(256) void sample_kernel(
    const float* __restrict__ invP, const int* __restrict__ kidx,
    const float* __restrict__ P, const float* __restrict__ key, const float* __restrict__ value,
    unsigned short* __restrict__ Khg,   // [BH][800][64] bf16
    unsigned short* __restrict__ WhTg,  // [BH][80][800] bf16 (transposed, cols 65..79 = 0)
    int* __restrict__ sblk) {
  __shared__ float ivl[Nc];       // 16 KB staged invP
  __shared__ float sv[256];
  __shared__ int si[256];
  int blk = blockIdx.x;           // bh*S + s
  int bh = blk / Sc, s = blk % Sc;
  int b = bh / Hc, h = bh % Hc;
  int t = threadIdx.x;
  const float* ivg = invP + bh * Nc;
  for (int it = 0; it < 16; it++) ivl[t + it * 256] = ivg[t + it * 256];
  __syncthreads();
  float best = -3.4e38f; int besti = Nc;
  u32 base = ((u32)(s * BHc + bh)) * (u32)Nc;  // flat index into (800,16,4096)
  for (int it = 0; it < 16; it++) {
    int n = t + it * 256;
    u32 o0, o1;
    threefry2x32(0u, 1234u, 0u, base + (u32)n, o0, o1);
    u32 bits = o0 ^ o1;
    float u = __uint_as_float((bits >> 9) | 0x3f800000u) - 1.0f;  // [0,1)
    float val = __log2f(u) * ivl[n];
    if (val > best || (val == best && n < besti)) { best = val; besti = n; }
  }
  sv[t] = best; si[t] = besti;
  __syncthreads();
  for (int w = 128; w > 0; w >>= 1) {
    if (t < w) {
      float v2 = sv[t + w]; int i2 = si[t + w];
      if (v2 > sv[t] || (v2 == sv[t] && i2 < si[t])) { sv[t] = v2; si[t] = i2; }
    }
    __syncthreads();
  }
  int m = si[0];
  if (t == 0) sblk[blk] = m >> 8;
  int src = kidx[bh * Nc + m];
  float sg = 1.0f / (P[bh * Nc + m] * (float)Sc);
  const float* kr = key + (((size_t)b * Nc + src) * Hc + h) * Dc;
  const float* vr = value + (((size_t)b * Nc + src) * Hc + h) * Dc;
  if (t < Dc) Khg[((size_t)bh * Sc + s) * 64 + t] = f2bf(kr[t]);
  if (t < 80) {
    float val = (t < Dc) ? sg * vr[t] : ((t == Dc) ? sg : 0.0f);
    WhTg[((size_t)bh * 80 + t) * Sc + s] = f2bf(val);
  }
}

// ---- K10: residual attention via MFMA (bf16) ------------------------------
__global__ __launch_bounds__(256) void residual_kernel(
    const float* __restrict__ q,
    const unsigned short* __restrict__ Khg, const unsigned short* __restrict__ WhTg,
    const int* __restrict__ sblk,
    const int* __restrict__ qblk, const float* __restrict__ att, float* __restrict__ out) {
  __shared__ unsigned short sm[14976];  // Kh[64][72] | WhT[80][72] | P[64][72]
  __shared__ int bl[64];
  unsigned short* KhL = sm;             // 4608
  unsigned short* WTL = sm + 4608;      // 5760
  unsigned short* PL  = sm + 10368;     // 4608
  int blk = blockIdx.x;
  int bh = blk >> 6;
  int n0 = (blk & 63) * 64;
  int b = bh / Hc, h = bh % Hc;
  int t = threadIdx.x;
  int w = t >> 6, l = t & 63;
  int l15 = l & 15, l4 = l >> 4;
  int nq = n0 + 16 * w + l15;
  const float* qrow = q + (((size_t)b * Nc + nq) * Hc + h) * Dc;
  bf16x8 qf[2];
#pragma unroll
  for (int kb = 0; kb < 2; kb++) {
    const float* srcq = qrow + kb * 32 + l4 * 8;
    float4 f0 = ((const float4*)srcq)[0];
    float4 f1 = ((const float4*)srcq)[1];
    bf16x8 vq;
    vq[0] = (short)f2bf(f0.x); vq[1] = (short)f2bf(f0.y);
    vq[2] = (short)f2bf(f0.z); vq[3] = (short)f2bf(f0.w);
    vq[4] = (short)f2bf(f1.x); vq[5] = (short)f2bf(f1.y);
    vq[6] = (short)f2bf(f1.z); vq[7] = (short)f2bf(f1.w);
    qf[kb] = vq;
  }
  int qb = qblk[bh * Nc + nq];
  f32x4 oacc[5];
#pragma unroll
  for (int nt = 0; nt < 5; nt++) oacc[nt] = (f32x4){0.f, 0.f, 0.f, 0.f};
  const unsigned short* KhB = Khg + (size_t)bh * Sc * 64;
  const unsigned short* WTB = WhTg + (size_t)bh * 80 * Sc;
  const int* sblkB = sblk + bh * Sc;
  for (int tile = 0; tile < 13; tile++) {
    int s0 = tile * 64;
    int cnt = (tile < 12) ? 64 : 32;
    for (int idx = t; idx < cnt * 8; idx += 256) {
      int r = idx >> 3, sg = idx & 7;
      *(uint4*)&KhL[r * 72 + sg * 8] = *(const uint4*)&KhB[(size_t)(s0 + r) * 64 + sg * 8];
    }
    int ssh = (cnt == 64) ? 3 : 2;
    int segs = cnt >> 3;
    for (int idx = t; idx < 80 * segs; idx += 256) {
      int c = idx >> ssh, sg = idx & (segs - 1);
      *(uint4*)&WTL[c * 72 + sg * 8] = *(const uint4*)&WTB[(size_t)c * Sc + s0 + sg * 8];
    }
    if (t < cnt) bl[t] = sblkB[s0 + t];
    __syncthreads();
    int mtn = cnt >> 4;
    f32x4 sacc[4];
#pragma unroll
    for (int mt = 0; mt < 4; mt++) sacc[mt] = (f32x4){0.f, 0.f, 0.f, 0.f};
#pragma unroll
    for (int kb = 0; kb < 2; kb++) {
#pragma unroll
      for (int mt = 0; mt < 4; mt++) {
        if (mt >= mtn) break;
        bf16x8 ka = *(const bf16x8*)&KhL[(mt * 16 + l15) * 72 + kb * 32 + l4 * 8];
        sacc[mt] = __builtin_amdgcn_mfma_f32_16x16x32_bf16(ka, qf[kb], sacc[mt], 0, 0, 0);
      }
    }
#pragma unroll
    for (int mt = 0; mt < 4; mt++) {
      if (mt >= mtn) break;
      int sb = mt * 16 + l4 * 4;
      unsigned short p0 = (bl[sb + 0] == qb) ? 0 : f2bf(__expf(sacc[mt][0]));
      unsigned short p1 = (bl[sb + 1] == qb) ? 0 : f2bf(__expf(sacc[mt][1]));
      unsigned short p2 = (bl[sb + 2] == qb) ? 0 : f2bf(__expf(sacc[mt][2]));
      unsigned short p3 = (bl[sb + 3] == qb) ? 0 : f2bf(__expf(sacc[mt][3]));
      uint2 pk;
      pk.x = (u32)p0 | ((u32)p1 << 16);
      pk.y = (u32)p2 | ((u32)p3 << 16);
      *(uint2*)&PL[(16 * w + l15) * 72 + sb] = pk;
    }
    int kbn = cnt >> 5;
#pragma unroll
    for (int kb = 0; kb < 2; kb++) {
      if (kb >= kbn) break;
      bf16x8 pa = *(const bf16x8*)&PL[(16 * w + l15) * 72 + kb * 32 + l4 * 8];
#pragma unroll
      for (int nt = 0; nt < 5; nt++) {
        bf16x8 wb = *(const bf16x8*)&WTL[(nt * 16 + l15) * 72 + kb * 32 + l4 * 8];
        oacc[nt] = __builtin_amdgcn_mfma_f32_16x16x32_bf16(pa, wb, oacc[nt], 0, 0, 0);
      }
    }
    __syncthreads();
  }
  float den[4];
#pragma unroll
  for (int i = 0; i < 4; i++) {
    int n = n0 + 16 * w + l4 * 4 + i;
    const float* arow = att + ((size_t)bh * Nc + n) * D1c;
    float cand = (l15 == 0) ? (arow[Dc] + oacc[4][i]) : 0.f;
    den[i] = __shfl(cand, l & 48);   // broadcast from col-64 lane of this group
  }
#pragma unroll
  for (int i = 0; i < 4; i++) {
    int n = n0 + 16 * w + l4 * 4 + i;
    const float* arow = att + ((size_t)bh * Nc + n) * D1c;
    float* orow = out + ((size_t)bh * Nc + n) * Dc;
#pragma unroll
    for (int nt = 0; nt < 4; nt++) {
      int c = nt * 16 + l15;
      orow[c] = (arow[c] + oacc[nt][i]) / den[i];
    }
  }
}

// ---------------------------------------------------------------------------
extern "C" void kernel_launch(void* const* d_in, const int* in_sizes, int n_in,
                              void* d_out, int out_size, void* d_ws, size_t ws_size,
                              hipStream_t stream) {
  const float* q  = (const float*)d_in[0];
  const float* k  = (const float*)d_in[1];
  const float* v  = (const float*)d_in[2];
  const float* pd = (const float*)d_in[3];
  const float* pm = (const float*)d_in[4];
  float* out = (float*)d_out;

  char* w = (char*)d_ws;
  size_t off = 0;
  auto take = [&](size_t nbytes) -> void* {
    void* p = w + off;
    off += (nbytes + 255) & ~(size_t)255;
    return p;
  };
  double* gram = (double*)take((size_t)BHc * D1c * D1c * sizeof(double));
  double* sigm = (double*)take((size_t)BHc * sizeof(double));
  double* Pun  = (double*)take((size_t)BHc * Nc * sizeof(double));
  double* psum = (double*)take((size_t)BHc * 8 * sizeof(double));
  int* hq   = (int*)take((size_t)BHc * Nc * 4);
  int* hk   = (int*)take((size_t)BHc * Nc * 4);
  int* qidx = (int*)take((size_t)BHc * Nc * 4);
  int* kidx = (int*)take((size_t)BHc * Nc * 4);
  int* qblk = (int*)take((size_t)BHc * Nc * 4);
  float* P    = (float*)take((size_t)BHc * Nc * 4);
  float* invP = (float*)take((size_t)BHc * Nc * 4);
  int* sblk = (int*)take((size_t)BHc * Sc * 4);
  unsigned short* Khg  = (unsigned short*)take((size_t)BHc * Sc * 64 * 2);
  unsigned short* WhTg = (unsigned short*)take((size_t)BHc * 80 * Sc * 2);
  // union region: Gram chunk partials (used first), then att (written after
  // gram_reduce has consumed the partials — stream order guarantees this).
  size_t partBytes = (size_t)BHc * NCHUNK * D1c * D1c * sizeof(double);
  size_t attBytes  = (size_t)BHc * Nc * D1c * 4;
  void* uni = take(partBytes > attBytes ? partBytes : attBytes);
  double* part = (double*)uni;
  float*  att  = (float*)uni;
  (void)ws_size; (void)in_sizes; (void)n_in; (void)out_size;

  hash_kernel<<<2 * BHc * Nc / 256, 256, 0, stream>>>(q, k, pd, hq, hk);
  sort_kernel<<<dim3(BHc, 2), 512, 0, stream>>>(hq, hk, qidx, kidx, qblk);
  gram_partial_kernel<<<BHc * NCHUNK, 256, 0, stream>>>(v, part);
  gram_reduce_kernel<<<(BHc * D1c * D1c + 255) / 256, 256, 0, stream>>>(part, gram);
  power_kernel<<<BHc, 128, 0, stream>>>(gram, pm, sigm);
  p_partial_kernel<<<BHc * 8, 256, 0, stream>>>(v, kidx, sigm, Pun, psum);
  p_final_kernel<<<BHc * Nc / 256, 256, 0, stream>>>(Pun, psum, P, invP);
  sample_kernel<<<BHc * Sc, 256, 0, stream>>>(invP, kidx, P, k, v, Khg, WhTg, sblk);
  sparse_kernel<<<BHc * NBc * 4, 256, 0, stream>>>(q, k, v, qidx, kidx, att);  // writes att (over part)
  residual_kernel<<<BHc * 64, 256, 0, stream>>>(q, Khg, WhTg, sblk, qblk, att, out);
}